// Round 13
// baseline (583.327 us; speedup 1.0000x reference)
//
#include <hip/hip_runtime.h>
#include <math.h>

// Problem constants (fixed by setup_inputs)
#define B_   4
#define N_   4096
#define E_   1024
#define H_   16
#define BN_  (B_*N_)
#define BH_  (B_*H_)
#define SPLITK 8

// favorp constants
#define NRM_C   0.35355339059327373f   // 64^-0.25
#define DIAG_C  0.0625f                // 0.5 * NRM^2
#define RATIO_C 0.125f                 // 64^-0.5
#define EPSF    1e-4f
#define EPSD    0.01f

typedef __attribute__((ext_vector_type(8))) short bf16x8;   // 8 bf16 in 4 VGPRs
typedef __attribute__((ext_vector_type(4))) float f32x4;

__device__ __forceinline__ unsigned short f32_to_bf16(float x) {
    unsigned int u = __float_as_uint(x);
    unsigned int r = (u + 0x7fffu + ((u >> 16) & 1u)) >> 16;   // RTN-even
    return (unsigned short)r;
}
__device__ __forceinline__ float bf16_to_f32(unsigned short h) {
    return __uint_as_float(((unsigned int)h) << 16);
}

// packed f32->bf16 via HW instruction; D.lo=bf16(a), D.hi=bf16(b)
__device__ __forceinline__ unsigned int pk_bf16(float a, float b) {
    unsigned int r;
    asm("v_cvt_pk_bf16_f32 %0, %1, %2" : "=v"(r) : "v"(a), "v"(b));
    return r;
}

// 8 fp32 -> split bf16 hi/lo fragments (pk-based)
__device__ __forceinline__ void f32x8_split(float4 fa, float4 fb, bf16x8& hi, bf16x8& lo) {
    unsigned int h0 = pk_bf16(fa.x, fa.y), h1 = pk_bf16(fa.z, fa.w);
    unsigned int h2 = pk_bf16(fb.x, fb.y), h3 = pk_bf16(fb.z, fb.w);
    float e0 = __uint_as_float(h0 << 16), e1 = __uint_as_float(h0 & 0xffff0000u);
    float e2 = __uint_as_float(h1 << 16), e3 = __uint_as_float(h1 & 0xffff0000u);
    float e4 = __uint_as_float(h2 << 16), e5 = __uint_as_float(h2 & 0xffff0000u);
    float e6 = __uint_as_float(h3 << 16), e7 = __uint_as_float(h3 & 0xffff0000u);
    unsigned int l0 = pk_bf16(fa.x - e0, fa.y - e1), l1 = pk_bf16(fa.z - e2, fa.w - e3);
    unsigned int l2 = pk_bf16(fb.x - e4, fb.y - e5), l3 = pk_bf16(fb.z - e6, fb.w - e7);
    union { unsigned int u[4]; bf16x8 v; } H, L;
    H.u[0] = h0; H.u[1] = h1; H.u[2] = h2; H.u[3] = h3;
    L.u[0] = l0; L.u[1] = l1; L.u[2] = l2; L.u[3] = l3;
    hi = H.v; lo = L.v;
}

__device__ __forceinline__ void atomicMaxF(float* addr, float v) {
    if (v >= 0.f) atomicMax((int*)addr, __float_as_int(v));
    else          atomicMin((unsigned int*)addr, __float_as_uint(v));
}

__global__ void init_stab(float* stab) {
    if (threadIdx.x < BH_) stab[threadIdx.x] = -INFINITY;
}

// ---------------- split-bf16 conversion ----------------
template<int IN_MODE>
__global__ __launch_bounds__(256) void convert_split(const float* __restrict__ src,
                                                     unsigned short* __restrict__ hi,
                                                     unsigned short* __restrict__ lo,
                                                     int total4)
{
    int i = blockIdx.x * 256 + threadIdx.x;
    const int stride = gridDim.x * 256;
    for (; i < total4; i += stride) {
        long e4 = (long)i * 4;
        const float* p;
        if (IN_MODE == 0) {
            long r = e4 >> 10; int e = (int)(e4 & 1023);
            int b = (int)(r >> 12), n = (int)(r & 4095);
            p = src + (((long)(n * B_ + b)) << 10) + e;
        } else {
            p = src + e4;
        }
        float4 v = *(const float4*)p;
        ushort4 h, l;
        h.x = f32_to_bf16(v.x); l.x = f32_to_bf16(v.x - bf16_to_f32(h.x));
        h.y = f32_to_bf16(v.y); l.y = f32_to_bf16(v.y - bf16_to_f32(h.y));
        h.z = f32_to_bf16(v.z); l.z = f32_to_bf16(v.z - bf16_to_f32(h.z));
        h.w = f32_to_bf16(v.w); l.w = f32_to_bf16(v.w - bf16_to_f32(h.w));
        *(ushort4*)(hi + e4) = h;
        *(ushort4*)(lo + e4) = l;
    }
}

__device__ __forceinline__ void gl_lds16(const unsigned short* g, unsigned short* l) {
    __builtin_amdgcn_global_load_lds((const __attribute__((address_space(1))) void*)g,
                                     (__attribute__((address_space(3))) void*)l, 16, 0, 0);
}

// =====================================================================
// Fine-phase pipelined GEMM, all modes: 256x128 tile, BK=32, 8 waves,
// 3 LDS buffers (144KB), 2-deep prefetch, counted vmcnt(6) at K boundaries.
// MODE 0: Y fp32 [BN,E];  MODE 1: Y fp32 [N,B,E] transposed;
// MODE 2: K-fused favorp (T1 + stab);  MODE 3: Q-fused favorp_q + qkv -> attn split-bf16.
// Epilogue overlay: accF 8x[64][68] f32 (139264B) + diag 2KB + rnm 2KB = 143360 <= 147456.
// =====================================================================
#define SMEM_DYN8 147456

template<int MODE>
__global__ __launch_bounds__(512, 2) void gemm8p(const unsigned short* __restrict__ Ahi,
                                                 const unsigned short* __restrict__ Alo,
                                                 const unsigned short* __restrict__ Bhi,
                                                 const unsigned short* __restrict__ Blo,
                                                 const float* __restrict__ bias,
                                                 float* __restrict__ Y,
                                                 float* __restrict__ stab,
                                                 const unsigned short* __restrict__ PShi,
                                                 const unsigned short* __restrict__ PSlo,
                                                 const unsigned short* __restrict__ kvThi,
                                                 const unsigned short* __restrict__ kvTlo,
                                                 const float* __restrict__ ksum,
                                                 unsigned short* __restrict__ AttnHi,
                                                 unsigned short* __restrict__ AttnLo)
{
    extern __shared__ char SMEM8[];
    unsigned short* U = (unsigned short*)SMEM8;
    const int t = threadIdx.x;
    const int w = t >> 6, lane = t & 63;
    const int row0 = blockIdx.x * 256, col0 = blockIdx.y * 128;
    const int wrow = (w >> 1) * 64, wcol = (w & 1) * 64;
    const int g = lane >> 4, rl = lane & 15;
    const int lr8 = lane >> 3, lc8 = lane & 7;

    // staging address precompute (granule = 16B = 8 shorts)
    int gi0 = t, gi1 = 512 + t;
    int ar0 = gi0 >> 2, as0 = gi0 & 3;
    int ar1 = gi1 >> 2, as1 = gi1 & 3;
    const long aSrc0 = (long)(row0 + ar0) * E_ + ((as0 ^ (ar0 & 3)) << 3);
    const long aSrc1 = (long)(row0 + ar1) * E_ + ((as1 ^ (ar1 & 3)) << 3);
    const int aDst0 = (w * 64) * 8;
    const int aDst1 = (512 + w * 64) * 8;
    const long bSrc = (long)(col0 + (t >> 2)) * E_ + (((t & 3) ^ ((t >> 2) & 3)) << 3);
    const int bDst = (w * 64) * 8;

    f32x4 acc[4][4];
#pragma unroll
    for (int m = 0; m < 4; ++m)
#pragma unroll
        for (int n = 0; n < 4; ++n) acc[m][n] = (f32x4){0.f, 0.f, 0.f, 0.f};

#define STAGE_FULL(TILE, BUFI) {                                        \
        const int k0_ = (TILE) * 32;                                    \
        unsigned short* bu_ = U + (BUFI) * 24576;                       \
        gl_lds16(Ahi + aSrc0 + k0_, bu_ + aDst0);                       \
        gl_lds16(Ahi + aSrc1 + k0_, bu_ + aDst1);                       \
        gl_lds16(Alo + aSrc0 + k0_, bu_ + 8192 + aDst0);                \
        gl_lds16(Alo + aSrc1 + k0_, bu_ + 8192 + aDst1);                \
        gl_lds16(Bhi + bSrc + k0_, bu_ + 16384 + bDst);                 \
        gl_lds16(Blo + bSrc + k0_, bu_ + 20480 + bDst); }

    STAGE_FULL(0, 0);
    STAGE_FULL(1, 1);
    asm volatile("s_waitcnt vmcnt(6)" ::: "memory");   // tile 0 landed (own; FIFO)
    __builtin_amdgcn_s_barrier();                      // all waves' tile 0 landed
    __builtin_amdgcn_sched_barrier(0);

    for (int tt = 0; tt < 32; ++tt) {
        const unsigned short* sb = U + (tt % 3) * 24576;
        unsigned short* ub = U + ((tt + 2) % 3) * 24576;
        const bool st = (tt + 2 < 32);
        const int k2 = (tt + 2) * 32;
        bf16x8 bhf[4], blf[4];

        // ---- phase 0: B frags + A frag m=0; stage Ahi(t+2) ----
#pragma unroll
        for (int n = 0; n < 4; ++n) {
            int r = wcol + n * 16 + rl;
            int off = r * 32 + ((g ^ (r & 3)) << 3);
            bhf[n] = *(const bf16x8*)(sb + 16384 + off);
            blf[n] = *(const bf16x8*)(sb + 20480 + off);
        }
        {
            int r = wrow + rl;
            int off = r * 32 + ((g ^ (r & 3)) << 3);
            bf16x8 ah = *(const bf16x8*)(sb + off);
            bf16x8 al = *(const bf16x8*)(sb + 8192 + off);
            if (st) { gl_lds16(Ahi + aSrc0 + k2, ub + aDst0);
                      gl_lds16(Ahi + aSrc1 + k2, ub + aDst1); }
            asm volatile("s_waitcnt lgkmcnt(0)" ::: "memory");
            __builtin_amdgcn_sched_barrier(0);
            __builtin_amdgcn_s_setprio(1);
#pragma unroll
            for (int n = 0; n < 4; ++n)
                acc[0][n] = __builtin_amdgcn_mfma_f32_16x16x32_bf16(ah, bhf[n], acc[0][n], 0, 0, 0);
#pragma unroll
            for (int n = 0; n < 4; ++n)
                acc[0][n] = __builtin_amdgcn_mfma_f32_16x16x32_bf16(ah, blf[n], acc[0][n], 0, 0, 0);
#pragma unroll
            for (int n = 0; n < 4; ++n)
                acc[0][n] = __builtin_amdgcn_mfma_f32_16x16x32_bf16(al, bhf[n], acc[0][n], 0, 0, 0);
            __builtin_amdgcn_s_setprio(0);
        }
        __builtin_amdgcn_s_barrier();
        __builtin_amdgcn_sched_barrier(0);

        // ---- phase 1: A frag m=1; stage Alo(t+2) ----
        {
            int r = wrow + 16 + rl;
            int off = r * 32 + ((g ^ (r & 3)) << 3);
            bf16x8 ah = *(const bf16x8*)(sb + off);
            bf16x8 al = *(const bf16x8*)(sb + 8192 + off);
            if (st) { gl_lds16(Alo + aSrc0 + k2, ub + 8192 + aDst0);
                      gl_lds16(Alo + aSrc1 + k2, ub + 8192 + aDst1); }
            asm volatile("s_waitcnt lgkmcnt(0)" ::: "memory");
            __builtin_amdgcn_sched_barrier(0);
            __builtin_amdgcn_s_setprio(1);
#pragma unroll
            for (int n = 0; n < 4; ++n)
                acc[1][n] = __builtin_amdgcn_mfma_f32_16x16x32_bf16(ah, bhf[n], acc[1][n], 0, 0, 0);
#pragma unroll
            for (int n = 0; n < 4; ++n)
                acc[1][n] = __builtin_amdgcn_mfma_f32_16x16x32_bf16(ah, blf[n], acc[1][n], 0, 0, 0);
#pragma unroll
            for (int n = 0; n < 4; ++n)
                acc[1][n] = __builtin_amdgcn_mfma_f32_16x16x32_bf16(al, bhf[n], acc[1][n], 0, 0, 0);
            __builtin_amdgcn_s_setprio(0);
        }
        __builtin_amdgcn_s_barrier();
        __builtin_amdgcn_sched_barrier(0);

        // ---- phase 2: A frag m=2; stage Bhi(t+2) ----
        {
            int r = wrow + 32 + rl;
            int off = r * 32 + ((g ^ (r & 3)) << 3);
            bf16x8 ah = *(const bf16x8*)(sb + off);
            bf16x8 al = *(const bf16x8*)(sb + 8192 + off);
            if (st) gl_lds16(Bhi + bSrc + k2, ub + 16384 + bDst);
            asm volatile("s_waitcnt lgkmcnt(0)" ::: "memory");
            __builtin_amdgcn_sched_barrier(0);
            __builtin_amdgcn_s_setprio(1);
#pragma unroll
            for (int n = 0; n < 4; ++n)
                acc[2][n] = __builtin_amdgcn_mfma_f32_16x16x32_bf16(ah, bhf[n], acc[2][n], 0, 0, 0);
#pragma unroll
            for (int n = 0; n < 4; ++n)
                acc[2][n] = __builtin_amdgcn_mfma_f32_16x16x32_bf16(ah, blf[n], acc[2][n], 0, 0, 0);
#pragma unroll
            for (int n = 0; n < 4; ++n)
                acc[2][n] = __builtin_amdgcn_mfma_f32_16x16x32_bf16(al, bhf[n], acc[2][n], 0, 0, 0);
            __builtin_amdgcn_s_setprio(0);
        }
        __builtin_amdgcn_s_barrier();
        __builtin_amdgcn_sched_barrier(0);

        // ---- phase 3: A frag m=3; stage Blo(t+2); counted boundary wait ----
        {
            int r = wrow + 48 + rl;
            int off = r * 32 + ((g ^ (r & 3)) << 3);
            bf16x8 ah = *(const bf16x8*)(sb + off);
            bf16x8 al = *(const bf16x8*)(sb + 8192 + off);
            if (st) gl_lds16(Blo + bSrc + k2, ub + 20480 + bDst);
            asm volatile("s_waitcnt lgkmcnt(0)" ::: "memory");
            __builtin_amdgcn_sched_barrier(0);
            __builtin_amdgcn_s_setprio(1);
#pragma unroll
            for (int n = 0; n < 4; ++n)
                acc[3][n] = __builtin_amdgcn_mfma_f32_16x16x32_bf16(ah, bhf[n], acc[3][n], 0, 0, 0);
#pragma unroll
            for (int n = 0; n < 4; ++n)
                acc[3][n] = __builtin_amdgcn_mfma_f32_16x16x32_bf16(ah, blf[n], acc[3][n], 0, 0, 0);
#pragma unroll
            for (int n = 0; n < 4; ++n)
                acc[3][n] = __builtin_amdgcn_mfma_f32_16x16x32_bf16(al, bhf[n], acc[3][n], 0, 0, 0);
            __builtin_amdgcn_s_setprio(0);
        }
        if (tt < 31) {
            if (st) asm volatile("s_waitcnt vmcnt(6)" ::: "memory");
            else    asm volatile("s_waitcnt vmcnt(0)" ::: "memory");
            __builtin_amdgcn_s_barrier();
            __builtin_amdgcn_sched_barrier(0);
        }
    }
#undef STAGE_FULL

    float bv[4];
#pragma unroll
    for (int n = 0; n < 4; ++n) bv[n] = bias[col0 + wcol + n * 16 + rl];

    if (MODE <= 1) {
        // plain epilogue: direct stores from acc registers
#pragma unroll
        for (int m = 0; m < 4; ++m) {
            int rbase = row0 + wrow + m * 16 + g * 4;
#pragma unroll
            for (int n = 0; n < 4; ++n) {
                int c = col0 + wcol + n * 16 + rl;
#pragma unroll
                for (int q = 0; q < 4; ++q) {
                    int r = rbase + q;
                    float v = acc[m][n][q] + bv[n];
                    long off;
                    if (MODE == 0) off = (long)r * E_ + c;
                    else { int b = r >> 12, nn = r & (N_ - 1); off = (long)(nn * B_ + b) * E_ + c; }
                    Y[off] = v;
                }
            }
        }
        return;
    }

    // ---------------- fused favorp epilogue (MODE 2 / 3) ----------------
    __syncthreads();   // all waves done with staging LDS; overlay accF
    float* accF  = (float*)SMEM8 + w * (64 * 68);              // wave-private [64][68]
    float* diagL = (float*)(SMEM8 + 139264) + w * 64;
    float* rnmL  = (float*)(SMEM8 + 139264 + 2048) + w * 64;
    const int b_idx = row0 >> 12;
    const int hg = (col0 >> 6) + (w & 1);                      // global head 0..15
    const int bh_i = b_idx * H_ + hg;

    // hoisted PS fragment loads — band-invariant
    bf16x8 pbh[8], pbl[8];
#pragma unroll
    for (int n = 0; n < 4; ++n)
#pragma unroll
        for (int kk = 0; kk < 2; ++kk) {
            long po = (long)hg * 4096 + (n*16 + rl) * 64 + kk*32 + g*8;
            pbh[n*2+kk] = *(const bf16x8*)(PShi + po);
            pbl[n*2+kk] = *(const bf16x8*)(PSlo + po);
        }

#pragma unroll
    for (int m = 0; m < 4; ++m)
#pragma unroll
        for (int n = 0; n < 4; ++n)
#pragma unroll
            for (int q = 0; q < 4; ++q)
                accF[(m*16 + g*4 + q) * 68 + n*16 + rl] = acc[m][n][q] + bv[n];
    {
        float s = 0.f;
#pragma unroll 16
        for (int d = 0; d < 64; ++d) { float x = accF[lane * 68 + d]; s = fmaf(x, x, s); }
        diagL[lane] = s * DIAG_C;
    }
    __syncthreads();

    float wavemax = -INFINITY;
#pragma unroll
    for (int mi = 0; mi < 4; ++mi) {
        bf16x8 dah[2], dal[2];
#pragma unroll
        for (int kk = 0; kk < 2; ++kk) {
            const float* src = &accF[(mi*16 + rl) * 68 + kk*32 + g*8];
            float4 f0 = *(const float4*)src, f1 = *(const float4*)(src + 4);
            f32x8_split(f0, f1, dah[kk], dal[kk]);
        }
        f32x4 dacc[4];
#pragma unroll
        for (int n = 0; n < 4; ++n) dacc[n] = (f32x4){0.f,0.f,0.f,0.f};
#pragma unroll
        for (int n = 0; n < 4; ++n)
#pragma unroll
            for (int kk = 0; kk < 2; ++kk) {
                dacc[n] = __builtin_amdgcn_mfma_f32_16x16x32_bf16(dah[kk], pbh[n*2+kk], dacc[n], 0, 0, 0);
                dacc[n] = __builtin_amdgcn_mfma_f32_16x16x32_bf16(dah[kk], pbl[n*2+kk], dacc[n], 0, 0, 0);
                dacc[n] = __builtin_amdgcn_mfma_f32_16x16x32_bf16(dal[kk], pbh[n*2+kk], dacc[n], 0, 0, 0);
            }
        if (MODE == 2) {
#pragma unroll
            for (int n = 0; n < 4; ++n)
#pragma unroll
                for (int q = 0; q < 4; ++q) {
                    float dsh = dacc[n][q] * NRM_C;
                    wavemax = fmaxf(wavemax, dsh);
                    int rloc = mi*16 + g*4 + q;
                    accF[rloc * 68 + n*16 + rl] = dsh - diagL[rloc];
                }
        } else {
            float rm0 = -INFINITY, rm1 = -INFINITY, rm2 = -INFINITY, rm3 = -INFINITY;
#pragma unroll
            for (int n = 0; n < 4; ++n) {
                rm0 = fmaxf(rm0, dacc[n][0]); rm1 = fmaxf(rm1, dacc[n][1]);
                rm2 = fmaxf(rm2, dacc[n][2]); rm3 = fmaxf(rm3, dacc[n][3]);
            }
#pragma unroll
            for (int off = 1; off < 16; off <<= 1) {
                rm0 = fmaxf(rm0, __shfl_xor(rm0, off));
                rm1 = fmaxf(rm1, __shfl_xor(rm1, off));
                rm2 = fmaxf(rm2, __shfl_xor(rm2, off));
                rm3 = fmaxf(rm3, __shfl_xor(rm3, off));
            }
            float rmq[4] = {rm0 * NRM_C, rm1 * NRM_C, rm2 * NRM_C, rm3 * NRM_C};
#pragma unroll
            for (int n = 0; n < 4; ++n)
#pragma unroll
                for (int q = 0; q < 4; ++q) {
                    int rloc = mi*16 + g*4 + q;
                    float qp = RATIO_C * expf(dacc[n][q] * NRM_C - diagL[rloc] - rmq[q]) + EPSF;
                    accF[rloc * 68 + n*16 + rl] = qp;
                }
        }
    }

    if (MODE == 2) {
#pragma unroll
        for (int off = 1; off < 64; off <<= 1) wavemax = fmaxf(wavemax, __shfl_xor(wavemax, off));
        if (lane == 0) atomicMaxF(&stab[bh_i], wavemax);
#pragma unroll
        for (int pass = 0; pass < 8; ++pass) {
            int rloc = pass * 8 + lr8;
            const float* sp = &accF[rloc * 68 + lc8 * 8];
            float4 f0 = *(const float4*)sp;
            float4 f1 = *(const float4*)(sp + 4);
            long off = (long)(row0 + wrow + rloc) * E_ + col0 + wcol + lc8 * 8;
            *(float4*)(Y + off) = f0;
            *(float4*)(Y + off + 4) = f1;
        }
        return;
    }

    // MODE 3: normalizer, then qkv via MFMA against kvT
    {
        float s = 0.f;
        const float* kb = ksum + bh_i * 64;
#pragma unroll 16
        for (int m = 0; m < 64; ++m) s = fmaf(accF[lane * 68 + m], kb[m], s);
        rnmL[lane] = 1.f / fmaxf(s, EPSD);
    }
    bf16x8 kbh[8], kbl[8];
#pragma unroll
    for (int n = 0; n < 4; ++n)
#pragma unroll
        for (int kk = 0; kk < 2; ++kk) {
            long ko = (long)bh_i * 4096 + (n*16 + rl) * 64 + kk*32 + g*8;
            kbh[n*2+kk] = *(const bf16x8*)(kvThi + ko);
            kbl[n*2+kk] = *(const bf16x8*)(kvTlo + ko);
        }
    __syncthreads();
#pragma unroll
    for (int mi = 0; mi < 4; ++mi) {
        bf16x8 qah[2], qal[2];
#pragma unroll
        for (int kk = 0; kk < 2; ++kk) {
            const float* src = &accF[(mi*16 + rl) * 68 + kk*32 + g*8];
            float4 f0 = *(const float4*)src, f1 = *(const float4*)(src + 4);
            f32x8_split(f0, f1, qah[kk], qal[kk]);
        }
        f32x4 oacc[4];
#pragma unroll
        for (int n = 0; n < 4; ++n) oacc[n] = (f32x4){0.f,0.f,0.f,0.f};
#pragma unroll
        for (int n = 0; n < 4; ++n)
#pragma unroll
            for (int kk = 0; kk < 2; ++kk) {
                oacc[n] = __builtin_amdgcn_mfma_f32_16x16x32_bf16(qah[kk], kbh[n*2+kk], oacc[n], 0, 0, 0);
                oacc[n] = __builtin_amdgcn_mfma_f32_16x16x32_bf16(qah[kk], kbl[n*2+kk], oacc[n], 0, 0, 0);
                oacc[n] = __builtin_amdgcn_mfma_f32_16x16x32_bf16(qal[kk], kbh[n*2+kk], oacc[n], 0, 0, 0);
            }
#pragma unroll
        for (int n = 0; n < 4; ++n)
#pragma unroll
            for (int q = 0; q < 4; ++q) {
                int rloc = mi*16 + g*4 + q;
                accF[rloc * 68 + n*16 + rl] = oacc[n][q] * rnmL[rloc];
            }
    }
#pragma unroll
    for (int pass = 0; pass < 8; ++pass) {
        int rloc = pass * 8 + lr8;
        const float* sp = &accF[rloc * 68 + lc8 * 8];
        float4 f0 = *(const float4*)sp;
        float4 f1 = *(const float4*)(sp + 4);
        float v[8] = {f0.x,f0.y,f0.z,f0.w,f1.x,f1.y,f1.z,f1.w};
        unsigned int hu[4], lu[4];
#pragma unroll
        for (int j = 0; j < 4; ++j) {
            hu[j] = pk_bf16(v[2*j], v[2*j+1]);
            float ea = __uint_as_float(hu[j] << 16);
            float eb = __uint_as_float(hu[j] & 0xffff0000u);
            lu[j] = pk_bf16(v[2*j] - ea, v[2*j+1] - eb);
        }
        long off = (long)(row0 + wrow + rloc) * E_ + col0 + wcol + lc8 * 8;
        uint4 hv = {hu[0], hu[1], hu[2], hu[3]};
        uint4 lv = {lu[0], lu[1], lu[2], lu[3]};
        *(uint4*)(AttnHi + off) = hv;
        *(uint4*)(AttnLo + off) = lv;
    }
}

// ---------------- fp32 fallback GEMM (round-2 proven) ----------------
template<int IN_MODE, int OUT_MODE>
__global__ __launch_bounds__(256) void lin_gemm(const float* __restrict__ X,
                                                const float* __restrict__ W,
                                                const float* __restrict__ bias,
                                                float* __restrict__ Y)
{
    __shared__ float As[16][68];
    __shared__ float Ws[16][68];
    const int row0 = blockIdx.x * 64;
    const int col0 = blockIdx.y * 64;
    const int t  = threadIdx.x;
    const int lr = t >> 2;
    const int lk = (t & 3) * 4;
    const int ty = t >> 4, tx = t & 15;

    long arow;
    {
        int r = row0 + lr;
        if (IN_MODE == 0) { int b = r >> 12, n = r & (N_ - 1); arow = (long)(n * B_ + b) * E_; }
        else              { arow = (long)r * E_; }
    }
    const long wrow = (long)(col0 + lr) * E_;

    float acc[4][4] = {};
    for (int e0 = 0; e0 < E_; e0 += 16) {
        float4 av = *(const float4*)(X + arow + e0 + lk);
        float4 wv = *(const float4*)(W + wrow + e0 + lk);
        As[lk+0][lr] = av.x; As[lk+1][lr] = av.y; As[lk+2][lr] = av.z; As[lk+3][lr] = av.w;
        Ws[lk+0][lr] = wv.x; Ws[lk+1][lr] = wv.y; Ws[lk+2][lr] = wv.z; Ws[lk+3][lr] = wv.w;
        __syncthreads();
#pragma unroll
        for (int k = 0; k < 16; ++k) {
            float4 a = *(const float4*)&As[k][ty*4];
            float4 w = *(const float4*)&Ws[k][tx*4];
            float a_[4] = {a.x,a.y,a.z,a.w};
            float w_[4] = {w.x,w.y,w.z,w.w};
#pragma unroll
            for (int i = 0; i < 4; ++i)
#pragma unroll
                for (int j = 0; j < 4; ++j)
                    acc[i][j] = fmaf(a_[i], w_[j], acc[i][j]);
        }
        __syncthreads();
    }
    float4 bvv = *(const float4*)(bias + col0 + tx*4);
    float b_[4] = {bvv.x,bvv.y,bvv.z,bvv.w};
#pragma unroll
    for (int i = 0; i < 4; ++i) {
        int r = row0 + ty*4 + i;
        float4 o;
        o.x = acc[i][0] + b_[0]; o.y = acc[i][1] + b_[1];
        o.z = acc[i][2] + b_[2]; o.w = acc[i][3] + b_[3];
        long off;
        if (OUT_MODE == 0) off = (long)r * E_ + col0 + tx*4;
        else { int b = r >> 12, n = r & (N_ - 1); off = (long)(n * B_ + b) * E_ + col0 + tx*4; }
        *(float4*)(Y + off) = o;
    }
}

// ---------------- favorp dash (fallback, IN-PLACE over [B,N,E]) ----------------
template<int IS_QUERY>
__global__ __launch_bounds__(256) void favorp_dash(float* __restrict__ Xh,
                                                   const float* __restrict__ proj,
                                                   float* __restrict__ stab)
{
    __shared__ float Xs[64][68];
    __shared__ float Ps[64][68];
    __shared__ float diag[64];
    __shared__ float red4[4];
    __shared__ float rowred[64][17];
    const int bh = blockIdx.x, b = bh >> 4, h = bh & 15;
    const int n0 = blockIdx.y * 64;
    const int t = threadIdx.x;
    const int r = t >> 2, c0 = (t & 3) * 16;
    const int ty = t >> 4, tx = t & 15;

    const float* xrow = Xh + (long)(b * N_ + n0 + r) * E_ + h * 64;
    const float* prow = proj + (long)(h * 64 + r) * 64;
#pragma unroll
    for (int c = 0; c < 4; ++c) {
        float4 v = *(const float4*)(xrow + c0 + c*4);
        Xs[c0+c*4+0][r] = v.x; Xs[c0+c*4+1][r] = v.y; Xs[c0+c*4+2][r] = v.z; Xs[c0+c*4+3][r] = v.w;
        float4 p = *(const float4*)(prow + c0 + c*4);
        Ps[c0+c*4+0][r] = p.x; Ps[c0+c*4+1][r] = p.y; Ps[c0+c*4+2][r] = p.z; Ps[c0+c*4+3][r] = p.w;
    }
    __syncthreads();
    if (t < 64) {
        float s = 0.f;
#pragma unroll 16
        for (int d = 0; d < 64; ++d) { float x = Xs[d][t]; s = fmaf(x, x, s); }
        diag[t] = s * DIAG_C;
    }
    __syncthreads();

    float acc[4][4] = {};
#pragma unroll 16
    for (int d = 0; d < 64; ++d) {
        float4 a = *(const float4*)&Xs[d][ty*4];
        float4 p = *(const float4*)&Ps[d][tx*4];
        float a_[4] = {a.x,a.y,a.z,a.w};
        float p_[4] = {p.x,p.y,p.z,p.w};
#pragma unroll
        for (int i = 0; i < 4; ++i)
#pragma unroll
            for (int j = 0; j < 4; ++j)
                acc[i][j] = fmaf(a_[i], p_[j], acc[i][j]);
    }
    float dash[4][4];
#pragma unroll
    for (int i = 0; i < 4; ++i)
#pragma unroll
        for (int j = 0; j < 4; ++j) dash[i][j] = acc[i][j] * NRM_C;

    if (IS_QUERY) {
#pragma unroll
        for (int i = 0; i < 4; ++i) {
            float m = fmaxf(fmaxf(dash[i][0], dash[i][1]), fmaxf(dash[i][2], dash[i][3]));
            rowred[ty*4+i][tx] = m;
        }
        __syncthreads();
#pragma unroll
        for (int i = 0; i < 4; ++i) {
            int row = ty*4 + i;
            float m = rowred[row][0];
#pragma unroll
            for (int jj = 1; jj < 16; ++jj) m = fmaxf(m, rowred[row][jj]);
            float dg = diag[row];
            float4 o;
            o.x = RATIO_C * expf(dash[i][0] - dg - m) + EPSF;
            o.y = RATIO_C * expf(dash[i][1] - dg - m) + EPSF;
            o.z = RATIO_C * expf(dash[i][2] - dg - m) + EPSF;
            o.w = RATIO_C * expf(dash[i][3] - dg - m) + EPSF;
            *(float4*)(Xh + (long)(b * N_ + n0 + row) * E_ + h * 64 + tx*4) = o;
        }
    } else {
        float lmax = dash[0][0];
#pragma unroll
        for (int i = 0; i < 4; ++i)
#pragma unroll
            for (int j = 0; j < 4; ++j) lmax = fmaxf(lmax, dash[i][j]);
#pragma unroll
        for (int i = 0; i < 4; ++i) {
            int row = ty*4 + i;
            float dg = diag[row];
            float4 o = { dash[i][0]-dg, dash[i][1]-dg, dash[i][2]-dg, dash[i][3]-dg };
            *(float4*)(Xh + (long)(b * N_ + n0 + row) * E_ + h * 64 + tx*4) = o;
        }
#pragma unroll
        for (int off = 32; off > 0; off >>= 1) lmax = fmaxf(lmax, __shfl_down(lmax, off));
        if ((t & 63) == 0) red4[t >> 6] = lmax;
        __syncthreads();
        if (t == 0)
            atomicMaxF(&stab[bh], fmaxf(fmaxf(red4[0], red4[1]), fmaxf(red4[2], red4[3])));
    }
}

// ---------------- kv partials ----------------
__global__ __launch_bounds__(256) void kv_partial(const float* __restrict__ T1,
                                                  const float* __restrict__ V,
                                                  const float* __restrict__ stab,
                                                  float* __restrict__ kvp,
                                                  float* __restrict__ ksump)
{
    __shared__ float KPs[16][68];
    __shared__ float Vs[16][68];
    const int bh = blockIdx.x, chunk = blockIdx.y;
    const int b = bh >> 4, h = bh & 15;
    const int t = threadIdx.x;
    const int lr = t >> 4, lm = (t & 15) * 4;
    const int ty = t >> 4, tx = t & 15;
    const float stb = stab[bh];
    float acc[4][4] = {};
    float ks = 0.f;
    const int nbeg = chunk * (N_ / SPLITK), nend = nbeg + (N_ / SPLITK);
    for (int n0 = nbeg; n0 < nend; n0 += 16) {
        long rowoff = (long)(b * N_ + n0 + lr) * E_ + h * 64 + lm;
        float4 tv = *(const float4*)(T1 + rowoff);
        float4 vv = *(const float4*)(V + rowoff);
        KPs[lr][lm+0] = RATIO_C * expf(tv.x - stb) + EPSF;
        KPs[lr][lm+1] = RATIO_C * expf(tv.y - stb) + EPSF;
        KPs[lr][lm+2] = RATIO_C * expf(tv.z - stb) + EPSF;
        KPs[lr][lm+3] = RATIO_C * expf(tv.w - stb) + EPSF;
        *(float4*)&Vs[lr][lm] = vv;
        __syncthreads();
        if (t < 64) {
#pragma unroll
            for (int rr = 0; rr < 16; ++rr) ks += KPs[rr][t];
        }
#pragma unroll
        for (int k = 0; k < 16; ++k) {
            float4 a = *(const float4*)&KPs[k][ty*4];
            float4 v4 = *(const float4*)&Vs[k][tx*4];
            float a_[4] = {a.x,a.y,a.z,a.w};
            float v_[4] = {v4.x,v4.y,v4.z,v4.w};
#pragma unroll
            for (int i = 0; i < 4; ++i)
#pragma unroll
                for (int j = 0; j < 4; ++j)
                    acc[i][j] = fmaf(a_[i], v_[j], acc[i][j]);
        }
        __syncthreads();
    }
    const long kvbase = ((long)chunk * BH_ + bh) * 4096;
#pragma unroll
    for (int i = 0; i < 4; ++i) {
        float4 o = {acc[i][0], acc[i][1], acc[i][2], acc[i][3]};
        *(float4*)(kvp + kvbase + (ty*4+i) * 64 + tx*4) = o;
    }
    if (t < 64) ksump[((long)chunk * BH_ + bh) * 64 + t] = ks;
}

// reduce partials; write kv TRANSPOSED split-bf16 [BH][d][m] + ksum fp32 (+kvM fp32 for fallback)
__global__ __launch_bounds__(256) void kv_reduce(const float* __restrict__ kvp,
                                                 const float* __restrict__ ksump,
                                                 float* __restrict__ kvM,
                                                 float* __restrict__ ksum,
                                                 unsigned short* __restrict__ kvThi,
                                                 unsigned short* __restrict__ kvTlo)
{
    int idx = blockIdx.x * 256 + threadIdx.x;
    if (idx < BH_ * 4096) {
        float s = 0.f;
#pragma unroll
        for (int c = 0; c < SPLITK; ++c) s += kvp[(long)c * BH_ * 4096 + idx];
        kvM[idx] = s;
        int bh = idx >> 12, md = idx & 4095, m = md >> 6, d = md & 63;
        unsigned short h16 = f32_to_bf16(s);
        long toff = (long)bh * 4096 + d * 64 + m;
        kvThi[toff] = h16;
        kvTlo[toff] = f32_to_bf16(s - bf16_to_f32(h16));
    } else {
        int j = idx - BH_ * 4096;
        if (j < BH_ * 64) {
            float s = 0.f;
#pragma unroll
            for (int c = 0; c < SPLITK; ++c) s += ksump[(long)c * BH_ * 64 + j];
            ksum[j] = s;
        }
    }
}

// ---------------- qkv + normalize (fallback only) ----------------
__global__ __launch_bounds__(256) void qkv_attn(const float* __restrict__ Qp,
                                                const float* __restrict__ kvM,
                                                const float* __restrict__ ksum,
                                                float* __restrict__ attn)
{
    __shared__ float QPs[64][68];
    __shared__ float kvs[64][68];
    __shared__ float ksums[64];
    __shared__ float rnorm[64];
    const int bh = blockIdx.x, b = bh >> 4, h = bh & 15;
    const int n0 = blockIdx.y * 64;
    const int t = threadIdx.x;
    const int r = t >> 2, c0 = (t & 3) * 16;
    const int ty = t >> 4, tx = t & 15;

#pragma unroll
    for (int c = 0; c < 4; ++c) {
        int idx = t * 16 + c * 4;
        float4 v = *(const float4*)(kvM + (long)bh * 4096 + idx);
        *(float4*)&kvs[idx >> 6][idx & 63] = v;
    }
    if (t < 64) ksums[t] = ksum[bh * 64 + t];
    const float* qrow = Qp + (long)(b * N_ + n0 + r) * E_ + h * 64;
#pragma unroll
    for (int c = 0; c < 4; ++c) {
        float4 v = *(const float4*)(qrow + c0 + c*4);
        QPs[c0+c*4+0][r] = v.x; QPs[c0+c*4+1][r] = v.y; QPs[c0+c*4+2][r] = v.z; QPs[c0+c*4+3][r] = v.w;
    }
    __syncthreads();
    if (t < 64) {
        float s = 0.f;
#pragma unroll 16
        for (int m = 0; m < 64; ++m) s = fmaf(QPs[m][t], ksums[m], s);
        rnorm[t] = 1.f / fmaxf(s, EPSD);
    }
    __syncthreads();
    float acc[4][4] = {};
#pragma unroll 16
    for (int m = 0; m < 64; ++m) {
        float4 a = *(const float4*)&QPs[m][ty*4];
        float4 v4 = *(const float4*)&kvs[m][tx*4];
        float a_[4] = {a.x,a.y,a.z,a.w};
        float v_[4] = {v4.x,v4.y,v4.z,v4.w};
#pragma unroll
        for (int i = 0; i < 4; ++i)
#pragma unroll
            for (int j = 0; j < 4; ++j)
                acc[i][j] = fmaf(a_[i], v_[j], acc[i][j]);
    }
#pragma unroll
    for (int i = 0; i < 4; ++i) {
        int row = ty*4 + i;
        float rn = rnorm[row];
        float4 o = {acc[i][0]*rn, acc[i][1]*rn, acc[i][2]*rn, acc[i][3]*rn};
        *(float4*)(attn + (long)(b * N_ + n0 + row) * E_ + h * 64 + tx*4) = o;
    }
}

extern "C" void kernel_launch(void* const* d_in, const int* in_sizes, int n_in,
                              void* d_out, int out_size, void* d_ws, size_t ws_size,
                              hipStream_t stream)
{
    const float* query = (const float*)d_in[0];
    const float* key   = (const float*)d_in[1];
    const float* value = (const float*)d_in[2];
    const float* Wq    = (const float*)d_in[3];
    const float* bq    = (const float*)d_in[4];
    const float* Wk    = (const float*)d_in[5];
    const float* bk    = (const float*)d_in[6];
    const float* Wv    = (const float*)d_in[7];
    const float* bv    = (const float*)d_in[8];
    const float* Wo    = (const float*)d_in[9];
    const float* bo    = (const float*)d_in[10];
    const float* proj  = (const float*)d_in[11];
    float* O = (float*)d_out;                 // scratch; fully rewritten by final GEMM

    float* ws = (float*)d_ws;
    const size_t SZ = (size_t)BN_ * E_;       // 16.78M floats
    float* A     = ws;                        // V fp32; later attn (split-bf16 in fast path)
    float* kvp   = ws + SZ;
    float* ksump = kvp + (size_t)SPLITK * BH_ * 4096;
    float* kvM   = ksump + (size_t)SPLITK * BH_ * 64;
    float* ksum  = kvM + (size_t)BH_ * 4096;
    float* stab  = ksum + (size_t)BH_ * 64;
    unsigned short* kvThi = (unsigned short*)(stab + 64);            // BH*4096 ush
    unsigned short* kvTlo = kvThi + (size_t)BH_ * 4096;
    unsigned short* PShi  = kvTlo + (size_t)BH_ * 4096;              // 65536 ush
    unsigned short* PSlo  = PShi + 65536;
    const size_t EXTRA_F = (size_t)BH_ * 4096 /*kvT pair*/ + 65536 /*PS pair*/;
    const size_t COMMON_F = SZ + (size_t)SPLITK * BH_ * 4096 + (size_t)SPLITK * BH_ * 64
                          + (size_t)BH_ * 4096 + (size_t)BH_ * 64 + 64 + EXTRA_F;
    unsigned short* Xhi = (unsigned short*)(ws + COMMON_F);
    unsigned short* Xlo = Xhi + SZ;
    unsigned short* Whi = Xlo + SZ;
    unsigned short* Wlo = Whi + (size_t)E_ * E_;
    const size_t NEED_FAST = (COMMON_F + SZ + (size_t)E_ * E_) * 4;  // bytes

    dim3 gF(BH_, N_ / 64);
    dim3 gKV(BH_, SPLITK);
    const int nRed = (BH_ * 4096 + BH_ * 64) / 256;

    if (ws_size >= NEED_FAST) {
        dim3 gP(BN_ / 256, E_ / 128);    // pipelined GEMM, all modes
        const int X4 = (int)(SZ / 4), W4 = (E_ * E_) / 4;
        unsigned short* AttnHi = (unsigned short*)A;
        unsigned short* AttnLo = AttnHi + SZ;

        (void)hipFuncSetAttribute((const void*)&gemm8p<0>, hipFuncAttributeMaxDynamicSharedMemorySize, SMEM_DYN8);
        (void)hipFuncSetAttribute((const void*)&gemm8p<1>, hipFuncAttributeMaxDynamicSharedMemorySize, SMEM_DYN8);
        (void)hipFuncSetAttribute((const void*)&gemm8p<2>, hipFuncAttributeMaxDynamicSharedMemorySize, SMEM_DYN8);
        (void)hipFuncSetAttribute((const void*)&gemm8p<3>, hipFuncAttributeMaxDynamicSharedMemorySize, SMEM_DYN8);

        convert_split<1><<<64, 256, 0, stream>>>(proj, PShi, PSlo, 16384);
        init_stab<<<1, 64, 0, stream>>>(stab);
        // K chain: pipelined GEMM + fused favorp_k -> T1 (O) + stab
        convert_split<0><<<2048, 256, 0, stream>>>(key, Xhi, Xlo, X4);
        convert_split<1><<<1024, 256, 0, stream>>>(Wk, Whi, Wlo, W4);
        gemm8p<2><<<gP, 512, SMEM_DYN8, stream>>>(Xhi, Xlo, Whi, Wlo, bk, O, stab,
                                                  PShi, PSlo, nullptr, nullptr, nullptr, nullptr, nullptr);
        // V chain
        convert_split<0><<<2048, 256, 0, stream>>>(value, Xhi, Xlo, X4);
        convert_split<1><<<1024, 256, 0, stream>>>(Wv, Whi, Wlo, W4);
        gemm8p<0><<<gP, 512, SMEM_DYN8, stream>>>(Xhi, Xlo, Whi, Wlo, bv, A, nullptr,
                                                  nullptr, nullptr, nullptr, nullptr, nullptr, nullptr, nullptr);
        // kv
        kv_partial<<<gKV, 256, 0, stream>>>(O, A, stab, kvp, ksump);
        kv_reduce<<<nRed, 256, 0, stream>>>(kvp, ksump, kvM, ksum, kvThi, kvTlo);
        // Q chain: pipelined GEMM + fused favorp_q + qkv -> attn split-bf16 (A region)
        convert_split<0><<<2048, 256, 0, stream>>>(query, Xhi, Xlo, X4);
        convert_split<1><<<1024, 256, 0, stream>>>(Wq, Whi, Wlo, W4);
        gemm8p<3><<<gP, 512, SMEM_DYN8, stream>>>(Xhi, Xlo, Whi, Wlo, bq, nullptr, nullptr,
                                                  PShi, PSlo, kvThi, kvTlo, ksum, AttnHi, AttnLo);
        // output GEMM (transposed store)
        convert_split<1><<<1024, 256, 0, stream>>>(Wo, Whi, Wlo, W4);
        gemm8p<1><<<gP, 512, SMEM_DYN8, stream>>>(AttnHi, AttnLo, Whi, Wlo, bo, O, nullptr,
                                                  nullptr, nullptr, nullptr, nullptr, nullptr, nullptr, nullptr);
    } else {
        // fp32 fallback (round-2 proven path)
        dim3 gGemm(BN_ / 64, E_ / 64);
        lin_gemm<0,0><<<gGemm, 256, 0, stream>>>(key, Wk, bk, O);
        init_stab<<<1, 64, 0, stream>>>(stab);
        favorp_dash<0><<<gF, 256, 0, stream>>>(O, proj, stab);
        lin_gemm<0,0><<<gGemm, 256, 0, stream>>>(value, Wv, bv, A);
        kv_partial<<<gKV, 256, 0, stream>>>(O, A, stab, kvp, ksump);
        kv_reduce<<<nRed, 256, 0, stream>>>(kvp, ksump, kvM, ksum, kvThi, kvTlo);
        lin_gemm<0,0><<<gGemm, 256, 0, stream>>>(query, Wq, bq, O);
        favorp_dash<1><<<gF, 256, 0, stream>>>(O, proj, stab);
        qkv_attn<<<gF, 256, 0, stream>>>(O, kvM, ksum, A);
        lin_gemm<1,1><<<gGemm, 256, 0, stream>>>(A, Wo, bo, O);
    }
}

// Round 14
// 566.611 us; speedup vs baseline: 1.0295x; 1.0295x over previous
//
#include <hip/hip_runtime.h>
#include <math.h>

// Problem constants (fixed by setup_inputs)
#define B_   4
#define N_   4096
#define E_   1024
#define H_   16
#define BN_  (B_*N_)
#define BH_  (B_*H_)
#define SPLITK 8

// favorp constants
#define NRM_C   0.35355339059327373f   // 64^-0.25
#define DIAG_C  0.0625f                // 0.5 * NRM^2
#define RATIO_C 0.125f                 // 64^-0.5
#define EPSF    1e-4f
#define EPSD    0.01f

typedef __attribute__((ext_vector_type(8))) short bf16x8;   // 8 bf16 in 4 VGPRs
typedef __attribute__((ext_vector_type(4))) float f32x4;

__device__ __forceinline__ unsigned short f32_to_bf16(float x) {
    unsigned int u = __float_as_uint(x);
    unsigned int r = (u + 0x7fffu + ((u >> 16) & 1u)) >> 16;   // RTN-even
    return (unsigned short)r;
}
__device__ __forceinline__ float bf16_to_f32(unsigned short h) {
    return __uint_as_float(((unsigned int)h) << 16);
}

// packed f32->bf16 via HW instruction; D.lo=bf16(a), D.hi=bf16(b)
__device__ __forceinline__ unsigned int pk_bf16(float a, float b) {
    unsigned int r;
    asm("v_cvt_pk_bf16_f32 %0, %1, %2" : "=v"(r) : "v"(a), "v"(b));
    return r;
}

// 8 fp32 -> split bf16 hi/lo fragments (pk-based)
__device__ __forceinline__ void f32x8_split(float4 fa, float4 fb, bf16x8& hi, bf16x8& lo) {
    unsigned int h0 = pk_bf16(fa.x, fa.y), h1 = pk_bf16(fa.z, fa.w);
    unsigned int h2 = pk_bf16(fb.x, fb.y), h3 = pk_bf16(fb.z, fb.w);
    float e0 = __uint_as_float(h0 << 16), e1 = __uint_as_float(h0 & 0xffff0000u);
    float e2 = __uint_as_float(h1 << 16), e3 = __uint_as_float(h1 & 0xffff0000u);
    float e4 = __uint_as_float(h2 << 16), e5 = __uint_as_float(h2 & 0xffff0000u);
    float e6 = __uint_as_float(h3 << 16), e7 = __uint_as_float(h3 & 0xffff0000u);
    unsigned int l0 = pk_bf16(fa.x - e0, fa.y - e1), l1 = pk_bf16(fa.z - e2, fa.w - e3);
    unsigned int l2 = pk_bf16(fb.x - e4, fb.y - e5), l3 = pk_bf16(fb.z - e6, fb.w - e7);
    union { unsigned int u[4]; bf16x8 v; } H, L;
    H.u[0] = h0; H.u[1] = h1; H.u[2] = h2; H.u[3] = h3;
    L.u[0] = l0; L.u[1] = l1; L.u[2] = l2; L.u[3] = l3;
    hi = H.v; lo = L.v;
}

__device__ __forceinline__ void atomicMaxF(float* addr, float v) {
    if (v >= 0.f) atomicMax((int*)addr, __float_as_int(v));
    else          atomicMin((unsigned int*)addr, __float_as_uint(v));
}

__global__ void init_stab(float* stab) {
    if (threadIdx.x < BH_) stab[threadIdx.x] = -INFINITY;
}

// ---------------- split-bf16 conversion ----------------
template<int IN_MODE>
__global__ __launch_bounds__(256) void convert_split(const float* __restrict__ src,
                                                     unsigned short* __restrict__ hi,
                                                     unsigned short* __restrict__ lo,
                                                     int total4)
{
    int i = blockIdx.x * 256 + threadIdx.x;
    const int stride = gridDim.x * 256;
    for (; i < total4; i += stride) {
        long e4 = (long)i * 4;
        const float* p;
        if (IN_MODE == 0) {
            long r = e4 >> 10; int e = (int)(e4 & 1023);
            int b = (int)(r >> 12), n = (int)(r & 4095);
            p = src + (((long)(n * B_ + b)) << 10) + e;
        } else {
            p = src + e4;
        }
        float4 v = *(const float4*)p;
        ushort4 h, l;
        h.x = f32_to_bf16(v.x); l.x = f32_to_bf16(v.x - bf16_to_f32(h.x));
        h.y = f32_to_bf16(v.y); l.y = f32_to_bf16(v.y - bf16_to_f32(h.y));
        h.z = f32_to_bf16(v.z); l.z = f32_to_bf16(v.z - bf16_to_f32(h.z));
        h.w = f32_to_bf16(v.w); l.w = f32_to_bf16(v.w - bf16_to_f32(h.w));
        *(ushort4*)(hi + e4) = h;
        *(ushort4*)(lo + e4) = l;
    }
}

__device__ __forceinline__ void gl_lds16(const unsigned short* g, unsigned short* l) {
    __builtin_amdgcn_global_load_lds((const __attribute__((address_space(1))) void*)g,
                                     (__attribute__((address_space(3))) void*)l, 16, 0, 0);
}

// =====================================================================
// Fine-phase pipelined GEMM, all modes: 256x128 tile, BK=32, 8 waves,
// 3 LDS buffers (144KB), 2-deep prefetch, counted vmcnt(6) at K boundaries.
// Bank-conflict-free fragment swizzle: slot = g ^ ((row>>1)&3)  (2-way = free).
// MODE 0: Y fp32 [BN,E];  MODE 1: Y fp32 [N,B,E] transposed;
// MODE 2: K-fused favorp (T1 + stab);  MODE 3: Q-fused favorp_q + qkv -> attn split-bf16.
// =====================================================================
#define SMEM_DYN8 147456

template<int MODE>
__global__ __launch_bounds__(512, 2) void gemm8p(const unsigned short* __restrict__ Ahi,
                                                 const unsigned short* __restrict__ Alo,
                                                 const unsigned short* __restrict__ Bhi,
                                                 const unsigned short* __restrict__ Blo,
                                                 const float* __restrict__ bias,
                                                 float* __restrict__ Y,
                                                 float* __restrict__ stab,
                                                 const unsigned short* __restrict__ PShi,
                                                 const unsigned short* __restrict__ PSlo,
                                                 const unsigned short* __restrict__ kvThi,
                                                 const unsigned short* __restrict__ kvTlo,
                                                 const float* __restrict__ ksum,
                                                 unsigned short* __restrict__ AttnHi,
                                                 unsigned short* __restrict__ AttnLo)
{
    extern __shared__ char SMEM8[];
    unsigned short* U = (unsigned short*)SMEM8;
    const int t = threadIdx.x;
    const int w = t >> 6, lane = t & 63;
    const int row0 = blockIdx.x * 256, col0 = blockIdx.y * 128;
    const int wrow = (w >> 1) * 64, wcol = (w & 1) * 64;
    const int g = lane >> 4, rl = lane & 15;
    const int lr8 = lane >> 3, lc8 = lane & 7;

    // staging address precompute (granule = 16B = 8 shorts)
    // pre-swizzled source: LDS(row r, slot s) holds global k-octet s ^ ((r>>1)&3)
    int gi0 = t, gi1 = 512 + t;
    int ar0 = gi0 >> 2, as0 = gi0 & 3;
    int ar1 = gi1 >> 2, as1 = gi1 & 3;
    const long aSrc0 = (long)(row0 + ar0) * E_ + ((as0 ^ ((ar0 >> 1) & 3)) << 3);
    const long aSrc1 = (long)(row0 + ar1) * E_ + ((as1 ^ ((ar1 >> 1) & 3)) << 3);
    const int aDst0 = (w * 64) * 8;
    const int aDst1 = (512 + w * 64) * 8;
    const long bSrc = (long)(col0 + (t >> 2)) * E_ + (((t & 3) ^ ((t >> 3) & 3)) << 3);
    const int bDst = (w * 64) * 8;

    f32x4 acc[4][4];
#pragma unroll
    for (int m = 0; m < 4; ++m)
#pragma unroll
        for (int n = 0; n < 4; ++n) acc[m][n] = (f32x4){0.f, 0.f, 0.f, 0.f};

#define STAGE_FULL(TILE, BUFI) {                                        \
        const int k0_ = (TILE) * 32;                                    \
        unsigned short* bu_ = U + (BUFI) * 24576;                       \
        gl_lds16(Ahi + aSrc0 + k0_, bu_ + aDst0);                       \
        gl_lds16(Ahi + aSrc1 + k0_, bu_ + aDst1);                       \
        gl_lds16(Alo + aSrc0 + k0_, bu_ + 8192 + aDst0);                \
        gl_lds16(Alo + aSrc1 + k0_, bu_ + 8192 + aDst1);                \
        gl_lds16(Bhi + bSrc + k0_, bu_ + 16384 + bDst);                 \
        gl_lds16(Blo + bSrc + k0_, bu_ + 20480 + bDst); }

    STAGE_FULL(0, 0);
    STAGE_FULL(1, 1);
    asm volatile("s_waitcnt vmcnt(6)" ::: "memory");   // tile 0 landed (own; FIFO)
    __builtin_amdgcn_s_barrier();                      // all waves' tile 0 landed
    __builtin_amdgcn_sched_barrier(0);

    for (int tt = 0; tt < 32; ++tt) {
        const unsigned short* sb = U + (tt % 3) * 24576;
        unsigned short* ub = U + ((tt + 2) % 3) * 24576;
        const bool st = (tt + 2 < 32);
        const int k2 = (tt + 2) * 32;
        bf16x8 bhf[4], blf[4];

        // ---- phase 0: B frags + A frag m=0; stage Ahi(t+2) ----
#pragma unroll
        for (int n = 0; n < 4; ++n) {
            int r = wcol + n * 16 + rl;
            int off = r * 32 + ((g ^ ((r >> 1) & 3)) << 3);
            bhf[n] = *(const bf16x8*)(sb + 16384 + off);
            blf[n] = *(const bf16x8*)(sb + 20480 + off);
        }
        {
            int r = wrow + rl;
            int off = r * 32 + ((g ^ ((r >> 1) & 3)) << 3);
            bf16x8 ah = *(const bf16x8*)(sb + off);
            bf16x8 al = *(const bf16x8*)(sb + 8192 + off);
            if (st) { gl_lds16(Ahi + aSrc0 + k2, ub + aDst0);
                      gl_lds16(Ahi + aSrc1 + k2, ub + aDst1); }
            asm volatile("s_waitcnt lgkmcnt(0)" ::: "memory");
            __builtin_amdgcn_sched_barrier(0);
            __builtin_amdgcn_s_setprio(1);
#pragma unroll
            for (int n = 0; n < 4; ++n)
                acc[0][n] = __builtin_amdgcn_mfma_f32_16x16x32_bf16(ah, bhf[n], acc[0][n], 0, 0, 0);
#pragma unroll
            for (int n = 0; n < 4; ++n)
                acc[0][n] = __builtin_amdgcn_mfma_f32_16x16x32_bf16(ah, blf[n], acc[0][n], 0, 0, 0);
#pragma unroll
            for (int n = 0; n < 4; ++n)
                acc[0][n] = __builtin_amdgcn_mfma_f32_16x16x32_bf16(al, bhf[n], acc[0][n], 0, 0, 0);
            __builtin_amdgcn_s_setprio(0);
        }
        __builtin_amdgcn_s_barrier();
        __builtin_amdgcn_sched_barrier(0);

        // ---- phase 1: A frag m=1; stage Alo(t+2) ----
        {
            int r = wrow + 16 + rl;
            int off = r * 32 + ((g ^ ((r >> 1) & 3)) << 3);
            bf16x8 ah = *(const bf16x8*)(sb + off);
            bf16x8 al = *(const bf16x8*)(sb + 8192 + off);
            if (st) { gl_lds16(Alo + aSrc0 + k2, ub + 8192 + aDst0);
                      gl_lds16(Alo + aSrc1 + k2, ub + 8192 + aDst1); }
            asm volatile("s_waitcnt lgkmcnt(0)" ::: "memory");
            __builtin_amdgcn_sched_barrier(0);
            __builtin_amdgcn_s_setprio(1);
#pragma unroll
            for (int n = 0; n < 4; ++n)
                acc[1][n] = __builtin_amdgcn_mfma_f32_16x16x32_bf16(ah, bhf[n], acc[1][n], 0, 0, 0);
#pragma unroll
            for (int n = 0; n < 4; ++n)
                acc[1][n] = __builtin_amdgcn_mfma_f32_16x16x32_bf16(ah, blf[n], acc[1][n], 0, 0, 0);
#pragma unroll
            for (int n = 0; n < 4; ++n)
                acc[1][n] = __builtin_amdgcn_mfma_f32_16x16x32_bf16(al, bhf[n], acc[1][n], 0, 0, 0);
            __builtin_amdgcn_s_setprio(0);
        }
        __builtin_amdgcn_s_barrier();
        __builtin_amdgcn_sched_barrier(0);

        // ---- phase 2: A frag m=2; stage Bhi(t+2) ----
        {
            int r = wrow + 32 + rl;
            int off = r * 32 + ((g ^ ((r >> 1) & 3)) << 3);
            bf16x8 ah = *(const bf16x8*)(sb + off);
            bf16x8 al = *(const bf16x8*)(sb + 8192 + off);
            if (st) gl_lds16(Bhi + bSrc + k2, ub + 16384 + bDst);
            asm volatile("s_waitcnt lgkmcnt(0)" ::: "memory");
            __builtin_amdgcn_sched_barrier(0);
            __builtin_amdgcn_s_setprio(1);
#pragma unroll
            for (int n = 0; n < 4; ++n)
                acc[2][n] = __builtin_amdgcn_mfma_f32_16x16x32_bf16(ah, bhf[n], acc[2][n], 0, 0, 0);
#pragma unroll
            for (int n = 0; n < 4; ++n)
                acc[2][n] = __builtin_amdgcn_mfma_f32_16x16x32_bf16(ah, blf[n], acc[2][n], 0, 0, 0);
#pragma unroll
            for (int n = 0; n < 4; ++n)
                acc[2][n] = __builtin_amdgcn_mfma_f32_16x16x32_bf16(al, bhf[n], acc[2][n], 0, 0, 0);
            __builtin_amdgcn_s_setprio(0);
        }
        __builtin_amdgcn_s_barrier();
        __builtin_amdgcn_sched_barrier(0);

        // ---- phase 3: A frag m=3; stage Blo(t+2); counted boundary wait ----
        {
            int r = wrow + 48 + rl;
            int off = r * 32 + ((g ^ ((r >> 1) & 3)) << 3);
            bf16x8 ah = *(const bf16x8*)(sb + off);
            bf16x8 al = *(const bf16x8*)(sb + 8192 + off);
            if (st) gl_lds16(Blo + bSrc + k2, ub + 20480 + bDst);
            asm volatile("s_waitcnt lgkmcnt(0)" ::: "memory");
            __builtin_amdgcn_sched_barrier(0);
            __builtin_amdgcn_s_setprio(1);
#pragma unroll
            for (int n = 0; n < 4; ++n)
                acc[3][n] = __builtin_amdgcn_mfma_f32_16x16x32_bf16(ah, bhf[n], acc[3][n], 0, 0, 0);
#pragma unroll
            for (int n = 0; n < 4; ++n)
                acc[3][n] = __builtin_amdgcn_mfma_f32_16x16x32_bf16(ah, blf[n], acc[3][n], 0, 0, 0);
#pragma unroll
            for (int n = 0; n < 4; ++n)
                acc[3][n] = __builtin_amdgcn_mfma_f32_16x16x32_bf16(al, bhf[n], acc[3][n], 0, 0, 0);
            __builtin_amdgcn_s_setprio(0);
        }
        if (tt < 31) {
            if (st) asm volatile("s_waitcnt vmcnt(6)" ::: "memory");
            else    asm volatile("s_waitcnt vmcnt(0)" ::: "memory");
            __builtin_amdgcn_s_barrier();
            __builtin_amdgcn_sched_barrier(0);
        }
    }
#undef STAGE_FULL

    float bv[4];
#pragma unroll
    for (int n = 0; n < 4; ++n) bv[n] = bias[col0 + wcol + n * 16 + rl];

    if (MODE <= 1) {
        // plain epilogue: direct stores from acc registers
#pragma unroll
        for (int m = 0; m < 4; ++m) {
            int rbase = row0 + wrow + m * 16 + g * 4;
#pragma unroll
            for (int n = 0; n < 4; ++n) {
                int c = col0 + wcol + n * 16 + rl;
#pragma unroll
                for (int q = 0; q < 4; ++q) {
                    int r = rbase + q;
                    float v = acc[m][n][q] + bv[n];
                    long off;
                    if (MODE == 0) off = (long)r * E_ + c;
                    else { int b = r >> 12, nn = r & (N_ - 1); off = (long)(nn * B_ + b) * E_ + c; }
                    Y[off] = v;
                }
            }
        }
        return;
    }

    // ---------------- fused favorp epilogue (MODE 2 / 3) ----------------
    __syncthreads();   // all waves done with staging LDS; overlay accF
    float* accF  = (float*)SMEM8 + w * (64 * 68);              // wave-private [64][68]
    float* diagL = (float*)(SMEM8 + 139264) + w * 64;
    float* rnmL  = (float*)(SMEM8 + 139264 + 2048) + w * 64;
    const int b_idx = row0 >> 12;
    const int hg = (col0 >> 6) + (w & 1);                      // global head 0..15
    const int bh_i = b_idx * H_ + hg;

    // hoisted PS fragment loads — band-invariant
    bf16x8 pbh[8], pbl[8];
#pragma unroll
    for (int n = 0; n < 4; ++n)
#pragma unroll
        for (int kk = 0; kk < 2; ++kk) {
            long po = (long)hg * 4096 + (n*16 + rl) * 64 + kk*32 + g*8;
            pbh[n*2+kk] = *(const bf16x8*)(PShi + po);
            pbl[n*2+kk] = *(const bf16x8*)(PSlo + po);
        }

#pragma unroll
    for (int m = 0; m < 4; ++m)
#pragma unroll
        for (int n = 0; n < 4; ++n)
#pragma unroll
            for (int q = 0; q < 4; ++q)
                accF[(m*16 + g*4 + q) * 68 + n*16 + rl] = acc[m][n][q] + bv[n];
    {
        float s = 0.f;
#pragma unroll 16
        for (int d = 0; d < 64; ++d) { float x = accF[lane * 68 + d]; s = fmaf(x, x, s); }
        diagL[lane] = s * DIAG_C;
    }
    __syncthreads();

    float wavemax = -INFINITY;
#pragma unroll
    for (int mi = 0; mi < 4; ++mi) {
        bf16x8 dah[2], dal[2];
#pragma unroll
        for (int kk = 0; kk < 2; ++kk) {
            const float* src = &accF[(mi*16 + rl) * 68 + kk*32 + g*8];
            float4 f0 = *(const float4*)src, f1 = *(const float4*)(src + 4);
            f32x8_split(f0, f1, dah[kk], dal[kk]);
        }
        f32x4 dacc[4];
#pragma unroll
        for (int n = 0; n < 4; ++n) dacc[n] = (f32x4){0.f,0.f,0.f,0.f};
#pragma unroll
        for (int n = 0; n < 4; ++n)
#pragma unroll
            for (int kk = 0; kk < 2; ++kk) {
                dacc[n] = __builtin_amdgcn_mfma_f32_16x16x32_bf16(dah[kk], pbh[n*2+kk], dacc[n], 0, 0, 0);
                dacc[n] = __builtin_amdgcn_mfma_f32_16x16x32_bf16(dah[kk], pbl[n*2+kk], dacc[n], 0, 0, 0);
                dacc[n] = __builtin_amdgcn_mfma_f32_16x16x32_bf16(dal[kk], pbh[n*2+kk], dacc[n], 0, 0, 0);
            }
        if (MODE == 2) {
#pragma unroll
            for (int n = 0; n < 4; ++n)
#pragma unroll
                for (int q = 0; q < 4; ++q) {
                    float dsh = dacc[n][q] * NRM_C;
                    wavemax = fmaxf(wavemax, dsh);
                    int rloc = mi*16 + g*4 + q;
                    accF[rloc * 68 + n*16 + rl] = dsh - diagL[rloc];
                }
        } else {
            float rm0 = -INFINITY, rm1 = -INFINITY, rm2 = -INFINITY, rm3 = -INFINITY;
#pragma unroll
            for (int n = 0; n < 4; ++n) {
                rm0 = fmaxf(rm0, dacc[n][0]); rm1 = fmaxf(rm1, dacc[n][1]);
                rm2 = fmaxf(rm2, dacc[n][2]); rm3 = fmaxf(rm3, dacc[n][3]);
            }
#pragma unroll
            for (int off = 1; off < 16; off <<= 1) {
                rm0 = fmaxf(rm0, __shfl_xor(rm0, off));
                rm1 = fmaxf(rm1, __shfl_xor(rm1, off));
                rm2 = fmaxf(rm2, __shfl_xor(rm2, off));
                rm3 = fmaxf(rm3, __shfl_xor(rm3, off));
            }
            float rmq[4] = {rm0 * NRM_C, rm1 * NRM_C, rm2 * NRM_C, rm3 * NRM_C};
#pragma unroll
            for (int n = 0; n < 4; ++n)
#pragma unroll
                for (int q = 0; q < 4; ++q) {
                    int rloc = mi*16 + g*4 + q;
                    float qp = RATIO_C * expf(dacc[n][q] * NRM_C - diagL[rloc] - rmq[q]) + EPSF;
                    accF[rloc * 68 + n*16 + rl] = qp;
                }
        }
    }

    if (MODE == 2) {
#pragma unroll
        for (int off = 1; off < 64; off <<= 1) wavemax = fmaxf(wavemax, __shfl_xor(wavemax, off));
        if (lane == 0) atomicMaxF(&stab[bh_i], wavemax);
#pragma unroll
        for (int pass = 0; pass < 8; ++pass) {
            int rloc = pass * 8 + lr8;
            const float* sp = &accF[rloc * 68 + lc8 * 8];
            float4 f0 = *(const float4*)sp;
            float4 f1 = *(const float4*)(sp + 4);
            long off = (long)(row0 + wrow + rloc) * E_ + col0 + wcol + lc8 * 8;
            *(float4*)(Y + off) = f0;
            *(float4*)(Y + off + 4) = f1;
        }
        return;
    }

    // MODE 3: normalizer, then qkv via MFMA against kvT
    {
        float s = 0.f;
        const float* kb = ksum + bh_i * 64;
#pragma unroll 16
        for (int m = 0; m < 64; ++m) s = fmaf(accF[lane * 68 + m], kb[m], s);
        rnmL[lane] = 1.f / fmaxf(s, EPSD);
    }
    bf16x8 kbh[8], kbl[8];
#pragma unroll
    for (int n = 0; n < 4; ++n)
#pragma unroll
        for (int kk = 0; kk < 2; ++kk) {
            long ko = (long)bh_i * 4096 + (n*16 + rl) * 64 + kk*32 + g*8;
            kbh[n*2+kk] = *(const bf16x8*)(kvThi + ko);
            kbl[n*2+kk] = *(const bf16x8*)(kvTlo + ko);
        }
    __syncthreads();
#pragma unroll
    for (int mi = 0; mi < 4; ++mi) {
        bf16x8 qah[2], qal[2];
#pragma unroll
        for (int kk = 0; kk < 2; ++kk) {
            const float* src = &accF[(mi*16 + rl) * 68 + kk*32 + g*8];
            float4 f0 = *(const float4*)src, f1 = *(const float4*)(src + 4);
            f32x8_split(f0, f1, qah[kk], qal[kk]);
        }
        f32x4 oacc[4];
#pragma unroll
        for (int n = 0; n < 4; ++n) oacc[n] = (f32x4){0.f,0.f,0.f,0.f};
#pragma unroll
        for (int n = 0; n < 4; ++n)
#pragma unroll
            for (int kk = 0; kk < 2; ++kk) {
                oacc[n] = __builtin_amdgcn_mfma_f32_16x16x32_bf16(qah[kk], kbh[n*2+kk], oacc[n], 0, 0, 0);
                oacc[n] = __builtin_amdgcn_mfma_f32_16x16x32_bf16(qah[kk], kbl[n*2+kk], oacc[n], 0, 0, 0);
                oacc[n] = __builtin_amdgcn_mfma_f32_16x16x32_bf16(qal[kk], kbh[n*2+kk], oacc[n], 0, 0, 0);
            }
#pragma unroll
        for (int n = 0; n < 4; ++n)
#pragma unroll
            for (int q = 0; q < 4; ++q) {
                int rloc = mi*16 + g*4 + q;
                accF[rloc * 68 + n*16 + rl] = oacc[n][q] * rnmL[rloc];
            }
    }
#pragma unroll
    for (int pass = 0; pass < 8; ++pass) {
        int rloc = pass * 8 + lr8;
        const float* sp = &accF[rloc * 68 + lc8 * 8];
        float4 f0 = *(const float4*)sp;
        float4 f1 = *(const float4*)(sp + 4);
        float v[8] = {f0.x,f0.y,f0.z,f0.w,f1.x,f1.y,f1.z,f1.w};
        unsigned int hu[4], lu[4];
#pragma unroll
        for (int j = 0; j < 4; ++j) {
            hu[j] = pk_bf16(v[2*j], v[2*j+1]);
            float ea = __uint_as_float(hu[j] << 16);
            float eb = __uint_as_float(hu[j] & 0xffff0000u);
            lu[j] = pk_bf16(v[2*j] - ea, v[2*j+1] - eb);
        }
        long off = (long)(row0 + wrow + rloc) * E_ + col0 + wcol + lc8 * 8;
        uint4 hv = {hu[0], hu[1], hu[2], hu[3]};
        uint4 lv = {lu[0], lu[1], lu[2], lu[3]};
        *(uint4*)(AttnHi + off) = hv;
        *(uint4*)(AttnLo + off) = lv;
    }
}

// ---------------- fp32 fallback GEMM (round-2 proven) ----------------
template<int IN_MODE, int OUT_MODE>
__global__ __launch_bounds__(256) void lin_gemm(const float* __restrict__ X,
                                                const float* __restrict__ W,
                                                const float* __restrict__ bias,
                                                float* __restrict__ Y)
{
    __shared__ float As[16][68];
    __shared__ float Ws[16][68];
    const int row0 = blockIdx.x * 64;
    const int col0 = blockIdx.y * 64;
    const int t  = threadIdx.x;
    const int lr = t >> 2;
    const int lk = (t & 3) * 4;
    const int ty = t >> 4, tx = t & 15;

    long arow;
    {
        int r = row0 + lr;
        if (IN_MODE == 0) { int b = r >> 12, n = r & (N_ - 1); arow = (long)(n * B_ + b) * E_; }
        else              { arow = (long)r * E_; }
    }
    const long wrow = (long)(col0 + lr) * E_;

    float acc[4][4] = {};
    for (int e0 = 0; e0 < E_; e0 += 16) {
        float4 av = *(const float4*)(X + arow + e0 + lk);
        float4 wv = *(const float4*)(W + wrow + e0 + lk);
        As[lk+0][lr] = av.x; As[lk+1][lr] = av.y; As[lk+2][lr] = av.z; As[lk+3][lr] = av.w;
        Ws[lk+0][lr] = wv.x; Ws[lk+1][lr] = wv.y; Ws[lk+2][lr] = wv.z; Ws[lk+3][lr] = wv.w;
        __syncthreads();
#pragma unroll
        for (int k = 0; k < 16; ++k) {
            float4 a = *(const float4*)&As[k][ty*4];
            float4 w = *(const float4*)&Ws[k][tx*4];
            float a_[4] = {a.x,a.y,a.z,a.w};
            float w_[4] = {w.x,w.y,w.z,w.w};
#pragma unroll
            for (int i = 0; i < 4; ++i)
#pragma unroll
                for (int j = 0; j < 4; ++j)
                    acc[i][j] = fmaf(a_[i], w_[j], acc[i][j]);
        }
        __syncthreads();
    }
    float4 bvv = *(const float4*)(bias + col0 + tx*4);
    float b_[4] = {bvv.x,bvv.y,bvv.z,bvv.w};
#pragma unroll
    for (int i = 0; i < 4; ++i) {
        int r = row0 + ty*4 + i;
        float4 o;
        o.x = acc[i][0] + b_[0]; o.y = acc[i][1] + b_[1];
        o.z = acc[i][2] + b_[2]; o.w = acc[i][3] + b_[3];
        long off;
        if (OUT_MODE == 0) off = (long)r * E_ + col0 + tx*4;
        else { int b = r >> 12, n = r & (N_ - 1); off = (long)(n * B_ + b) * E_ + col0 + tx*4; }
        *(float4*)(Y + off) = o;
    }
}

// ---------------- favorp dash (fallback, IN-PLACE over [B,N,E]) ----------------
template<int IS_QUERY>
__global__ __launch_bounds__(256) void favorp_dash(float* __restrict__ Xh,
                                                   const float* __restrict__ proj,
                                                   float* __restrict__ stab)
{
    __shared__ float Xs[64][68];
    __shared__ float Ps[64][68];
    __shared__ float diag[64];
    __shared__ float red4[4];
    __shared__ float rowred[64][17];
    const int bh = blockIdx.x, b = bh >> 4, h = bh & 15;
    const int n0 = blockIdx.y * 64;
    const int t = threadIdx.x;
    const int r = t >> 2, c0 = (t & 3) * 16;
    const int ty = t >> 4, tx = t & 15;

    const float* xrow = Xh + (long)(b * N_ + n0 + r) * E_ + h * 64;
    const float* prow = proj + (long)(h * 64 + r) * 64;
#pragma unroll
    for (int c = 0; c < 4; ++c) {
        float4 v = *(const float4*)(xrow + c0 + c*4);
        Xs[c0+c*4+0][r] = v.x; Xs[c0+c*4+1][r] = v.y; Xs[c0+c*4+2][r] = v.z; Xs[c0+c*4+3][r] = v.w;
        float4 p = *(const float4*)(prow + c0 + c*4);
        Ps[c0+c*4+0][r] = p.x; Ps[c0+c*4+1][r] = p.y; Ps[c0+c*4+2][r] = p.z; Ps[c0+c*4+3][r] = p.w;
    }
    __syncthreads();
    if (t < 64) {
        float s = 0.f;
#pragma unroll 16
        for (int d = 0; d < 64; ++d) { float x = Xs[d][t]; s = fmaf(x, x, s); }
        diag[t] = s * DIAG_C;
    }
    __syncthreads();

    float acc[4][4] = {};
#pragma unroll 16
    for (int d = 0; d < 64; ++d) {
        float4 a = *(const float4*)&Xs[d][ty*4];
        float4 p = *(const float4*)&Ps[d][tx*4];
        float a_[4] = {a.x,a.y,a.z,a.w};
        float p_[4] = {p.x,p.y,p.z,p.w};
#pragma unroll
        for (int i = 0; i < 4; ++i)
#pragma unroll
            for (int j = 0; j < 4; ++j)
                acc[i][j] = fmaf(a_[i], p_[j], acc[i][j]);
    }
    float dash[4][4];
#pragma unroll
    for (int i = 0; i < 4; ++i)
#pragma unroll
        for (int j = 0; j < 4; ++j) dash[i][j] = acc[i][j] * NRM_C;

    if (IS_QUERY) {
#pragma unroll
        for (int i = 0; i < 4; ++i) {
            float m = fmaxf(fmaxf(dash[i][0], dash[i][1]), fmaxf(dash[i][2], dash[i][3]));
            rowred[ty*4+i][tx] = m;
        }
        __syncthreads();
#pragma unroll
        for (int i = 0; i < 4; ++i) {
            int row = ty*4 + i;
            float m = rowred[row][0];
#pragma unroll
            for (int jj = 1; jj < 16; ++jj) m = fmaxf(m, rowred[row][jj]);
            float dg = diag[row];
            float4 o;
            o.x = RATIO_C * expf(dash[i][0] - dg - m) + EPSF;
            o.y = RATIO_C * expf(dash[i][1] - dg - m) + EPSF;
            o.z = RATIO_C * expf(dash[i][2] - dg - m) + EPSF;
            o.w = RATIO_C * expf(dash[i][3] - dg - m) + EPSF;
            *(float4*)(Xh + (long)(b * N_ + n0 + row) * E_ + h * 64 + tx*4) = o;
        }
    } else {
        float lmax = dash[0][0];
#pragma unroll
        for (int i = 0; i < 4; ++i)
#pragma unroll
            for (int j = 0; j < 4; ++j) lmax = fmaxf(lmax, dash[i][j]);
#pragma unroll
        for (int i = 0; i < 4; ++i) {
            int row = ty*4 + i;
            float dg = diag[row];
            float4 o = { dash[i][0]-dg, dash[i][1]-dg, dash[i][2]-dg, dash[i][3]-dg };
            *(float4*)(Xh + (long)(b * N_ + n0 + row) * E_ + h * 64 + tx*4) = o;
        }
#pragma unroll
        for (int off = 32; off > 0; off >>= 1) lmax = fmaxf(lmax, __shfl_down(lmax, off));
        if ((t & 63) == 0) red4[t >> 6] = lmax;
        __syncthreads();
        if (t == 0)
            atomicMaxF(&stab[bh], fmaxf(fmaxf(red4[0], red4[1]), fmaxf(red4[2], red4[3])));
    }
}

// ---------------- kv partials ----------------
__global__ __launch_bounds__(256) void kv_partial(const float* __restrict__ T1,
                                                  const float* __restrict__ V,
                                                  const float* __restrict__ stab,
                                                  float* __restrict__ kvp,
                                                  float* __restrict__ ksump)
{
    __shared__ float KPs[16][68];
    __shared__ float Vs[16][68];
    const int bh = blockIdx.x, chunk = blockIdx.y;
    const int b = bh >> 4, h = bh & 15;
    const int t = threadIdx.x;
    const int lr = t >> 4, lm = (t & 15) * 4;
    const int ty = t >> 4, tx = t & 15;
    const float stb = stab[bh];
    float acc[4][4] = {};
    float ks = 0.f;
    const int nbeg = chunk * (N_ / SPLITK), nend = nbeg + (N_ / SPLITK);
    for (int n0 = nbeg; n0 < nend; n0 += 16) {
        long rowoff = (long)(b * N_ + n0 + lr) * E_ + h * 64 + lm;
        float4 tv = *(const float4*)(T1 + rowoff);
        float4 vv = *(const float4*)(V + rowoff);
        KPs[lr][lm+0] = RATIO_C * expf(tv.x - stb) + EPSF;
        KPs[lr][lm+1] = RATIO_C * expf(tv.y - stb) + EPSF;
        KPs[lr][lm+2] = RATIO_C * expf(tv.z - stb) + EPSF;
        KPs[lr][lm+3] = RATIO_C * expf(tv.w - stb) + EPSF;
        *(float4*)&Vs[lr][lm] = vv;
        __syncthreads();
        if (t < 64) {
#pragma unroll
            for (int rr = 0; rr < 16; ++rr) ks += KPs[rr][t];
        }
#pragma unroll
        for (int k = 0; k < 16; ++k) {
            float4 a = *(const float4*)&KPs[k][ty*4];
            float4 v4 = *(const float4*)&Vs[k][tx*4];
            float a_[4] = {a.x,a.y,a.z,a.w};
            float v_[4] = {v4.x,v4.y,v4.z,v4.w};
#pragma unroll
            for (int i = 0; i < 4; ++i)
#pragma unroll
                for (int j = 0; j < 4; ++j)
                    acc[i][j] = fmaf(a_[i], v_[j], acc[i][j]);
        }
        __syncthreads();
    }
    const long kvbase = ((long)chunk * BH_ + bh) * 4096;
#pragma unroll
    for (int i = 0; i < 4; ++i) {
        float4 o = {acc[i][0], acc[i][1], acc[i][2], acc[i][3]};
        *(float4*)(kvp + kvbase + (ty*4+i) * 64 + tx*4) = o;
    }
    if (t < 64) ksump[((long)chunk * BH_ + bh) * 64 + t] = ks;
}

// reduce partials; write kv TRANSPOSED split-bf16 [BH][d][m] + ksum fp32 (+kvM fp32 for fallback)
__global__ __launch_bounds__(256) void kv_reduce(const float* __restrict__ kvp,
                                                 const float* __restrict__ ksump,
                                                 float* __restrict__ kvM,
                                                 float* __restrict__ ksum,
                                                 unsigned short* __restrict__ kvThi,
                                                 unsigned short* __restrict__ kvTlo)
{
    int idx = blockIdx.x * 256 + threadIdx.x;
    if (idx < BH_ * 4096) {
        float s = 0.f;
#pragma unroll
        for (int c = 0; c < SPLITK; ++c) s += kvp[(long)c * BH_ * 4096 + idx];
        kvM[idx] = s;
        int bh = idx >> 12, md = idx & 4095, m = md >> 6, d = md & 63;
        unsigned short h16 = f32_to_bf16(s);
        long toff = (long)bh * 4096 + d * 64 + m;
        kvThi[toff] = h16;
        kvTlo[toff] = f32_to_bf16(s - bf16_to_f32(h16));
    } else {
        int j = idx - BH_ * 4096;
        if (j < BH_ * 64) {
            float s = 0.f;
#pragma unroll
            for (int c = 0; c < SPLITK; ++c) s += ksump[(long)c * BH_ * 64 + j];
            ksum[j] = s;
        }
    }
}

// ---------------- qkv + normalize (fallback only) ----------------
__global__ __launch_bounds__(256) void qkv_attn(const float* __restrict__ Qp,
                                                const float* __restrict__ kvM,
                                                const float* __restrict__ ksum,
                                                float* __restrict__ attn)
{
    __shared__ float QPs[64][68];
    __shared__ float kvs[64][68];
    __shared__ float ksums[64];
    __shared__ float rnorm[64];
    const int bh = blockIdx.x, b = bh >> 4, h = bh & 15;
    const int n0 = blockIdx.y * 64;
    const int t = threadIdx.x;
    const int r = t >> 2, c0 = (t & 3) * 16;
    const int ty = t >> 4, tx = t & 15;

#pragma unroll
    for (int c = 0; c < 4; ++c) {
        int idx = t * 16 + c * 4;
        float4 v = *(const float4*)(kvM + (long)bh * 4096 + idx);
        *(float4*)&kvs[idx >> 6][idx & 63] = v;
    }
    if (t < 64) ksums[t] = ksum[bh * 64 + t];
    const float* qrow = Qp + (long)(b * N_ + n0 + r) * E_ + h * 64;
#pragma unroll
    for (int c = 0; c < 4; ++c) {
        float4 v = *(const float4*)(qrow + c0 + c*4);
        QPs[c0+c*4+0][r] = v.x; QPs[c0+c*4+1][r] = v.y; QPs[c0+c*4+2][r] = v.z; QPs[c0+c*4+3][r] = v.w;
    }
    __syncthreads();
    if (t < 64) {
        float s = 0.f;
#pragma unroll 16
        for (int m = 0; m < 64; ++m) s = fmaf(QPs[m][t], ksums[m], s);
        rnorm[t] = 1.f / fmaxf(s, EPSD);
    }
    __syncthreads();
    float acc[4][4] = {};
#pragma unroll 16
    for (int m = 0; m < 64; ++m) {
        float4 a = *(const float4*)&QPs[m][ty*4];
        float4 v4 = *(const float4*)&kvs[m][tx*4];
        float a_[4] = {a.x,a.y,a.z,a.w};
        float v_[4] = {v4.x,v4.y,v4.z,v4.w};
#pragma unroll
        for (int i = 0; i < 4; ++i)
#pragma unroll
            for (int j = 0; j < 4; ++j)
                acc[i][j] = fmaf(a_[i], v_[j], acc[i][j]);
    }
#pragma unroll
    for (int i = 0; i < 4; ++i) {
        int row = ty*4 + i;
        float rn = rnorm[row];
        float4 o = {acc[i][0]*rn, acc[i][1]*rn, acc[i][2]*rn, acc[i][3]*rn};
        *(float4*)(attn + (long)(b * N_ + n0 + row) * E_ + h * 64 + tx*4) = o;
    }
}

extern "C" void kernel_launch(void* const* d_in, const int* in_sizes, int n_in,
                              void* d_out, int out_size, void* d_ws, size_t ws_size,
                              hipStream_t stream)
{
    const float* query = (const float*)d_in[0];
    const float* key   = (const float*)d_in[1];
    const float* value = (const float*)d_in[2];
    const float* Wq    = (const float*)d_in[3];
    const float* bq    = (const float*)d_in[4];
    const float* Wk    = (const float*)d_in[5];
    const float* bk    = (const float*)d_in[6];
    const float* Wv    = (const float*)d_in[7];
    const float* bv    = (const float*)d_in[8];
    const float* Wo    = (const float*)d_in[9];
    const float* bo    = (const float*)d_in[10];
    const float* proj  = (const float*)d_in[11];
    float* O = (float*)d_out;                 // scratch; fully rewritten by final GEMM

    float* ws = (float*)d_ws;
    const size_t SZ = (size_t)BN_ * E_;       // 16.78M floats
    float* A     = ws;                        // V fp32; later attn (split-bf16 in fast path)
    float* kvp   = ws + SZ;
    float* ksump = kvp + (size_t)SPLITK * BH_ * 4096;
    float* kvM   = ksump + (size_t)SPLITK * BH_ * 64;
    float* ksum  = kvM + (size_t)BH_ * 4096;
    float* stab  = ksum + (size_t)BH_ * 64;
    unsigned short* kvThi = (unsigned short*)(stab + 64);            // BH*4096 ush
    unsigned short* kvTlo = kvThi + (size_t)BH_ * 4096;
    unsigned short* PShi  = kvTlo + (size_t)BH_ * 4096;              // 65536 ush
    unsigned short* PSlo  = PShi + 65536;
    const size_t EXTRA_F = (size_t)BH_ * 4096 /*kvT pair*/ + 65536 /*PS pair*/;
    const size_t COMMON_F = SZ + (size_t)SPLITK * BH_ * 4096 + (size_t)SPLITK * BH_ * 64
                          + (size_t)BH_ * 4096 + (size_t)BH_ * 64 + 64 + EXTRA_F;
    unsigned short* Xhi = (unsigned short*)(ws + COMMON_F);
    unsigned short* Xlo = Xhi + SZ;
    unsigned short* Whi = Xlo + SZ;
    unsigned short* Wlo = Whi + (size_t)E_ * E_;
    const size_t NEED_FAST = (COMMON_F + SZ + (size_t)E_ * E_) * 4;  // bytes

    dim3 gF(BH_, N_ / 64);
    dim3 gKV(BH_, SPLITK);
    const int nRed = (BH_ * 4096 + BH_ * 64) / 256;

    if (ws_size >= NEED_FAST) {
        dim3 gP(BN_ / 256, E_ / 128);    // pipelined GEMM, all modes
        const int X4 = (int)(SZ / 4), W4 = (E_ * E_) / 4;
        unsigned short* AttnHi = (unsigned short*)A;
        unsigned short* AttnLo = AttnHi + SZ;

        (void)hipFuncSetAttribute((const void*)&gemm8p<0>, hipFuncAttributeMaxDynamicSharedMemorySize, SMEM_DYN8);
        (void)hipFuncSetAttribute((const void*)&gemm8p<1>, hipFuncAttributeMaxDynamicSharedMemorySize, SMEM_DYN8);
        (void)hipFuncSetAttribute((const void*)&gemm8p<2>, hipFuncAttributeMaxDynamicSharedMemorySize, SMEM_DYN8);
        (void)hipFuncSetAttribute((const void*)&gemm8p<3>, hipFuncAttributeMaxDynamicSharedMemorySize, SMEM_DYN8);

        convert_split<1><<<64, 256, 0, stream>>>(proj, PShi, PSlo, 16384);
        init_stab<<<1, 64, 0, stream>>>(stab);
        // K chain: pipelined GEMM + fused favorp_k -> T1 (O) + stab
        convert_split<0><<<2048, 256, 0, stream>>>(key, Xhi, Xlo, X4);
        convert_split<1><<<1024, 256, 0, stream>>>(Wk, Whi, Wlo, W4);
        gemm8p<2><<<gP, 512, SMEM_DYN8, stream>>>(Xhi, Xlo, Whi, Wlo, bk, O, stab,
                                                  PShi, PSlo, nullptr, nullptr, nullptr, nullptr, nullptr);
        // V chain
        convert_split<0><<<2048, 256, 0, stream>>>(value, Xhi, Xlo, X4);
        convert_split<1><<<1024, 256, 0, stream>>>(Wv, Whi, Wlo, W4);
        gemm8p<0><<<gP, 512, SMEM_DYN8, stream>>>(Xhi, Xlo, Whi, Wlo, bv, A, nullptr,
                                                  nullptr, nullptr, nullptr, nullptr, nullptr, nullptr, nullptr);
        // kv
        kv_partial<<<gKV, 256, 0, stream>>>(O, A, stab, kvp, ksump);
        kv_reduce<<<nRed, 256, 0, stream>>>(kvp, ksump, kvM, ksum, kvThi, kvTlo);
        // Q chain: pipelined GEMM + fused favorp_q + qkv -> attn split-bf16 (A region)
        convert_split<0><<<2048, 256, 0, stream>>>(query, Xhi, Xlo, X4);
        convert_split<1><<<1024, 256, 0, stream>>>(Wq, Whi, Wlo, W4);
        gemm8p<3><<<gP, 512, SMEM_DYN8, stream>>>(Xhi, Xlo, Whi, Wlo, bq, nullptr, nullptr,
                                                  PShi, PSlo, kvThi, kvTlo, ksum, AttnHi, AttnLo);
        // output GEMM (transposed store)
        convert_split<1><<<1024, 256, 0, stream>>>(Wo, Whi, Wlo, W4);
        gemm8p<1><<<gP, 512, SMEM_DYN8, stream>>>(AttnHi, AttnLo, Whi, Wlo, bo, O, nullptr,
                                                  nullptr, nullptr, nullptr, nullptr, nullptr, nullptr, nullptr);
    } else {
        // fp32 fallback (round-2 proven path)
        dim3 gGemm(BN_ / 64, E_ / 64);
        lin_gemm<0,0><<<gGemm, 256, 0, stream>>>(key, Wk, bk, O);
        init_stab<<<1, 64, 0, stream>>>(stab);
        favorp_dash<0><<<gF, 256, 0, stream>>>(O, proj, stab);
        lin_gemm<0,0><<<gGemm, 256, 0, stream>>>(value, Wv, bv, A);
        kv_partial<<<gKV, 256, 0, stream>>>(O, A, stab, kvp, ksump);
        kv_reduce<<<nRed, 256, 0, stream>>>(kvp, ksump, kvM, ksum, kvThi, kvTlo);
        lin_gemm<0,0><<<gGemm, 256, 0, stream>>>(query, Wq, bq, O);
        favorp_dash<1><<<gF, 256, 0, stream>>>(O, proj, stab);
        qkv_attn<<<gF, 256, 0, stream>>>(O, kvM, ksum, A);
        lin_gemm<1,1><<<gGemm, 256, 0, stream>>>(A, Wo, bo, O);
    }
}

// Round 15
// 564.978 us; speedup vs baseline: 1.0325x; 1.0029x over previous
//
#include <hip/hip_runtime.h>
#include <math.h>

// Problem constants (fixed by setup_inputs)
#define B_   4
#define N_   4096
#define E_   1024
#define H_   16
#define BN_  (B_*N_)
#define BH_  (B_*H_)
#define SPLITK 8

// favorp constants
#define NRM_C   0.35355339059327373f   // 64^-0.25
#define DIAG_C  0.0625f                // 0.5 * NRM^2
#define RATIO_C 0.125f                 // 64^-0.5
#define EPSF    1e-4f
#define EPSD    0.01f

typedef __attribute__((ext_vector_type(8))) short bf16x8;   // 8 bf16 in 4 VGPRs
typedef __attribute__((ext_vector_type(4))) float f32x4;

__device__ __forceinline__ unsigned short f32_to_bf16(float x) {
    unsigned int u = __float_as_uint(x);
    unsigned int r = (u + 0x7fffu + ((u >> 16) & 1u)) >> 16;   // RTN-even
    return (unsigned short)r;
}
__device__ __forceinline__ float bf16_to_f32(unsigned short h) {
    return __uint_as_float(((unsigned int)h) << 16);
}

// packed f32->bf16 via HW instruction; D.lo=bf16(a), D.hi=bf16(b)
__device__ __forceinline__ unsigned int pk_bf16(float a, float b) {
    unsigned int r;
    asm("v_cvt_pk_bf16_f32 %0, %1, %2" : "=v"(r) : "v"(a), "v"(b));
    return r;
}

// 8 fp32 -> split bf16 hi/lo fragments (pk-based)
__device__ __forceinline__ void f32x8_split(float4 fa, float4 fb, bf16x8& hi, bf16x8& lo) {
    unsigned int h0 = pk_bf16(fa.x, fa.y), h1 = pk_bf16(fa.z, fa.w);
    unsigned int h2 = pk_bf16(fb.x, fb.y), h3 = pk_bf16(fb.z, fb.w);
    float e0 = __uint_as_float(h0 << 16), e1 = __uint_as_float(h0 & 0xffff0000u);
    float e2 = __uint_as_float(h1 << 16), e3 = __uint_as_float(h1 & 0xffff0000u);
    float e4 = __uint_as_float(h2 << 16), e5 = __uint_as_float(h2 & 0xffff0000u);
    float e6 = __uint_as_float(h3 << 16), e7 = __uint_as_float(h3 & 0xffff0000u);
    unsigned int l0 = pk_bf16(fa.x - e0, fa.y - e1), l1 = pk_bf16(fa.z - e2, fa.w - e3);
    unsigned int l2 = pk_bf16(fb.x - e4, fb.y - e5), l3 = pk_bf16(fb.z - e6, fb.w - e7);
    union { unsigned int u[4]; bf16x8 v; } H, L;
    H.u[0] = h0; H.u[1] = h1; H.u[2] = h2; H.u[3] = h3;
    L.u[0] = l0; L.u[1] = l1; L.u[2] = l2; L.u[3] = l3;
    hi = H.v; lo = L.v;
}

__device__ __forceinline__ void atomicMaxF(float* addr, float v) {
    if (v >= 0.f) atomicMax((int*)addr, __float_as_int(v));
    else          atomicMin((unsigned int*)addr, __float_as_uint(v));
}

__global__ void init_stab(float* stab) {
    if (threadIdx.x < BH_) stab[threadIdx.x] = -INFINITY;
}

// ---------------- split-bf16 conversion ----------------
template<int IN_MODE>
__global__ __launch_bounds__(256) void convert_split(const float* __restrict__ src,
                                                     unsigned short* __restrict__ hi,
                                                     unsigned short* __restrict__ lo,
                                                     int total4)
{
    int i = blockIdx.x * 256 + threadIdx.x;
    const int stride = gridDim.x * 256;
    for (; i < total4; i += stride) {
        long e4 = (long)i * 4;
        const float* p;
        if (IN_MODE == 0) {
            long r = e4 >> 10; int e = (int)(e4 & 1023);
            int b = (int)(r >> 12), n = (int)(r & 4095);
            p = src + (((long)(n * B_ + b)) << 10) + e;
        } else {
            p = src + e4;
        }
        float4 v = *(const float4*)p;
        ushort4 h, l;
        h.x = f32_to_bf16(v.x); l.x = f32_to_bf16(v.x - bf16_to_f32(h.x));
        h.y = f32_to_bf16(v.y); l.y = f32_to_bf16(v.y - bf16_to_f32(h.y));
        h.z = f32_to_bf16(v.z); l.z = f32_to_bf16(v.z - bf16_to_f32(h.z));
        h.w = f32_to_bf16(v.w); l.w = f32_to_bf16(v.w - bf16_to_f32(h.w));
        *(ushort4*)(hi + e4) = h;
        *(ushort4*)(lo + e4) = l;
    }
}

__device__ __forceinline__ void gl_lds16(const unsigned short* g, unsigned short* l) {
    __builtin_amdgcn_global_load_lds((const __attribute__((address_space(1))) void*)g,
                                     (__attribute__((address_space(3))) void*)l, 16, 0, 0);
}

// =====================================================================
// Fine-phase pipelined GEMM, all modes: 256x128 tile, BK=32, 8 waves,
// 3 LDS buffers (144KB), 2-deep prefetch, counted vmcnt(6) at K boundaries.
// Bank-conflict-free fragment swizzle: slot = g ^ ((row>>1)&3)  (2-way = free).
// 2 merged phases per K-tile (m-bands 0+1, 2+3): 5 barriers/tile.
// MODE 0: Y fp32 [BN,E];  MODE 1: Y fp32 [N,B,E] transposed;
// MODE 2: K-fused favorp (T1 + stab);  MODE 3: Q-fused favorp_q + qkv -> attn split-bf16.
// =====================================================================
#define SMEM_DYN8 147456

template<int MODE>
__global__ __launch_bounds__(512, 2) void gemm8p(const unsigned short* __restrict__ Ahi,
                                                 const unsigned short* __restrict__ Alo,
                                                 const unsigned short* __restrict__ Bhi,
                                                 const unsigned short* __restrict__ Blo,
                                                 const float* __restrict__ bias,
                                                 float* __restrict__ Y,
                                                 float* __restrict__ stab,
                                                 const unsigned short* __restrict__ PShi,
                                                 const unsigned short* __restrict__ PSlo,
                                                 const unsigned short* __restrict__ kvThi,
                                                 const unsigned short* __restrict__ kvTlo,
                                                 const float* __restrict__ ksum,
                                                 unsigned short* __restrict__ AttnHi,
                                                 unsigned short* __restrict__ AttnLo)
{
    extern __shared__ char SMEM8[];
    unsigned short* U = (unsigned short*)SMEM8;
    const int t = threadIdx.x;
    const int w = t >> 6, lane = t & 63;
    const int row0 = blockIdx.x * 256, col0 = blockIdx.y * 128;
    const int wrow = (w >> 1) * 64, wcol = (w & 1) * 64;
    const int g = lane >> 4, rl = lane & 15;
    const int lr8 = lane >> 3, lc8 = lane & 7;

    // staging address precompute (granule = 16B = 8 shorts)
    // pre-swizzled source: LDS(row r, slot s) holds global k-octet s ^ ((r>>1)&3)
    int gi0 = t, gi1 = 512 + t;
    int ar0 = gi0 >> 2, as0 = gi0 & 3;
    int ar1 = gi1 >> 2, as1 = gi1 & 3;
    const long aSrc0 = (long)(row0 + ar0) * E_ + ((as0 ^ ((ar0 >> 1) & 3)) << 3);
    const long aSrc1 = (long)(row0 + ar1) * E_ + ((as1 ^ ((ar1 >> 1) & 3)) << 3);
    const int aDst0 = (w * 64) * 8;
    const int aDst1 = (512 + w * 64) * 8;
    const long bSrc = (long)(col0 + (t >> 2)) * E_ + (((t & 3) ^ ((t >> 3) & 3)) << 3);
    const int bDst = (w * 64) * 8;

    f32x4 acc[4][4];
#pragma unroll
    for (int m = 0; m < 4; ++m)
#pragma unroll
        for (int n = 0; n < 4; ++n) acc[m][n] = (f32x4){0.f, 0.f, 0.f, 0.f};

#define STAGE_FULL(TILE, BUFI) {                                        \
        const int k0_ = (TILE) * 32;                                    \
        unsigned short* bu_ = U + (BUFI) * 24576;                       \
        gl_lds16(Ahi + aSrc0 + k0_, bu_ + aDst0);                       \
        gl_lds16(Ahi + aSrc1 + k0_, bu_ + aDst1);                       \
        gl_lds16(Alo + aSrc0 + k0_, bu_ + 8192 + aDst0);                \
        gl_lds16(Alo + aSrc1 + k0_, bu_ + 8192 + aDst1);                \
        gl_lds16(Bhi + bSrc + k0_, bu_ + 16384 + bDst);                 \
        gl_lds16(Blo + bSrc + k0_, bu_ + 20480 + bDst); }

    // 12 MFMA for one m-band (order per-acc unchanged: ah*bh, ah*bl, al*bh over n)
#define MBAND(MI, AH, AL)                                                                     \
        _Pragma("unroll")                                                                     \
        for (int n = 0; n < 4; ++n)                                                           \
            acc[MI][n] = __builtin_amdgcn_mfma_f32_16x16x32_bf16(AH, bhf[n], acc[MI][n], 0, 0, 0); \
        _Pragma("unroll")                                                                     \
        for (int n = 0; n < 4; ++n)                                                           \
            acc[MI][n] = __builtin_amdgcn_mfma_f32_16x16x32_bf16(AH, blf[n], acc[MI][n], 0, 0, 0); \
        _Pragma("unroll")                                                                     \
        for (int n = 0; n < 4; ++n)                                                           \
            acc[MI][n] = __builtin_amdgcn_mfma_f32_16x16x32_bf16(AL, bhf[n], acc[MI][n], 0, 0, 0);

    STAGE_FULL(0, 0);
    STAGE_FULL(1, 1);
    asm volatile("s_waitcnt vmcnt(6)" ::: "memory");   // tile 0 landed (own; FIFO)
    __builtin_amdgcn_s_barrier();                      // all waves' tile 0 landed
    __builtin_amdgcn_sched_barrier(0);

    for (int tt = 0; tt < 32; ++tt) {
        const unsigned short* sb = U + (tt % 3) * 24576;
        unsigned short* ub = U + ((tt + 2) % 3) * 24576;
        const bool st = (tt + 2 < 32);
        const int k2 = (tt + 2) * 32;
        bf16x8 bhf[4], blf[4];

        // ---- phase A: B frags + A bands m=0,1; stage A(t+2) (4 loads) ----
#pragma unroll
        for (int n = 0; n < 4; ++n) {
            int r = wcol + n * 16 + rl;
            int off = r * 32 + ((g ^ ((r >> 1) & 3)) << 3);
            bhf[n] = *(const bf16x8*)(sb + 16384 + off);
            blf[n] = *(const bf16x8*)(sb + 20480 + off);
        }
        {
            int r0 = wrow + rl;
            int off0 = r0 * 32 + ((g ^ ((r0 >> 1) & 3)) << 3);
            bf16x8 ah0 = *(const bf16x8*)(sb + off0);
            bf16x8 al0 = *(const bf16x8*)(sb + 8192 + off0);
            int r1 = wrow + 16 + rl;
            int off1 = r1 * 32 + ((g ^ ((r1 >> 1) & 3)) << 3);
            bf16x8 ah1 = *(const bf16x8*)(sb + off1);
            bf16x8 al1 = *(const bf16x8*)(sb + 8192 + off1);
            if (st) { gl_lds16(Ahi + aSrc0 + k2, ub + aDst0);
                      gl_lds16(Ahi + aSrc1 + k2, ub + aDst1);
                      gl_lds16(Alo + aSrc0 + k2, ub + 8192 + aDst0);
                      gl_lds16(Alo + aSrc1 + k2, ub + 8192 + aDst1); }
            asm volatile("s_waitcnt lgkmcnt(0)" ::: "memory");
            __builtin_amdgcn_sched_barrier(0);
            __builtin_amdgcn_s_setprio(1);
            MBAND(0, ah0, al0)
            MBAND(1, ah1, al1)
            __builtin_amdgcn_s_setprio(0);
        }
        __builtin_amdgcn_s_barrier();
        __builtin_amdgcn_sched_barrier(0);

        // ---- phase B: A bands m=2,3; stage B(t+2) (2 loads); boundary wait ----
        {
            int r2 = wrow + 32 + rl;
            int off2 = r2 * 32 + ((g ^ ((r2 >> 1) & 3)) << 3);
            bf16x8 ah2 = *(const bf16x8*)(sb + off2);
            bf16x8 al2 = *(const bf16x8*)(sb + 8192 + off2);
            int r3 = wrow + 48 + rl;
            int off3 = r3 * 32 + ((g ^ ((r3 >> 1) & 3)) << 3);
            bf16x8 ah3 = *(const bf16x8*)(sb + off3);
            bf16x8 al3 = *(const bf16x8*)(sb + 8192 + off3);
            if (st) { gl_lds16(Bhi + bSrc + k2, ub + 16384 + bDst);
                      gl_lds16(Blo + bSrc + k2, ub + 20480 + bDst); }
            asm volatile("s_waitcnt lgkmcnt(0)" ::: "memory");
            __builtin_amdgcn_sched_barrier(0);
            __builtin_amdgcn_s_setprio(1);
            MBAND(2, ah2, al2)
            MBAND(3, ah3, al3)
            __builtin_amdgcn_s_setprio(0);
        }
        if (tt < 31) {
            if (st) asm volatile("s_waitcnt vmcnt(6)" ::: "memory");
            else    asm volatile("s_waitcnt vmcnt(0)" ::: "memory");
            __builtin_amdgcn_s_barrier();
            __builtin_amdgcn_sched_barrier(0);
        }
    }
#undef STAGE_FULL
#undef MBAND

    float bv[4];
#pragma unroll
    for (int n = 0; n < 4; ++n) bv[n] = bias[col0 + wcol + n * 16 + rl];

    if (MODE <= 1) {
        // plain epilogue: direct stores from acc registers
#pragma unroll
        for (int m = 0; m < 4; ++m) {
            int rbase = row0 + wrow + m * 16 + g * 4;
#pragma unroll
            for (int n = 0; n < 4; ++n) {
                int c = col0 + wcol + n * 16 + rl;
#pragma unroll
                for (int q = 0; q < 4; ++q) {
                    int r = rbase + q;
                    float v = acc[m][n][q] + bv[n];
                    long off;
                    if (MODE == 0) off = (long)r * E_ + c;
                    else { int b = r >> 12, nn = r & (N_ - 1); off = (long)(nn * B_ + b) * E_ + c; }
                    Y[off] = v;
                }
            }
        }
        return;
    }

    // ---------------- fused favorp epilogue (MODE 2 / 3) ----------------
    __syncthreads();   // all waves done with staging LDS; overlay accF
    float* accF  = (float*)SMEM8 + w * (64 * 68);              // wave-private [64][68]
    float* diagL = (float*)(SMEM8 + 139264) + w * 64;
    float* rnmL  = (float*)(SMEM8 + 139264 + 2048) + w * 64;
    const int b_idx = row0 >> 12;
    const int hg = (col0 >> 6) + (w & 1);                      // global head 0..15
    const int bh_i = b_idx * H_ + hg;

    // hoisted PS fragment loads — band-invariant
    bf16x8 pbh[8], pbl[8];
#pragma unroll
    for (int n = 0; n < 4; ++n)
#pragma unroll
        for (int kk = 0; kk < 2; ++kk) {
            long po = (long)hg * 4096 + (n*16 + rl) * 64 + kk*32 + g*8;
            pbh[n*2+kk] = *(const bf16x8*)(PShi + po);
            pbl[n*2+kk] = *(const bf16x8*)(PSlo + po);
        }

#pragma unroll
    for (int m = 0; m < 4; ++m)
#pragma unroll
        for (int n = 0; n < 4; ++n)
#pragma unroll
            for (int q = 0; q < 4; ++q)
                accF[(m*16 + g*4 + q) * 68 + n*16 + rl] = acc[m][n][q] + bv[n];
    {
        float s = 0.f;
#pragma unroll 16
        for (int d = 0; d < 64; ++d) { float x = accF[lane * 68 + d]; s = fmaf(x, x, s); }
        diagL[lane] = s * DIAG_C;
    }
    __syncthreads();

    float wavemax = -INFINITY;
#pragma unroll
    for (int mi = 0; mi < 4; ++mi) {
        bf16x8 dah[2], dal[2];
#pragma unroll
        for (int kk = 0; kk < 2; ++kk) {
            const float* src = &accF[(mi*16 + rl) * 68 + kk*32 + g*8];
            float4 f0 = *(const float4*)src, f1 = *(const float4*)(src + 4);
            f32x8_split(f0, f1, dah[kk], dal[kk]);
        }
        f32x4 dacc[4];
#pragma unroll
        for (int n = 0; n < 4; ++n) dacc[n] = (f32x4){0.f,0.f,0.f,0.f};
#pragma unroll
        for (int n = 0; n < 4; ++n)
#pragma unroll
            for (int kk = 0; kk < 2; ++kk) {
                dacc[n] = __builtin_amdgcn_mfma_f32_16x16x32_bf16(dah[kk], pbh[n*2+kk], dacc[n], 0, 0, 0);
                dacc[n] = __builtin_amdgcn_mfma_f32_16x16x32_bf16(dah[kk], pbl[n*2+kk], dacc[n], 0, 0, 0);
                dacc[n] = __builtin_amdgcn_mfma_f32_16x16x32_bf16(dal[kk], pbh[n*2+kk], dacc[n], 0, 0, 0);
            }
        if (MODE == 2) {
#pragma unroll
            for (int n = 0; n < 4; ++n)
#pragma unroll
                for (int q = 0; q < 4; ++q) {
                    float dsh = dacc[n][q] * NRM_C;
                    wavemax = fmaxf(wavemax, dsh);
                    int rloc = mi*16 + g*4 + q;
                    accF[rloc * 68 + n*16 + rl] = dsh - diagL[rloc];
                }
        } else {
            float rm0 = -INFINITY, rm1 = -INFINITY, rm2 = -INFINITY, rm3 = -INFINITY;
#pragma unroll
            for (int n = 0; n < 4; ++n) {
                rm0 = fmaxf(rm0, dacc[n][0]); rm1 = fmaxf(rm1, dacc[n][1]);
                rm2 = fmaxf(rm2, dacc[n][2]); rm3 = fmaxf(rm3, dacc[n][3]);
            }
#pragma unroll
            for (int off = 1; off < 16; off <<= 1) {
                rm0 = fmaxf(rm0, __shfl_xor(rm0, off));
                rm1 = fmaxf(rm1, __shfl_xor(rm1, off));
                rm2 = fmaxf(rm2, __shfl_xor(rm2, off));
                rm3 = fmaxf(rm3, __shfl_xor(rm3, off));
            }
            float rmq[4] = {rm0 * NRM_C, rm1 * NRM_C, rm2 * NRM_C, rm3 * NRM_C};
#pragma unroll
            for (int n = 0; n < 4; ++n)
#pragma unroll
                for (int q = 0; q < 4; ++q) {
                    int rloc = mi*16 + g*4 + q;
                    float qp = RATIO_C * expf(dacc[n][q] * NRM_C - diagL[rloc] - rmq[q]) + EPSF;
                    accF[rloc * 68 + n*16 + rl] = qp;
                }
        }
    }

    if (MODE == 2) {
#pragma unroll
        for (int off = 1; off < 64; off <<= 1) wavemax = fmaxf(wavemax, __shfl_xor(wavemax, off));
        if (lane == 0) atomicMaxF(&stab[bh_i], wavemax);
#pragma unroll
        for (int pass = 0; pass < 8; ++pass) {
            int rloc = pass * 8 + lr8;
            const float* sp = &accF[rloc * 68 + lc8 * 8];
            float4 f0 = *(const float4*)sp;
            float4 f1 = *(const float4*)(sp + 4);
            long off = (long)(row0 + wrow + rloc) * E_ + col0 + wcol + lc8 * 8;
            *(float4*)(Y + off) = f0;
            *(float4*)(Y + off + 4) = f1;
        }
        return;
    }

    // MODE 3: normalizer, then qkv via MFMA against kvT
    {
        float s = 0.f;
        const float* kb = ksum + bh_i * 64;
#pragma unroll 16
        for (int m = 0; m < 64; ++m) s = fmaf(accF[lane * 68 + m], kb[m], s);
        rnmL[lane] = 1.f / fmaxf(s, EPSD);
    }
    bf16x8 kbh[8], kbl[8];
#pragma unroll
    for (int n = 0; n < 4; ++n)
#pragma unroll
        for (int kk = 0; kk < 2; ++kk) {
            long ko = (long)bh_i * 4096 + (n*16 + rl) * 64 + kk*32 + g*8;
            kbh[n*2+kk] = *(const bf16x8*)(kvThi + ko);
            kbl[n*2+kk] = *(const bf16x8*)(kvTlo + ko);
        }
    __syncthreads();
#pragma unroll
    for (int mi = 0; mi < 4; ++mi) {
        bf16x8 qah[2], qal[2];
#pragma unroll
        for (int kk = 0; kk < 2; ++kk) {
            const float* src = &accF[(mi*16 + rl) * 68 + kk*32 + g*8];
            float4 f0 = *(const float4*)src, f1 = *(const float4*)(src + 4);
            f32x8_split(f0, f1, qah[kk], qal[kk]);
        }
        f32x4 oacc[4];
#pragma unroll
        for (int n = 0; n < 4; ++n) oacc[n] = (f32x4){0.f,0.f,0.f,0.f};
#pragma unroll
        for (int n = 0; n < 4; ++n)
#pragma unroll
            for (int kk = 0; kk < 2; ++kk) {
                oacc[n] = __builtin_amdgcn_mfma_f32_16x16x32_bf16(qah[kk], kbh[n*2+kk], oacc[n], 0, 0, 0);
                oacc[n] = __builtin_amdgcn_mfma_f32_16x16x32_bf16(qah[kk], kbl[n*2+kk], oacc[n], 0, 0, 0);
                oacc[n] = __builtin_amdgcn_mfma_f32_16x16x32_bf16(qal[kk], kbh[n*2+kk], oacc[n], 0, 0, 0);
            }
#pragma unroll
        for (int n = 0; n < 4; ++n)
#pragma unroll
            for (int q = 0; q < 4; ++q) {
                int rloc = mi*16 + g*4 + q;
                accF[rloc * 68 + n*16 + rl] = oacc[n][q] * rnmL[rloc];
            }
    }
#pragma unroll
    for (int pass = 0; pass < 8; ++pass) {
        int rloc = pass * 8 + lr8;
        const float* sp = &accF[rloc * 68 + lc8 * 8];
        float4 f0 = *(const float4*)sp;
        float4 f1 = *(const float4*)(sp + 4);
        float v[8] = {f0.x,f0.y,f0.z,f0.w,f1.x,f1.y,f1.z,f1.w};
        unsigned int hu[4], lu[4];
#pragma unroll
        for (int j = 0; j < 4; ++j) {
            hu[j] = pk_bf16(v[2*j], v[2*j+1]);
            float ea = __uint_as_float(hu[j] << 16);
            float eb = __uint_as_float(hu[j] & 0xffff0000u);
            lu[j] = pk_bf16(v[2*j] - ea, v[2*j+1] - eb);
        }
        long off = (long)(row0 + wrow + rloc) * E_ + col0 + wcol + lc8 * 8;
        uint4 hv = {hu[0], hu[1], hu[2], hu[3]};
        uint4 lv = {lu[0], lu[1], lu[2], lu[3]};
        *(uint4*)(AttnHi + off) = hv;
        *(uint4*)(AttnLo + off) = lv;
    }
}

// ---------------- fp32 fallback GEMM (round-2 proven) ----------------
template<int IN_MODE, int OUT_MODE>
__global__ __launch_bounds__(256) void lin_gemm(const float* __restrict__ X,
                                                const float* __restrict__ W,
                                                const float* __restrict__ bias,
                                                float* __restrict__ Y)
{
    __shared__ float As[16][68];
    __shared__ float Ws[16][68];
    const int row0 = blockIdx.x * 64;
    const int col0 = blockIdx.y * 64;
    const int t  = threadIdx.x;
    const int lr = t >> 2;
    const int lk = (t & 3) * 4;
    const int ty = t >> 4, tx = t & 15;

    long arow;
    {
        int r = row0 + lr;
        if (IN_MODE == 0) { int b = r >> 12, n = r & (N_ - 1); arow = (long)(n * B_ + b) * E_; }
        else              { arow = (long)r * E_; }
    }
    const long wrow = (long)(col0 + lr) * E_;

    float acc[4][4] = {};
    for (int e0 = 0; e0 < E_; e0 += 16) {
        float4 av = *(const float4*)(X + arow + e0 + lk);
        float4 wv = *(const float4*)(W + wrow + e0 + lk);
        As[lk+0][lr] = av.x; As[lk+1][lr] = av.y; As[lk+2][lr] = av.z; As[lk+3][lr] = av.w;
        Ws[lk+0][lr] = wv.x; Ws[lk+1][lr] = wv.y; Ws[lk+2][lr] = wv.z; Ws[lk+3][lr] = wv.w;
        __syncthreads();
#pragma unroll
        for (int k = 0; k < 16; ++k) {
            float4 a = *(const float4*)&As[k][ty*4];
            float4 w = *(const float4*)&Ws[k][tx*4];
            float a_[4] = {a.x,a.y,a.z,a.w};
            float w_[4] = {w.x,w.y,w.z,w.w};
#pragma unroll
            for (int i = 0; i < 4; ++i)
#pragma unroll
                for (int j = 0; j < 4; ++j)
                    acc[i][j] = fmaf(a_[i], w_[j], acc[i][j]);
        }
        __syncthreads();
    }
    float4 bvv = *(const float4*)(bias + col0 + tx*4);
    float b_[4] = {bvv.x,bvv.y,bvv.z,bvv.w};
#pragma unroll
    for (int i = 0; i < 4; ++i) {
        int r = row0 + ty*4 + i;
        float4 o;
        o.x = acc[i][0] + b_[0]; o.y = acc[i][1] + b_[1];
        o.z = acc[i][2] + b_[2]; o.w = acc[i][3] + b_[3];
        long off;
        if (OUT_MODE == 0) off = (long)r * E_ + col0 + tx*4;
        else { int b = r >> 12, n = r & (N_ - 1); off = (long)(n * B_ + b) * E_ + col0 + tx*4; }
        *(float4*)(Y + off) = o;
    }
}

// ---------------- favorp dash (fallback, IN-PLACE over [B,N,E]) ----------------
template<int IS_QUERY>
__global__ __launch_bounds__(256) void favorp_dash(float* __restrict__ Xh,
                                                   const float* __restrict__ proj,
                                                   float* __restrict__ stab)
{
    __shared__ float Xs[64][68];
    __shared__ float Ps[64][68];
    __shared__ float diag[64];
    __shared__ float red4[4];
    __shared__ float rowred[64][17];
    const int bh = blockIdx.x, b = bh >> 4, h = bh & 15;
    const int n0 = blockIdx.y * 64;
    const int t = threadIdx.x;
    const int r = t >> 2, c0 = (t & 3) * 16;
    const int ty = t >> 4, tx = t & 15;

    const float* xrow = Xh + (long)(b * N_ + n0 + r) * E_ + h * 64;
    const float* prow = proj + (long)(h * 64 + r) * 64;
#pragma unroll
    for (int c = 0; c < 4; ++c) {
        float4 v = *(const float4*)(xrow + c0 + c*4);
        Xs[c0+c*4+0][r] = v.x; Xs[c0+c*4+1][r] = v.y; Xs[c0+c*4+2][r] = v.z; Xs[c0+c*4+3][r] = v.w;
        float4 p = *(const float4*)(prow + c0 + c*4);
        Ps[c0+c*4+0][r] = p.x; Ps[c0+c*4+1][r] = p.y; Ps[c0+c*4+2][r] = p.z; Ps[c0+c*4+3][r] = p.w;
    }
    __syncthreads();
    if (t < 64) {
        float s = 0.f;
#pragma unroll 16
        for (int d = 0; d < 64; ++d) { float x = Xs[d][t]; s = fmaf(x, x, s); }
        diag[t] = s * DIAG_C;
    }
    __syncthreads();

    float acc[4][4] = {};
#pragma unroll 16
    for (int d = 0; d < 64; ++d) {
        float4 a = *(const float4*)&Xs[d][ty*4];
        float4 p = *(const float4*)&Ps[d][tx*4];
        float a_[4] = {a.x,a.y,a.z,a.w};
        float p_[4] = {p.x,p.y,p.z,p.w};
#pragma unroll
        for (int i = 0; i < 4; ++i)
#pragma unroll
            for (int j = 0; j < 4; ++j)
                acc[i][j] = fmaf(a_[i], p_[j], acc[i][j]);
    }
    float dash[4][4];
#pragma unroll
    for (int i = 0; i < 4; ++i)
#pragma unroll
        for (int j = 0; j < 4; ++j) dash[i][j] = acc[i][j] * NRM_C;

    if (IS_QUERY) {
#pragma unroll
        for (int i = 0; i < 4; ++i) {
            float m = fmaxf(fmaxf(dash[i][0], dash[i][1]), fmaxf(dash[i][2], dash[i][3]));
            rowred[ty*4+i][tx] = m;
        }
        __syncthreads();
#pragma unroll
        for (int i = 0; i < 4; ++i) {
            int row = ty*4 + i;
            float m = rowred[row][0];
#pragma unroll
            for (int jj = 1; jj < 16; ++jj) m = fmaxf(m, rowred[row][jj]);
            float dg = diag[row];
            float4 o;
            o.x = RATIO_C * expf(dash[i][0] - dg - m) + EPSF;
            o.y = RATIO_C * expf(dash[i][1] - dg - m) + EPSF;
            o.z = RATIO_C * expf(dash[i][2] - dg - m) + EPSF;
            o.w = RATIO_C * expf(dash[i][3] - dg - m) + EPSF;
            *(float4*)(Xh + (long)(b * N_ + n0 + row) * E_ + h * 64 + tx*4) = o;
        }
    } else {
        float lmax = dash[0][0];
#pragma unroll
        for (int i = 0; i < 4; ++i)
#pragma unroll
            for (int j = 0; j < 4; ++j) lmax = fmaxf(lmax, dash[i][j]);
#pragma unroll
        for (int i = 0; i < 4; ++i) {
            int row = ty*4 + i;
            float dg = diag[row];
            float4 o = { dash[i][0]-dg, dash[i][1]-dg, dash[i][2]-dg, dash[i][3]-dg };
            *(float4*)(Xh + (long)(b * N_ + n0 + row) * E_ + h * 64 + tx*4) = o;
        }
#pragma unroll
        for (int off = 32; off > 0; off >>= 1) lmax = fmaxf(lmax, __shfl_down(lmax, off));
        if ((t & 63) == 0) red4[t >> 6] = lmax;
        __syncthreads();
        if (t == 0)
            atomicMaxF(&stab[bh], fmaxf(fmaxf(red4[0], red4[1]), fmaxf(red4[2], red4[3])));
    }
}

// ---------------- kv partials ----------------
__global__ __launch_bounds__(256) void kv_partial(const float* __restrict__ T1,
                                                  const float* __restrict__ V,
                                                  const float* __restrict__ stab,
                                                  float* __restrict__ kvp,
                                                  float* __restrict__ ksump)
{
    __shared__ float KPs[16][68];
    __shared__ float Vs[16][68];
    const int bh = blockIdx.x, chunk = blockIdx.y;
    const int b = bh >> 4, h = bh & 15;
    const int t = threadIdx.x;
    const int lr = t >> 4, lm = (t & 15) * 4;
    const int ty = t >> 4, tx = t & 15;
    const float stb = stab[bh];
    float acc[4][4] = {};
    float ks = 0.f;
    const int nbeg = chunk * (N_ / SPLITK), nend = nbeg + (N_ / SPLITK);
    for (int n0 = nbeg; n0 < nend; n0 += 16) {
        long rowoff = (long)(b * N_ + n0 + lr) * E_ + h * 64 + lm;
        float4 tv = *(const float4*)(T1 + rowoff);
        float4 vv = *(const float4*)(V + rowoff);
        KPs[lr][lm+0] = RATIO_C * expf(tv.x - stb) + EPSF;
        KPs[lr][lm+1] = RATIO_C * expf(tv.y - stb) + EPSF;
        KPs[lr][lm+2] = RATIO_C * expf(tv.z - stb) + EPSF;
        KPs[lr][lm+3] = RATIO_C * expf(tv.w - stb) + EPSF;
        *(float4*)&Vs[lr][lm] = vv;
        __syncthreads();
        if (t < 64) {
#pragma unroll
            for (int rr = 0; rr < 16; ++rr) ks += KPs[rr][t];
        }
#pragma unroll
        for (int k = 0; k < 16; ++k) {
            float4 a = *(const float4*)&KPs[k][ty*4];
            float4 v4 = *(const float4*)&Vs[k][tx*4];
            float a_[4] = {a.x,a.y,a.z,a.w};
            float v_[4] = {v4.x,v4.y,v4.z,v4.w};
#pragma unroll
            for (int i = 0; i < 4; ++i)
#pragma unroll
                for (int j = 0; j < 4; ++j)
                    acc[i][j] = fmaf(a_[i], v_[j], acc[i][j]);
        }
        __syncthreads();
    }
    const long kvbase = ((long)chunk * BH_ + bh) * 4096;
#pragma unroll
    for (int i = 0; i < 4; ++i) {
        float4 o = {acc[i][0], acc[i][1], acc[i][2], acc[i][3]};
        *(float4*)(kvp + kvbase + (ty*4+i) * 64 + tx*4) = o;
    }
    if (t < 64) ksump[((long)chunk * BH_ + bh) * 64 + t] = ks;
}

// reduce partials; write kv TRANSPOSED split-bf16 [BH][d][m] + ksum fp32 (+kvM fp32 for fallback)
__global__ __launch_bounds__(256) void kv_reduce(const float* __restrict__ kvp,
                                                 const float* __restrict__ ksump,
                                                 float* __restrict__ kvM,
                                                 float* __restrict__ ksum,
                                                 unsigned short* __restrict__ kvThi,
                                                 unsigned short* __restrict__ kvTlo)
{
    int idx = blockIdx.x * 256 + threadIdx.x;
    if (idx < BH_ * 4096) {
        float s = 0.f;
#pragma unroll
        for (int c = 0; c < SPLITK; ++c) s += kvp[(long)c * BH_ * 4096 + idx];
        kvM[idx] = s;
        int bh = idx >> 12, md = idx & 4095, m = md >> 6, d = md & 63;
        unsigned short h16 = f32_to_bf16(s);
        long toff = (long)bh * 4096 + d * 64 + m;
        kvThi[toff] = h16;
        kvTlo[toff] = f32_to_bf16(s - bf16_to_f32(h16));
    } else {
        int j = idx - BH_ * 4096;
        if (j < BH_ * 64) {
            float s = 0.f;
#pragma unroll
            for (int c = 0; c < SPLITK; ++c) s += ksump[(long)c * BH_ * 64 + j];
            ksum[j] = s;
        }
    }
}

// ---------------- qkv + normalize (fallback only) ----------------
__global__ __launch_bounds__(256) void qkv_attn(const float* __restrict__ Qp,
                                                const float* __restrict__ kvM,
                                                const float* __restrict__ ksum,
                                                float* __restrict__ attn)
{
    __shared__ float QPs[64][68];
    __shared__ float kvs[64][68];
    __shared__ float ksums[64];
    __shared__ float rnorm[64];
    const int bh = blockIdx.x, b = bh >> 4, h = bh & 15;
    const int n0 = blockIdx.y * 64;
    const int t = threadIdx.x;
    const int r = t >> 2, c0 = (t & 3) * 16;
    const int ty = t >> 4, tx = t & 15;

#pragma unroll
    for (int c = 0; c < 4; ++c) {
        int idx = t * 16 + c * 4;
        float4 v = *(const float4*)(kvM + (long)bh * 4096 + idx);
        *(float4*)&kvs[idx >> 6][idx & 63] = v;
    }
    if (t < 64) ksums[t] = ksum[bh * 64 + t];
    const float* qrow = Qp + (long)(b * N_ + n0 + r) * E_ + h * 64;
#pragma unroll
    for (int c = 0; c < 4; ++c) {
        float4 v = *(const float4*)(qrow + c0 + c*4);
        QPs[c0+c*4+0][r] = v.x; QPs[c0+c*4+1][r] = v.y; QPs[c0+c*4+2][r] = v.z; QPs[c0+c*4+3][r] = v.w;
    }
    __syncthreads();
    if (t < 64) {
        float s = 0.f;
#pragma unroll 16
        for (int m = 0; m < 64; ++m) s = fmaf(QPs[m][t], ksums[m], s);
        rnorm[t] = 1.f / fmaxf(s, EPSD);
    }
    __syncthreads();
    float acc[4][4] = {};
#pragma unroll 16
    for (int m = 0; m < 64; ++m) {
        float4 a = *(const float4*)&QPs[m][ty*4];
        float4 v4 = *(const float4*)&kvs[m][tx*4];
        float a_[4] = {a.x,a.y,a.z,a.w};
        float v_[4] = {v4.x,v4.y,v4.z,v4.w};
#pragma unroll
        for (int i = 0; i < 4; ++i)
#pragma unroll
            for (int j = 0; j < 4; ++j)
                acc[i][j] = fmaf(a_[i], v_[j], acc[i][j]);
    }
#pragma unroll
    for (int i = 0; i < 4; ++i) {
        int row = ty*4 + i;
        float rn = rnorm[row];
        float4 o = {acc[i][0]*rn, acc[i][1]*rn, acc[i][2]*rn, acc[i][3]*rn};
        *(float4*)(attn + (long)(b * N_ + n0 + row) * E_ + h * 64 + tx*4) = o;
    }
}

extern "C" void kernel_launch(void* const* d_in, const int* in_sizes, int n_in,
                              void* d_out, int out_size, void* d_ws, size_t ws_size,
                              hipStream_t stream)
{
    const float* query = (const float*)d_in[0];
    const float* key   = (const float*)d_in[1];
    const float* value = (const float*)d_in[2];
    const float* Wq    = (const float*)d_in[3];
    const float* bq    = (const float*)d_in[4];
    const float* Wk    = (const float*)d_in[5];
    const float* bk    = (const float*)d_in[6];
    const float* Wv    = (const float*)d_in[7];
    const float* bv    = (const float*)d_in[8];
    const float* Wo    = (const float*)d_in[9];
    const float* bo    = (const float*)d_in[10];
    const float* proj  = (const float*)d_in[11];
    float* O = (float*)d_out;                 // scratch; fully rewritten by final GEMM

    float* ws = (float*)d_ws;
    const size_t SZ = (size_t)BN_ * E_;       // 16.78M floats
    float* A     = ws;                        // V fp32; later attn (split-bf16 in fast path)
    float* kvp   = ws + SZ;
    float* ksump = kvp + (size_t)SPLITK * BH_ * 4096;
    float* kvM   = ksump + (size_t)SPLITK * BH_ * 64;
    float* ksum  = kvM + (size_t)BH_ * 4096;
    float* stab  = ksum + (size_t)BH_ * 64;
    unsigned short* kvThi = (unsigned short*)(stab + 64);            // BH*4096 ush
    unsigned short* kvTlo = kvThi + (size_t)BH_ * 4096;
    unsigned short* PShi  = kvTlo + (size_t)BH_ * 4096;              // 65536 ush
    unsigned short* PSlo  = PShi + 65536;
    const size_t EXTRA_F = (size_t)BH_ * 4096 /*kvT pair*/ + 65536 /*PS pair*/;
    const size_t COMMON_F = SZ + (size_t)SPLITK * BH_ * 4096 + (size_t)SPLITK * BH_ * 64
                          + (size_t)BH_ * 4096 + (size_t)BH_ * 64 + 64 + EXTRA_F;
    unsigned short* Xhi = (unsigned short*)(ws + COMMON_F);
    unsigned short* Xlo = Xhi + SZ;
    unsigned short* Whi = Xlo + SZ;
    unsigned short* Wlo = Whi + (size_t)E_ * E_;
    const size_t NEED_FAST = (COMMON_F + SZ + (size_t)E_ * E_) * 4;  // bytes

    dim3 gF(BH_, N_ / 64);
    dim3 gKV(BH_, SPLITK);
    const int nRed = (BH_ * 4096 + BH_ * 64) / 256;

    if (ws_size >= NEED_FAST) {
        dim3 gP(BN_ / 256, E_ / 128);    // pipelined GEMM, all modes
        const int X4 = (int)(SZ / 4), W4 = (E_ * E_) / 4;
        unsigned short* AttnHi = (unsigned short*)A;
        unsigned short* AttnLo = AttnHi + SZ;

        (void)hipFuncSetAttribute((const void*)&gemm8p<0>, hipFuncAttributeMaxDynamicSharedMemorySize, SMEM_DYN8);
        (void)hipFuncSetAttribute((const void*)&gemm8p<1>, hipFuncAttributeMaxDynamicSharedMemorySize, SMEM_DYN8);
        (void)hipFuncSetAttribute((const void*)&gemm8p<2>, hipFuncAttributeMaxDynamicSharedMemorySize, SMEM_DYN8);
        (void)hipFuncSetAttribute((const void*)&gemm8p<3>, hipFuncAttributeMaxDynamicSharedMemorySize, SMEM_DYN8);

        convert_split<1><<<64, 256, 0, stream>>>(proj, PShi, PSlo, 16384);
        init_stab<<<1, 64, 0, stream>>>(stab);
        // K chain: pipelined GEMM + fused favorp_k -> T1 (O) + stab
        convert_split<0><<<2048, 256, 0, stream>>>(key, Xhi, Xlo, X4);
        convert_split<1><<<1024, 256, 0, stream>>>(Wk, Whi, Wlo, W4);
        gemm8p<2><<<gP, 512, SMEM_DYN8, stream>>>(Xhi, Xlo, Whi, Wlo, bk, O, stab,
                                                  PShi, PSlo, nullptr, nullptr, nullptr, nullptr, nullptr);
        // V chain
        convert_split<0><<<2048, 256, 0, stream>>>(value, Xhi, Xlo, X4);
        convert_split<1><<<1024, 256, 0, stream>>>(Wv, Whi, Wlo, W4);
        gemm8p<0><<<gP, 512, SMEM_DYN8, stream>>>(Xhi, Xlo, Whi, Wlo, bv, A, nullptr,
                                                  nullptr, nullptr, nullptr, nullptr, nullptr, nullptr, nullptr);
        // kv
        kv_partial<<<gKV, 256, 0, stream>>>(O, A, stab, kvp, ksump);
        kv_reduce<<<nRed, 256, 0, stream>>>(kvp, ksump, kvM, ksum, kvThi, kvTlo);
        // Q chain: pipelined GEMM + fused favorp_q + qkv -> attn split-bf16 (A region)
        convert_split<0><<<2048, 256, 0, stream>>>(query, Xhi, Xlo, X4);
        convert_split<1><<<1024, 256, 0, stream>>>(Wq, Whi, Wlo, W4);
        gemm8p<3><<<gP, 512, SMEM_DYN8, stream>>>(Xhi, Xlo, Whi, Wlo, bq, nullptr, nullptr,
                                                  PShi, PSlo, kvThi, kvTlo, ksum, AttnHi, AttnLo);
        // output GEMM (transposed store)
        convert_split<1><<<1024, 256, 0, stream>>>(Wo, Whi, Wlo, W4);
        gemm8p<1><<<gP, 512, SMEM_DYN8, stream>>>(AttnHi, AttnLo, Whi, Wlo, bo, O, nullptr,
                                                  nullptr, nullptr, nullptr, nullptr, nullptr, nullptr, nullptr);
    } else {
        // fp32 fallback (round-2 proven path)
        dim3 gGemm(BN_ / 64, E_ / 64);
        lin_gemm<0,0><<<gGemm, 256, 0, stream>>>(key, Wk, bk, O);
        init_stab<<<1, 64, 0, stream>>>(stab);
        favorp_dash<0><<<gF, 256, 0, stream>>>(O, proj, stab);
        lin_gemm<0,0><<<gGemm, 256, 0, stream>>>(value, Wv, bv, A);
        kv_partial<<<gKV, 256, 0, stream>>>(O, A, stab, kvp, ksump);
        kv_reduce<<<nRed, 256, 0, stream>>>(kvp, ksump, kvM, ksum, kvThi, kvTlo);
        lin_gemm<0,0><<<gGemm, 256, 0, stream>>>(query, Wq, bq, O);
        favorp_dash<1><<<gF, 256, 0, stream>>>(O, proj, stab);
        qkv_attn<<<gF, 256, 0, stream>>>(O, kvM, ksum, A);
        lin_gemm<1,1><<<gGemm, 256, 0, stream>>>(A, Wo, bo, O);
    }
}

// Round 16
// 561.146 us; speedup vs baseline: 1.0395x; 1.0068x over previous
//
#include <hip/hip_runtime.h>
#include <math.h>

// Problem constants (fixed by setup_inputs)
#define B_   4
#define N_   4096
#define E_   1024
#define H_   16
#define BN_  (B_*N_)
#define BH_  (B_*H_)
#define SPLITK 8

// favorp constants
#define NRM_C   0.35355339059327373f   // 64^-0.25
#define DIAG_C  0.0625f                // 0.5 * NRM^2
#define RATIO_C 0.125f                 // 64^-0.5
#define EPSF    1e-4f
#define EPSD    0.01f

typedef __attribute__((ext_vector_type(8))) short bf16x8;   // 8 bf16 in 4 VGPRs
typedef __attribute__((ext_vector_type(4))) float f32x4;

__device__ __forceinline__ unsigned short f32_to_bf16(float x) {
    unsigned int u = __float_as_uint(x);
    unsigned int r = (u + 0x7fffu + ((u >> 16) & 1u)) >> 16;   // RTN-even
    return (unsigned short)r;
}
__device__ __forceinline__ float bf16_to_f32(unsigned short h) {
    return __uint_as_float(((unsigned int)h) << 16);
}

// packed f32->bf16 via HW instruction; D.lo=bf16(a), D.hi=bf16(b)
__device__ __forceinline__ unsigned int pk_bf16(float a, float b) {
    unsigned int r;
    asm("v_cvt_pk_bf16_f32 %0, %1, %2" : "=v"(r) : "v"(a), "v"(b));
    return r;
}

// 8 fp32 -> split bf16 hi/lo fragments (pk-based)
__device__ __forceinline__ void f32x8_split(float4 fa, float4 fb, bf16x8& hi, bf16x8& lo) {
    unsigned int h0 = pk_bf16(fa.x, fa.y), h1 = pk_bf16(fa.z, fa.w);
    unsigned int h2 = pk_bf16(fb.x, fb.y), h3 = pk_bf16(fb.z, fb.w);
    float e0 = __uint_as_float(h0 << 16), e1 = __uint_as_float(h0 & 0xffff0000u);
    float e2 = __uint_as_float(h1 << 16), e3 = __uint_as_float(h1 & 0xffff0000u);
    float e4 = __uint_as_float(h2 << 16), e5 = __uint_as_float(h2 & 0xffff0000u);
    float e6 = __uint_as_float(h3 << 16), e7 = __uint_as_float(h3 & 0xffff0000u);
    unsigned int l0 = pk_bf16(fa.x - e0, fa.y - e1), l1 = pk_bf16(fa.z - e2, fa.w - e3);
    unsigned int l2 = pk_bf16(fb.x - e4, fb.y - e5), l3 = pk_bf16(fb.z - e6, fb.w - e7);
    union { unsigned int u[4]; bf16x8 v; } H, L;
    H.u[0] = h0; H.u[1] = h1; H.u[2] = h2; H.u[3] = h3;
    L.u[0] = l0; L.u[1] = l1; L.u[2] = l2; L.u[3] = l3;
    hi = H.v; lo = L.v;
}

__device__ __forceinline__ void atomicMaxF(float* addr, float v) {
    if (v >= 0.f) atomicMax((int*)addr, __float_as_int(v));
    else          atomicMin((unsigned int*)addr, __float_as_uint(v));
}

__global__ void init_stab(float* stab) {
    if (threadIdx.x < BH_) stab[threadIdx.x] = -INFINITY;
}

// ---------------- split-bf16 conversion ----------------
template<int IN_MODE>
__global__ __launch_bounds__(256) void convert_split(const float* __restrict__ src,
                                                     unsigned short* __restrict__ hi,
                                                     unsigned short* __restrict__ lo,
                                                     int total4)
{
    int i = blockIdx.x * 256 + threadIdx.x;
    const int stride = gridDim.x * 256;
    for (; i < total4; i += stride) {
        long e4 = (long)i * 4;
        const float* p;
        if (IN_MODE == 0) {
            long r = e4 >> 10; int e = (int)(e4 & 1023);
            int b = (int)(r >> 12), n = (int)(r & 4095);
            p = src + (((long)(n * B_ + b)) << 10) + e;
        } else {
            p = src + e4;
        }
        float4 v = *(const float4*)p;
        ushort4 h, l;
        h.x = f32_to_bf16(v.x); l.x = f32_to_bf16(v.x - bf16_to_f32(h.x));
        h.y = f32_to_bf16(v.y); l.y = f32_to_bf16(v.y - bf16_to_f32(h.y));
        h.z = f32_to_bf16(v.z); l.z = f32_to_bf16(v.z - bf16_to_f32(h.z));
        h.w = f32_to_bf16(v.w); l.w = f32_to_bf16(v.w - bf16_to_f32(h.w));
        *(ushort4*)(hi + e4) = h;
        *(ushort4*)(lo + e4) = l;
    }
}

__device__ __forceinline__ void gl_lds16(const unsigned short* g, unsigned short* l) {
    __builtin_amdgcn_global_load_lds((const __attribute__((address_space(1))) void*)g,
                                     (__attribute__((address_space(3))) void*)l, 16, 0, 0);
}

// =====================================================================
// Fine-phase pipelined GEMM, all modes: 256x128 tile, BK=32, 8 waves,
// 3 LDS buffers (144KB), 2-deep prefetch, counted vmcnt(6) at K boundaries.
// Bank-conflict-free fragment swizzle: slot = g ^ ((row>>1)&3)  (2-way = free).
// 2 merged phases, 1 barrier per K-tile (mid-tile barrier removed — no hazard:
//  sb stable all iter; A/B stage disjoint ub halves; ub reuse ordered by boundary).
// MODE 0: Y fp32 [BN,E];  MODE 1: Y fp32 [N,B,E] transposed;
// MODE 2: K-fused favorp (T1 + stab);  MODE 3: Q-fused favorp_q + qkv -> attn split-bf16.
// =====================================================================
#define SMEM_DYN8 147456

template<int MODE>
__global__ __launch_bounds__(512, 2) void gemm8p(const unsigned short* __restrict__ Ahi,
                                                 const unsigned short* __restrict__ Alo,
                                                 const unsigned short* __restrict__ Bhi,
                                                 const unsigned short* __restrict__ Blo,
                                                 const float* __restrict__ bias,
                                                 float* __restrict__ Y,
                                                 float* __restrict__ stab,
                                                 const unsigned short* __restrict__ PShi,
                                                 const unsigned short* __restrict__ PSlo,
                                                 const unsigned short* __restrict__ kvThi,
                                                 const unsigned short* __restrict__ kvTlo,
                                                 const float* __restrict__ ksum,
                                                 unsigned short* __restrict__ AttnHi,
                                                 unsigned short* __restrict__ AttnLo)
{
    extern __shared__ char SMEM8[];
    unsigned short* U = (unsigned short*)SMEM8;
    const int t = threadIdx.x;
    const int w = t >> 6, lane = t & 63;
    const int row0 = blockIdx.x * 256, col0 = blockIdx.y * 128;
    const int wrow = (w >> 1) * 64, wcol = (w & 1) * 64;
    const int g = lane >> 4, rl = lane & 15;
    const int lr8 = lane >> 3, lc8 = lane & 7;

    // staging address precompute (granule = 16B = 8 shorts)
    // pre-swizzled source: LDS(row r, slot s) holds global k-octet s ^ ((r>>1)&3)
    int gi0 = t, gi1 = 512 + t;
    int ar0 = gi0 >> 2, as0 = gi0 & 3;
    int ar1 = gi1 >> 2, as1 = gi1 & 3;
    const long aSrc0 = (long)(row0 + ar0) * E_ + ((as0 ^ ((ar0 >> 1) & 3)) << 3);
    const long aSrc1 = (long)(row0 + ar1) * E_ + ((as1 ^ ((ar1 >> 1) & 3)) << 3);
    const int aDst0 = (w * 64) * 8;
    const int aDst1 = (512 + w * 64) * 8;
    const long bSrc = (long)(col0 + (t >> 2)) * E_ + (((t & 3) ^ ((t >> 3) & 3)) << 3);
    const int bDst = (w * 64) * 8;

    f32x4 acc[4][4];
#pragma unroll
    for (int m = 0; m < 4; ++m)
#pragma unroll
        for (int n = 0; n < 4; ++n) acc[m][n] = (f32x4){0.f, 0.f, 0.f, 0.f};

#define STAGE_FULL(TILE, BUFI) {                                        \
        const int k0_ = (TILE) * 32;                                    \
        unsigned short* bu_ = U + (BUFI) * 24576;                       \
        gl_lds16(Ahi + aSrc0 + k0_, bu_ + aDst0);                       \
        gl_lds16(Ahi + aSrc1 + k0_, bu_ + aDst1);                       \
        gl_lds16(Alo + aSrc0 + k0_, bu_ + 8192 + aDst0);                \
        gl_lds16(Alo + aSrc1 + k0_, bu_ + 8192 + aDst1);                \
        gl_lds16(Bhi + bSrc + k0_, bu_ + 16384 + bDst);                 \
        gl_lds16(Blo + bSrc + k0_, bu_ + 20480 + bDst); }

    // 12 MFMA for one m-band (order per-acc unchanged: ah*bh, ah*bl, al*bh over n)
#define MBAND(MI, AH, AL)                                                                     \
        _Pragma("unroll")                                                                     \
        for (int n = 0; n < 4; ++n)                                                           \
            acc[MI][n] = __builtin_amdgcn_mfma_f32_16x16x32_bf16(AH, bhf[n], acc[MI][n], 0, 0, 0); \
        _Pragma("unroll")                                                                     \
        for (int n = 0; n < 4; ++n)                                                           \
            acc[MI][n] = __builtin_amdgcn_mfma_f32_16x16x32_bf16(AH, blf[n], acc[MI][n], 0, 0, 0); \
        _Pragma("unroll")                                                                     \
        for (int n = 0; n < 4; ++n)                                                           \
            acc[MI][n] = __builtin_amdgcn_mfma_f32_16x16x32_bf16(AL, bhf[n], acc[MI][n], 0, 0, 0);

    STAGE_FULL(0, 0);
    STAGE_FULL(1, 1);
    asm volatile("s_waitcnt vmcnt(6)" ::: "memory");   // tile 0 landed (own; FIFO)
    __builtin_amdgcn_s_barrier();                      // all waves' tile 0 landed
    __builtin_amdgcn_sched_barrier(0);

    for (int tt = 0; tt < 32; ++tt) {
        const unsigned short* sb = U + (tt % 3) * 24576;
        unsigned short* ub = U + ((tt + 2) % 3) * 24576;
        const bool st = (tt + 2 < 32);
        const int k2 = (tt + 2) * 32;
        bf16x8 bhf[4], blf[4];

        // ---- phase A: B frags + A bands m=0,1; stage A(t+2) (4 loads) ----
#pragma unroll
        for (int n = 0; n < 4; ++n) {
            int r = wcol + n * 16 + rl;
            int off = r * 32 + ((g ^ ((r >> 1) & 3)) << 3);
            bhf[n] = *(const bf16x8*)(sb + 16384 + off);
            blf[n] = *(const bf16x8*)(sb + 20480 + off);
        }
        {
            int r0 = wrow + rl;
            int off0 = r0 * 32 + ((g ^ ((r0 >> 1) & 3)) << 3);
            bf16x8 ah0 = *(const bf16x8*)(sb + off0);
            bf16x8 al0 = *(const bf16x8*)(sb + 8192 + off0);
            int r1 = wrow + 16 + rl;
            int off1 = r1 * 32 + ((g ^ ((r1 >> 1) & 3)) << 3);
            bf16x8 ah1 = *(const bf16x8*)(sb + off1);
            bf16x8 al1 = *(const bf16x8*)(sb + 8192 + off1);
            if (st) { gl_lds16(Ahi + aSrc0 + k2, ub + aDst0);
                      gl_lds16(Ahi + aSrc1 + k2, ub + aDst1);
                      gl_lds16(Alo + aSrc0 + k2, ub + 8192 + aDst0);
                      gl_lds16(Alo + aSrc1 + k2, ub + 8192 + aDst1); }
            asm volatile("s_waitcnt lgkmcnt(0)" ::: "memory");
            __builtin_amdgcn_sched_barrier(0);
            __builtin_amdgcn_s_setprio(1);
            MBAND(0, ah0, al0)
            MBAND(1, ah1, al1)
            __builtin_amdgcn_s_setprio(0);
        }
        // (mid-tile barrier removed — see header hazard analysis)

        // ---- phase B: A bands m=2,3; stage B(t+2) (2 loads); boundary wait ----
        {
            int r2 = wrow + 32 + rl;
            int off2 = r2 * 32 + ((g ^ ((r2 >> 1) & 3)) << 3);
            bf16x8 ah2 = *(const bf16x8*)(sb + off2);
            bf16x8 al2 = *(const bf16x8*)(sb + 8192 + off2);
            int r3 = wrow + 48 + rl;
            int off3 = r3 * 32 + ((g ^ ((r3 >> 1) & 3)) << 3);
            bf16x8 ah3 = *(const bf16x8*)(sb + off3);
            bf16x8 al3 = *(const bf16x8*)(sb + 8192 + off3);
            if (st) { gl_lds16(Bhi + bSrc + k2, ub + 16384 + bDst);
                      gl_lds16(Blo + bSrc + k2, ub + 20480 + bDst); }
            asm volatile("s_waitcnt lgkmcnt(0)" ::: "memory");
            __builtin_amdgcn_sched_barrier(0);
            __builtin_amdgcn_s_setprio(1);
            MBAND(2, ah2, al2)
            MBAND(3, ah3, al3)
            __builtin_amdgcn_s_setprio(0);
        }
        if (tt < 31) {
            if (st) asm volatile("s_waitcnt vmcnt(6)" ::: "memory");
            else    asm volatile("s_waitcnt vmcnt(0)" ::: "memory");
            __builtin_amdgcn_s_barrier();
            __builtin_amdgcn_sched_barrier(0);
        }
    }
#undef STAGE_FULL
#undef MBAND

    float bv[4];
#pragma unroll
    for (int n = 0; n < 4; ++n) bv[n] = bias[col0 + wcol + n * 16 + rl];

    if (MODE <= 1) {
        // plain epilogue: direct stores from acc registers
#pragma unroll
        for (int m = 0; m < 4; ++m) {
            int rbase = row0 + wrow + m * 16 + g * 4;
#pragma unroll
            for (int n = 0; n < 4; ++n) {
                int c = col0 + wcol + n * 16 + rl;
#pragma unroll
                for (int q = 0; q < 4; ++q) {
                    int r = rbase + q;
                    float v = acc[m][n][q] + bv[n];
                    long off;
                    if (MODE == 0) off = (long)r * E_ + c;
                    else { int b = r >> 12, nn = r & (N_ - 1); off = (long)(nn * B_ + b) * E_ + c; }
                    Y[off] = v;
                }
            }
        }
        return;
    }

    // ---------------- fused favorp epilogue (MODE 2 / 3) ----------------
    __syncthreads();   // all waves done with staging LDS; overlay accF
    float* accF  = (float*)SMEM8 + w * (64 * 68);              // wave-private [64][68]
    float* diagL = (float*)(SMEM8 + 139264) + w * 64;
    float* rnmL  = (float*)(SMEM8 + 139264 + 2048) + w * 64;
    const int b_idx = row0 >> 12;
    const int hg = (col0 >> 6) + (w & 1);                      // global head 0..15
    const int bh_i = b_idx * H_ + hg;

    // hoisted PS fragment loads — band-invariant
    bf16x8 pbh[8], pbl[8];
#pragma unroll
    for (int n = 0; n < 4; ++n)
#pragma unroll
        for (int kk = 0; kk < 2; ++kk) {
            long po = (long)hg * 4096 + (n*16 + rl) * 64 + kk*32 + g*8;
            pbh[n*2+kk] = *(const bf16x8*)(PShi + po);
            pbl[n*2+kk] = *(const bf16x8*)(PSlo + po);
        }

#pragma unroll
    for (int m = 0; m < 4; ++m)
#pragma unroll
        for (int n = 0; n < 4; ++n)
#pragma unroll
            for (int q = 0; q < 4; ++q)
                accF[(m*16 + g*4 + q) * 68 + n*16 + rl] = acc[m][n][q] + bv[n];
    {
        float s = 0.f;
#pragma unroll 16
        for (int d = 0; d < 64; ++d) { float x = accF[lane * 68 + d]; s = fmaf(x, x, s); }
        diagL[lane] = s * DIAG_C;
    }
    __syncthreads();

    float wavemax = -INFINITY;
#pragma unroll
    for (int mi = 0; mi < 4; ++mi) {
        bf16x8 dah[2], dal[2];
#pragma unroll
        for (int kk = 0; kk < 2; ++kk) {
            const float* src = &accF[(mi*16 + rl) * 68 + kk*32 + g*8];
            float4 f0 = *(const float4*)src, f1 = *(const float4*)(src + 4);
            f32x8_split(f0, f1, dah[kk], dal[kk]);
        }
        f32x4 dacc[4];
#pragma unroll
        for (int n = 0; n < 4; ++n) dacc[n] = (f32x4){0.f,0.f,0.f,0.f};
#pragma unroll
        for (int n = 0; n < 4; ++n)
#pragma unroll
            for (int kk = 0; kk < 2; ++kk) {
                dacc[n] = __builtin_amdgcn_mfma_f32_16x16x32_bf16(dah[kk], pbh[n*2+kk], dacc[n], 0, 0, 0);
                dacc[n] = __builtin_amdgcn_mfma_f32_16x16x32_bf16(dah[kk], pbl[n*2+kk], dacc[n], 0, 0, 0);
                dacc[n] = __builtin_amdgcn_mfma_f32_16x16x32_bf16(dal[kk], pbh[n*2+kk], dacc[n], 0, 0, 0);
            }
        if (MODE == 2) {
#pragma unroll
            for (int n = 0; n < 4; ++n)
#pragma unroll
                for (int q = 0; q < 4; ++q) {
                    float dsh = dacc[n][q] * NRM_C;
                    wavemax = fmaxf(wavemax, dsh);
                    int rloc = mi*16 + g*4 + q;
                    accF[rloc * 68 + n*16 + rl] = dsh - diagL[rloc];
                }
        } else {
            float rm0 = -INFINITY, rm1 = -INFINITY, rm2 = -INFINITY, rm3 = -INFINITY;
#pragma unroll
            for (int n = 0; n < 4; ++n) {
                rm0 = fmaxf(rm0, dacc[n][0]); rm1 = fmaxf(rm1, dacc[n][1]);
                rm2 = fmaxf(rm2, dacc[n][2]); rm3 = fmaxf(rm3, dacc[n][3]);
            }
#pragma unroll
            for (int off = 1; off < 16; off <<= 1) {
                rm0 = fmaxf(rm0, __shfl_xor(rm0, off));
                rm1 = fmaxf(rm1, __shfl_xor(rm1, off));
                rm2 = fmaxf(rm2, __shfl_xor(rm2, off));
                rm3 = fmaxf(rm3, __shfl_xor(rm3, off));
            }
            float rmq[4] = {rm0 * NRM_C, rm1 * NRM_C, rm2 * NRM_C, rm3 * NRM_C};
#pragma unroll
            for (int n = 0; n < 4; ++n)
#pragma unroll
                for (int q = 0; q < 4; ++q) {
                    int rloc = mi*16 + g*4 + q;
                    float qp = RATIO_C * expf(dacc[n][q] * NRM_C - diagL[rloc] - rmq[q]) + EPSF;
                    accF[rloc * 68 + n*16 + rl] = qp;
                }
        }
    }

    if (MODE == 2) {
#pragma unroll
        for (int off = 1; off < 64; off <<= 1) wavemax = fmaxf(wavemax, __shfl_xor(wavemax, off));
        if (lane == 0) atomicMaxF(&stab[bh_i], wavemax);
#pragma unroll
        for (int pass = 0; pass < 8; ++pass) {
            int rloc = pass * 8 + lr8;
            const float* sp = &accF[rloc * 68 + lc8 * 8];
            float4 f0 = *(const float4*)sp;
            float4 f1 = *(const float4*)(sp + 4);
            long off = (long)(row0 + wrow + rloc) * E_ + col0 + wcol + lc8 * 8;
            *(float4*)(Y + off) = f0;
            *(float4*)(Y + off + 4) = f1;
        }
        return;
    }

    // MODE 3: normalizer, then qkv via MFMA against kvT
    {
        float s = 0.f;
        const float* kb = ksum + bh_i * 64;
#pragma unroll 16
        for (int m = 0; m < 64; ++m) s = fmaf(accF[lane * 68 + m], kb[m], s);
        rnmL[lane] = 1.f / fmaxf(s, EPSD);
    }
    bf16x8 kbh[8], kbl[8];
#pragma unroll
    for (int n = 0; n < 4; ++n)
#pragma unroll
        for (int kk = 0; kk < 2; ++kk) {
            long ko = (long)bh_i * 4096 + (n*16 + rl) * 64 + kk*32 + g*8;
            kbh[n*2+kk] = *(const bf16x8*)(kvThi + ko);
            kbl[n*2+kk] = *(const bf16x8*)(kvTlo + ko);
        }
    __syncthreads();
#pragma unroll
    for (int mi = 0; mi < 4; ++mi) {
        bf16x8 qah[2], qal[2];
#pragma unroll
        for (int kk = 0; kk < 2; ++kk) {
            const float* src = &accF[(mi*16 + rl) * 68 + kk*32 + g*8];
            float4 f0 = *(const float4*)src, f1 = *(const float4*)(src + 4);
            f32x8_split(f0, f1, qah[kk], qal[kk]);
        }
        f32x4 oacc[4];
#pragma unroll
        for (int n = 0; n < 4; ++n) oacc[n] = (f32x4){0.f,0.f,0.f,0.f};
#pragma unroll
        for (int n = 0; n < 4; ++n)
#pragma unroll
            for (int kk = 0; kk < 2; ++kk) {
                oacc[n] = __builtin_amdgcn_mfma_f32_16x16x32_bf16(qah[kk], kbh[n*2+kk], oacc[n], 0, 0, 0);
                oacc[n] = __builtin_amdgcn_mfma_f32_16x16x32_bf16(qah[kk], kbl[n*2+kk], oacc[n], 0, 0, 0);
                oacc[n] = __builtin_amdgcn_mfma_f32_16x16x32_bf16(qal[kk], kbh[n*2+kk], oacc[n], 0, 0, 0);
            }
#pragma unroll
        for (int n = 0; n < 4; ++n)
#pragma unroll
            for (int q = 0; q < 4; ++q) {
                int rloc = mi*16 + g*4 + q;
                accF[rloc * 68 + n*16 + rl] = oacc[n][q] * rnmL[rloc];
            }
    }
#pragma unroll
    for (int pass = 0; pass < 8; ++pass) {
        int rloc = pass * 8 + lr8;
        const float* sp = &accF[rloc * 68 + lc8 * 8];
        float4 f0 = *(const float4*)sp;
        float4 f1 = *(const float4*)(sp + 4);
        float v[8] = {f0.x,f0.y,f0.z,f0.w,f1.x,f1.y,f1.z,f1.w};
        unsigned int hu[4], lu[4];
#pragma unroll
        for (int j = 0; j < 4; ++j) {
            hu[j] = pk_bf16(v[2*j], v[2*j+1]);
            float ea = __uint_as_float(hu[j] << 16);
            float eb = __uint_as_float(hu[j] & 0xffff0000u);
            lu[j] = pk_bf16(v[2*j] - ea, v[2*j+1] - eb);
        }
        long off = (long)(row0 + wrow + rloc) * E_ + col0 + wcol + lc8 * 8;
        uint4 hv = {hu[0], hu[1], hu[2], hu[3]};
        uint4 lv = {lu[0], lu[1], lu[2], lu[3]};
        *(uint4*)(AttnHi + off) = hv;
        *(uint4*)(AttnLo + off) = lv;
    }
}

// ---------------- fp32 fallback GEMM (round-2 proven) ----------------
template<int IN_MODE, int OUT_MODE>
__global__ __launch_bounds__(256) void lin_gemm(const float* __restrict__ X,
                                                const float* __restrict__ W,
                                                const float* __restrict__ bias,
                                                float* __restrict__ Y)
{
    __shared__ float As[16][68];
    __shared__ float Ws[16][68];
    const int row0 = blockIdx.x * 64;
    const int col0 = blockIdx.y * 64;
    const int t  = threadIdx.x;
    const int lr = t >> 2;
    const int lk = (t & 3) * 4;
    const int ty = t >> 4, tx = t & 15;

    long arow;
    {
        int r = row0 + lr;
        if (IN_MODE == 0) { int b = r >> 12, n = r & (N_ - 1); arow = (long)(n * B_ + b) * E_; }
        else              { arow = (long)r * E_; }
    }
    const long wrow = (long)(col0 + lr) * E_;

    float acc[4][4] = {};
    for (int e0 = 0; e0 < E_; e0 += 16) {
        float4 av = *(const float4*)(X + arow + e0 + lk);
        float4 wv = *(const float4*)(W + wrow + e0 + lk);
        As[lk+0][lr] = av.x; As[lk+1][lr] = av.y; As[lk+2][lr] = av.z; As[lk+3][lr] = av.w;
        Ws[lk+0][lr] = wv.x; Ws[lk+1][lr] = wv.y; Ws[lk+2][lr] = wv.z; Ws[lk+3][lr] = wv.w;
        __syncthreads();
#pragma unroll
        for (int k = 0; k < 16; ++k) {
            float4 a = *(const float4*)&As[k][ty*4];
            float4 w = *(const float4*)&Ws[k][tx*4];
            float a_[4] = {a.x,a.y,a.z,a.w};
            float w_[4] = {w.x,w.y,w.z,w.w};
#pragma unroll
            for (int i = 0; i < 4; ++i)
#pragma unroll
                for (int j = 0; j < 4; ++j)
                    acc[i][j] = fmaf(a_[i], w_[j], acc[i][j]);
        }
        __syncthreads();
    }
    float4 bvv = *(const float4*)(bias + col0 + tx*4);
    float b_[4] = {bvv.x,bvv.y,bvv.z,bvv.w};
#pragma unroll
    for (int i = 0; i < 4; ++i) {
        int r = row0 + ty*4 + i;
        float4 o;
        o.x = acc[i][0] + b_[0]; o.y = acc[i][1] + b_[1];
        o.z = acc[i][2] + b_[2]; o.w = acc[i][3] + b_[3];
        long off;
        if (OUT_MODE == 0) off = (long)r * E_ + col0 + tx*4;
        else { int b = r >> 12, n = r & (N_ - 1); off = (long)(n * B_ + b) * E_ + col0 + tx*4; }
        *(float4*)(Y + off) = o;
    }
}

// ---------------- favorp dash (fallback, IN-PLACE over [B,N,E]) ----------------
template<int IS_QUERY>
__global__ __launch_bounds__(256) void favorp_dash(float* __restrict__ Xh,
                                                   const float* __restrict__ proj,
                                                   float* __restrict__ stab)
{
    __shared__ float Xs[64][68];
    __shared__ float Ps[64][68];
    __shared__ float diag[64];
    __shared__ float red4[4];
    __shared__ float rowred[64][17];
    const int bh = blockIdx.x, b = bh >> 4, h = bh & 15;
    const int n0 = blockIdx.y * 64;
    const int t = threadIdx.x;
    const int r = t >> 2, c0 = (t & 3) * 16;
    const int ty = t >> 4, tx = t & 15;

    const float* xrow = Xh + (long)(b * N_ + n0 + r) * E_ + h * 64;
    const float* prow = proj + (long)(h * 64 + r) * 64;
#pragma unroll
    for (int c = 0; c < 4; ++c) {
        float4 v = *(const float4*)(xrow + c0 + c*4);
        Xs[c0+c*4+0][r] = v.x; Xs[c0+c*4+1][r] = v.y; Xs[c0+c*4+2][r] = v.z; Xs[c0+c*4+3][r] = v.w;
        float4 p = *(const float4*)(prow + c0 + c*4);
        Ps[c0+c*4+0][r] = p.x; Ps[c0+c*4+1][r] = p.y; Ps[c0+c*4+2][r] = p.z; Ps[c0+c*4+3][r] = p.w;
    }
    __syncthreads();
    if (t < 64) {
        float s = 0.f;
#pragma unroll 16
        for (int d = 0; d < 64; ++d) { float x = Xs[d][t]; s = fmaf(x, x, s); }
        diag[t] = s * DIAG_C;
    }
    __syncthreads();

    float acc[4][4] = {};
#pragma unroll 16
    for (int d = 0; d < 64; ++d) {
        float4 a = *(const float4*)&Xs[d][ty*4];
        float4 p = *(const float4*)&Ps[d][tx*4];
        float a_[4] = {a.x,a.y,a.z,a.w};
        float p_[4] = {p.x,p.y,p.z,p.w};
#pragma unroll
        for (int i = 0; i < 4; ++i)
#pragma unroll
            for (int j = 0; j < 4; ++j)
                acc[i][j] = fmaf(a_[i], p_[j], acc[i][j]);
    }
    float dash[4][4];
#pragma unroll
    for (int i = 0; i < 4; ++i)
#pragma unroll
        for (int j = 0; j < 4; ++j) dash[i][j] = acc[i][j] * NRM_C;

    if (IS_QUERY) {
#pragma unroll
        for (int i = 0; i < 4; ++i) {
            float m = fmaxf(fmaxf(dash[i][0], dash[i][1]), fmaxf(dash[i][2], dash[i][3]));
            rowred[ty*4+i][tx] = m;
        }
        __syncthreads();
#pragma unroll
        for (int i = 0; i < 4; ++i) {
            int row = ty*4 + i;
            float m = rowred[row][0];
#pragma unroll
            for (int jj = 1; jj < 16; ++jj) m = fmaxf(m, rowred[row][jj]);
            float dg = diag[row];
            float4 o;
            o.x = RATIO_C * expf(dash[i][0] - dg - m) + EPSF;
            o.y = RATIO_C * expf(dash[i][1] - dg - m) + EPSF;
            o.z = RATIO_C * expf(dash[i][2] - dg - m) + EPSF;
            o.w = RATIO_C * expf(dash[i][3] - dg - m) + EPSF;
            *(float4*)(Xh + (long)(b * N_ + n0 + row) * E_ + h * 64 + tx*4) = o;
        }
    } else {
        float lmax = dash[0][0];
#pragma unroll
        for (int i = 0; i < 4; ++i)
#pragma unroll
            for (int j = 0; j < 4; ++j) lmax = fmaxf(lmax, dash[i][j]);
#pragma unroll
        for (int i = 0; i < 4; ++i) {
            int row = ty*4 + i;
            float dg = diag[row];
            float4 o = { dash[i][0]-dg, dash[i][1]-dg, dash[i][2]-dg, dash[i][3]-dg };
            *(float4*)(Xh + (long)(b * N_ + n0 + row) * E_ + h * 64 + tx*4) = o;
        }
#pragma unroll
        for (int off = 32; off > 0; off >>= 1) lmax = fmaxf(lmax, __shfl_down(lmax, off));
        if ((t & 63) == 0) red4[t >> 6] = lmax;
        __syncthreads();
        if (t == 0)
            atomicMaxF(&stab[bh], fmaxf(fmaxf(red4[0], red4[1]), fmaxf(red4[2], red4[3])));
    }
}

// ---------------- kv partials ----------------
__global__ __launch_bounds__(256) void kv_partial(const float* __restrict__ T1,
                                                  const float* __restrict__ V,
                                                  const float* __restrict__ stab,
                                                  float* __restrict__ kvp,
                                                  float* __restrict__ ksump)
{
    __shared__ float KPs[16][68];
    __shared__ float Vs[16][68];
    const int bh = blockIdx.x, chunk = blockIdx.y;
    const int b = bh >> 4, h = bh & 15;
    const int t = threadIdx.x;
    const int lr = t >> 4, lm = (t & 15) * 4;
    const int ty = t >> 4, tx = t & 15;
    const float stb = stab[bh];
    float acc[4][4] = {};
    float ks = 0.f;
    const int nbeg = chunk * (N_ / SPLITK), nend = nbeg + (N_ / SPLITK);
    for (int n0 = nbeg; n0 < nend; n0 += 16) {
        long rowoff = (long)(b * N_ + n0 + lr) * E_ + h * 64 + lm;
        float4 tv = *(const float4*)(T1 + rowoff);
        float4 vv = *(const float4*)(V + rowoff);
        KPs[lr][lm+0] = RATIO_C * expf(tv.x - stb) + EPSF;
        KPs[lr][lm+1] = RATIO_C * expf(tv.y - stb) + EPSF;
        KPs[lr][lm+2] = RATIO_C * expf(tv.z - stb) + EPSF;
        KPs[lr][lm+3] = RATIO_C * expf(tv.w - stb) + EPSF;
        *(float4*)&Vs[lr][lm] = vv;
        __syncthreads();
        if (t < 64) {
#pragma unroll
            for (int rr = 0; rr < 16; ++rr) ks += KPs[rr][t];
        }
#pragma unroll
        for (int k = 0; k < 16; ++k) {
            float4 a = *(const float4*)&KPs[k][ty*4];
            float4 v4 = *(const float4*)&Vs[k][tx*4];
            float a_[4] = {a.x,a.y,a.z,a.w};
            float v_[4] = {v4.x,v4.y,v4.z,v4.w};
#pragma unroll
            for (int i = 0; i < 4; ++i)
#pragma unroll
                for (int j = 0; j < 4; ++j)
                    acc[i][j] = fmaf(a_[i], v_[j], acc[i][j]);
        }
        __syncthreads();
    }
    const long kvbase = ((long)chunk * BH_ + bh) * 4096;
#pragma unroll
    for (int i = 0; i < 4; ++i) {
        float4 o = {acc[i][0], acc[i][1], acc[i][2], acc[i][3]};
        *(float4*)(kvp + kvbase + (ty*4+i) * 64 + tx*4) = o;
    }
    if (t < 64) ksump[((long)chunk * BH_ + bh) * 64 + t] = ks;
}

// reduce partials; write kv TRANSPOSED split-bf16 [BH][d][m] + ksum fp32 (+kvM fp32 for fallback)
__global__ __launch_bounds__(256) void kv_reduce(const float* __restrict__ kvp,
                                                 const float* __restrict__ ksump,
                                                 float* __restrict__ kvM,
                                                 float* __restrict__ ksum,
                                                 unsigned short* __restrict__ kvThi,
                                                 unsigned short* __restrict__ kvTlo)
{
    int idx = blockIdx.x * 256 + threadIdx.x;
    if (idx < BH_ * 4096) {
        float s = 0.f;
#pragma unroll
        for (int c = 0; c < SPLITK; ++c) s += kvp[(long)c * BH_ * 4096 + idx];
        kvM[idx] = s;
        int bh = idx >> 12, md = idx & 4095, m = md >> 6, d = md & 63;
        unsigned short h16 = f32_to_bf16(s);
        long toff = (long)bh * 4096 + d * 64 + m;
        kvThi[toff] = h16;
        kvTlo[toff] = f32_to_bf16(s - bf16_to_f32(h16));
    } else {
        int j = idx - BH_ * 4096;
        if (j < BH_ * 64) {
            float s = 0.f;
#pragma unroll
            for (int c = 0; c < SPLITK; ++c) s += ksump[(long)c * BH_ * 64 + j];
            ksum[j] = s;
        }
    }
}

// ---------------- qkv + normalize (fallback only) ----------------
__global__ __launch_bounds__(256) void qkv_attn(const float* __restrict__ Qp,
                                                const float* __restrict__ kvM,
                                                const float* __restrict__ ksum,
                                                float* __restrict__ attn)
{
    __shared__ float QPs[64][68];
    __shared__ float kvs[64][68];
    __shared__ float ksums[64];
    __shared__ float rnorm[64];
    const int bh = blockIdx.x, b = bh >> 4, h = bh & 15;
    const int n0 = blockIdx.y * 64;
    const int t = threadIdx.x;
    const int r = t >> 2, c0 = (t & 3) * 16;
    const int ty = t >> 4, tx = t & 15;

#pragma unroll
    for (int c = 0; c < 4; ++c) {
        int idx = t * 16 + c * 4;
        float4 v = *(const float4*)(kvM + (long)bh * 4096 + idx);
        *(float4*)&kvs[idx >> 6][idx & 63] = v;
    }
    if (t < 64) ksums[t] = ksum[bh * 64 + t];
    const float* qrow = Qp + (long)(b * N_ + n0 + r) * E_ + h * 64;
#pragma unroll
    for (int c = 0; c < 4; ++c) {
        float4 v = *(const float4*)(qrow + c0 + c*4);
        QPs[c0+c*4+0][r] = v.x; QPs[c0+c*4+1][r] = v.y; QPs[c0+c*4+2][r] = v.z; QPs[c0+c*4+3][r] = v.w;
    }
    __syncthreads();
    if (t < 64) {
        float s = 0.f;
#pragma unroll 16
        for (int m = 0; m < 64; ++m) s = fmaf(QPs[m][t], ksums[m], s);
        rnorm[t] = 1.f / fmaxf(s, EPSD);
    }
    __syncthreads();
    float acc[4][4] = {};
#pragma unroll 16
    for (int m = 0; m < 64; ++m) {
        float4 a = *(const float4*)&QPs[m][ty*4];
        float4 v4 = *(const float4*)&kvs[m][tx*4];
        float a_[4] = {a.x,a.y,a.z,a.w};
        float v_[4] = {v4.x,v4.y,v4.z,v4.w};
#pragma unroll
        for (int i = 0; i < 4; ++i)
#pragma unroll
            for (int j = 0; j < 4; ++j)
                acc[i][j] = fmaf(a_[i], v_[j], acc[i][j]);
    }
#pragma unroll
    for (int i = 0; i < 4; ++i) {
        int row = ty*4 + i;
        float rn = rnorm[row];
        float4 o = {acc[i][0]*rn, acc[i][1]*rn, acc[i][2]*rn, acc[i][3]*rn};
        *(float4*)(attn + (long)(b * N_ + n0 + row) * E_ + h * 64 + tx*4) = o;
    }
}

extern "C" void kernel_launch(void* const* d_in, const int* in_sizes, int n_in,
                              void* d_out, int out_size, void* d_ws, size_t ws_size,
                              hipStream_t stream)
{
    const float* query = (const float*)d_in[0];
    const float* key   = (const float*)d_in[1];
    const float* value = (const float*)d_in[2];
    const float* Wq    = (const float*)d_in[3];
    const float* bq    = (const float*)d_in[4];
    const float* Wk    = (const float*)d_in[5];
    const float* bk    = (const float*)d_in[6];
    const float* Wv    = (const float*)d_in[7];
    const float* bv    = (const float*)d_in[8];
    const float* Wo    = (const float*)d_in[9];
    const float* bo    = (const float*)d_in[10];
    const float* proj  = (const float*)d_in[11];
    float* O = (float*)d_out;                 // scratch; fully rewritten by final GEMM

    float* ws = (float*)d_ws;
    const size_t SZ = (size_t)BN_ * E_;       // 16.78M floats
    float* A     = ws;                        // V fp32; later attn (split-bf16 in fast path)
    float* kvp   = ws + SZ;
    float* ksump = kvp + (size_t)SPLITK * BH_ * 4096;
    float* kvM   = ksump + (size_t)SPLITK * BH_ * 64;
    float* ksum  = kvM + (size_t)BH_ * 4096;
    float* stab  = ksum + (size_t)BH_ * 64;
    unsigned short* kvThi = (unsigned short*)(stab + 64);            // BH*4096 ush
    unsigned short* kvTlo = kvThi + (size_t)BH_ * 4096;
    unsigned short* PShi  = kvTlo + (size_t)BH_ * 4096;              // 65536 ush
    unsigned short* PSlo  = PShi + 65536;
    const size_t EXTRA_F = (size_t)BH_ * 4096 /*kvT pair*/ + 65536 /*PS pair*/;
    const size_t COMMON_F = SZ + (size_t)SPLITK * BH_ * 4096 + (size_t)SPLITK * BH_ * 64
                          + (size_t)BH_ * 4096 + (size_t)BH_ * 64 + 64 + EXTRA_F;
    unsigned short* Xhi = (unsigned short*)(ws + COMMON_F);
    unsigned short* Xlo = Xhi + SZ;
    unsigned short* Whi = Xlo + SZ;
    unsigned short* Wlo = Whi + (size_t)E_ * E_;
    const size_t NEED_FAST = (COMMON_F + SZ + (size_t)E_ * E_) * 4;  // bytes

    dim3 gF(BH_, N_ / 64);
    dim3 gKV(BH_, SPLITK);
    const int nRed = (BH_ * 4096 + BH_ * 64) / 256;

    if (ws_size >= NEED_FAST) {
        dim3 gP(BN_ / 256, E_ / 128);    // pipelined GEMM, all modes
        const int X4 = (int)(SZ / 4), W4 = (E_ * E_) / 4;
        unsigned short* AttnHi = (unsigned short*)A;
        unsigned short* AttnLo = AttnHi + SZ;

        (void)hipFuncSetAttribute((const void*)&gemm8p<0>, hipFuncAttributeMaxDynamicSharedMemorySize, SMEM_DYN8);
        (void)hipFuncSetAttribute((const void*)&gemm8p<1>, hipFuncAttributeMaxDynamicSharedMemorySize, SMEM_DYN8);
        (void)hipFuncSetAttribute((const void*)&gemm8p<2>, hipFuncAttributeMaxDynamicSharedMemorySize, SMEM_DYN8);
        (void)hipFuncSetAttribute((const void*)&gemm8p<3>, hipFuncAttributeMaxDynamicSharedMemorySize, SMEM_DYN8);

        convert_split<1><<<64, 256, 0, stream>>>(proj, PShi, PSlo, 16384);
        init_stab<<<1, 64, 0, stream>>>(stab);
        // K chain: pipelined GEMM + fused favorp_k -> T1 (O) + stab
        convert_split<0><<<2048, 256, 0, stream>>>(key, Xhi, Xlo, X4);
        convert_split<1><<<1024, 256, 0, stream>>>(Wk, Whi, Wlo, W4);
        gemm8p<2><<<gP, 512, SMEM_DYN8, stream>>>(Xhi, Xlo, Whi, Wlo, bk, O, stab,
                                                  PShi, PSlo, nullptr, nullptr, nullptr, nullptr, nullptr);
        // V chain
        convert_split<0><<<2048, 256, 0, stream>>>(value, Xhi, Xlo, X4);
        convert_split<1><<<1024, 256, 0, stream>>>(Wv, Whi, Wlo, W4);
        gemm8p<0><<<gP, 512, SMEM_DYN8, stream>>>(Xhi, Xlo, Whi, Wlo, bv, A, nullptr,
                                                  nullptr, nullptr, nullptr, nullptr, nullptr, nullptr, nullptr);
        // kv
        kv_partial<<<gKV, 256, 0, stream>>>(O, A, stab, kvp, ksump);
        kv_reduce<<<nRed, 256, 0, stream>>>(kvp, ksump, kvM, ksum, kvThi, kvTlo);
        // Q chain: pipelined GEMM + fused favorp_q + qkv -> attn split-bf16 (A region)
        convert_split<0><<<2048, 256, 0, stream>>>(query, Xhi, Xlo, X4);
        convert_split<1><<<1024, 256, 0, stream>>>(Wq, Whi, Wlo, W4);
        gemm8p<3><<<gP, 512, SMEM_DYN8, stream>>>(Xhi, Xlo, Whi, Wlo, bq, nullptr, nullptr,
                                                  PShi, PSlo, kvThi, kvTlo, ksum, AttnHi, AttnLo);
        // output GEMM (transposed store)
        convert_split<1><<<1024, 256, 0, stream>>>(Wo, Whi, Wlo, W4);
        gemm8p<1><<<gP, 512, SMEM_DYN8, stream>>>(AttnHi, AttnLo, Whi, Wlo, bo, O, nullptr,
                                                  nullptr, nullptr, nullptr, nullptr, nullptr, nullptr, nullptr);
    } else {
        // fp32 fallback (round-2 proven path)
        dim3 gGemm(BN_ / 64, E_ / 64);
        lin_gemm<0,0><<<gGemm, 256, 0, stream>>>(key, Wk, bk, O);
        init_stab<<<1, 64, 0, stream>>>(stab);
        favorp_dash<0><<<gF, 256, 0, stream>>>(O, proj, stab);
        lin_gemm<0,0><<<gGemm, 256, 0, stream>>>(value, Wv, bv, A);
        kv_partial<<<gKV, 256, 0, stream>>>(O, A, stab, kvp, ksump);
        kv_reduce<<<nRed, 256, 0, stream>>>(kvp, ksump, kvM, ksum, kvThi, kvTlo);
        lin_gemm<0,0><<<gGemm, 256, 0, stream>>>(query, Wq, bq, O);
        favorp_dash<1><<<gF, 256, 0, stream>>>(O, proj, stab);
        qkv_attn<<<gF, 256, 0, stream>>>(O, kvM, ksum, A);
        lin_gemm<1,1><<<gGemm, 256, 0, stream>>>(A, Wo, bo, O);
    }
}

// Round 17
// 560.193 us; speedup vs baseline: 1.0413x; 1.0017x over previous
//
#include <hip/hip_runtime.h>
#include <math.h>

// Problem constants (fixed by setup_inputs)
#define B_   4
#define N_   4096
#define E_   1024
#define H_   16
#define BN_  (B_*N_)
#define BH_  (B_*H_)
#define SPLITK 8

// favorp constants
#define NRM_C   0.35355339059327373f   // 64^-0.25
#define DIAG_C  0.0625f                // 0.5 * NRM^2
#define RATIO_C 0.125f                 // 64^-0.5
#define EPSF    1e-4f
#define EPSD    0.01f

typedef __attribute__((ext_vector_type(8))) short bf16x8;   // 8 bf16 in 4 VGPRs
typedef __attribute__((ext_vector_type(4))) float f32x4;

__device__ __forceinline__ unsigned short f32_to_bf16(float x) {
    unsigned int u = __float_as_uint(x);
    unsigned int r = (u + 0x7fffu + ((u >> 16) & 1u)) >> 16;   // RTN-even
    return (unsigned short)r;
}
__device__ __forceinline__ float bf16_to_f32(unsigned short h) {
    return __uint_as_float(((unsigned int)h) << 16);
}

// packed f32->bf16 via HW instruction; D.lo=bf16(a), D.hi=bf16(b)
__device__ __forceinline__ unsigned int pk_bf16(float a, float b) {
    unsigned int r;
    asm("v_cvt_pk_bf16_f32 %0, %1, %2" : "=v"(r) : "v"(a), "v"(b));
    return r;
}

// 8 fp32 -> split bf16 hi/lo fragments (pk-based)
__device__ __forceinline__ void f32x8_split(float4 fa, float4 fb, bf16x8& hi, bf16x8& lo) {
    unsigned int h0 = pk_bf16(fa.x, fa.y), h1 = pk_bf16(fa.z, fa.w);
    unsigned int h2 = pk_bf16(fb.x, fb.y), h3 = pk_bf16(fb.z, fb.w);
    float e0 = __uint_as_float(h0 << 16), e1 = __uint_as_float(h0 & 0xffff0000u);
    float e2 = __uint_as_float(h1 << 16), e3 = __uint_as_float(h1 & 0xffff0000u);
    float e4 = __uint_as_float(h2 << 16), e5 = __uint_as_float(h2 & 0xffff0000u);
    float e6 = __uint_as_float(h3 << 16), e7 = __uint_as_float(h3 & 0xffff0000u);
    unsigned int l0 = pk_bf16(fa.x - e0, fa.y - e1), l1 = pk_bf16(fa.z - e2, fa.w - e3);
    unsigned int l2 = pk_bf16(fb.x - e4, fb.y - e5), l3 = pk_bf16(fb.z - e6, fb.w - e7);
    union { unsigned int u[4]; bf16x8 v; } H, L;
    H.u[0] = h0; H.u[1] = h1; H.u[2] = h2; H.u[3] = h3;
    L.u[0] = l0; L.u[1] = l1; L.u[2] = l2; L.u[3] = l3;
    hi = H.v; lo = L.v;
}

__device__ __forceinline__ void atomicMaxF(float* addr, float v) {
    if (v >= 0.f) atomicMax((int*)addr, __float_as_int(v));
    else          atomicMin((unsigned int*)addr, __float_as_uint(v));
}

__global__ void init_stab(float* stab) {
    if (threadIdx.x < BH_) stab[threadIdx.x] = -INFINITY;
}

// ---------------- split-bf16 conversion ----------------
template<int IN_MODE>
__global__ __launch_bounds__(256) void convert_split(const float* __restrict__ src,
                                                     unsigned short* __restrict__ hi,
                                                     unsigned short* __restrict__ lo,
                                                     int total4)
{
    int i = blockIdx.x * 256 + threadIdx.x;
    const int stride = gridDim.x * 256;
    for (; i < total4; i += stride) {
        long e4 = (long)i * 4;
        const float* p;
        if (IN_MODE == 0) {
            long r = e4 >> 10; int e = (int)(e4 & 1023);
            int b = (int)(r >> 12), n = (int)(r & 4095);
            p = src + (((long)(n * B_ + b)) << 10) + e;
        } else {
            p = src + e4;
        }
        float4 v = *(const float4*)p;
        ushort4 h, l;
        h.x = f32_to_bf16(v.x); l.x = f32_to_bf16(v.x - bf16_to_f32(h.x));
        h.y = f32_to_bf16(v.y); l.y = f32_to_bf16(v.y - bf16_to_f32(h.y));
        h.z = f32_to_bf16(v.z); l.z = f32_to_bf16(v.z - bf16_to_f32(h.z));
        h.w = f32_to_bf16(v.w); l.w = f32_to_bf16(v.w - bf16_to_f32(h.w));
        *(ushort4*)(hi + e4) = h;
        *(ushort4*)(lo + e4) = l;
    }
}

__device__ __forceinline__ void gl_lds16(const unsigned short* g, unsigned short* l) {
    __builtin_amdgcn_global_load_lds((const __attribute__((address_space(1))) void*)g,
                                     (__attribute__((address_space(3))) void*)l, 16, 0, 0);
}

// =====================================================================
// Fine-phase pipelined GEMM, all modes: 256x128 tile, BK=32, 8 waves,
// 3 LDS buffers (144KB), 2-deep prefetch, counted vmcnt(6) at K boundaries.
// Bank-conflict-free fragment swizzle: slot = g ^ ((row>>1)&3)  (2-way = free).
// 2 merged phases, 1 barrier per K-tile; intra-phase lgkmcnt left to compiler
// (plain C++ ds_reads -> register-tracked deps -> counted lgkmcnt emitted).
// MODE 0: Y fp32 [BN,E];  MODE 1: Y fp32 [N,B,E] transposed;
// MODE 2: K-fused favorp (T1 + stab);  MODE 3: Q-fused favorp_q + qkv -> attn split-bf16.
// =====================================================================
#define SMEM_DYN8 147456

template<int MODE>
__global__ __launch_bounds__(512, 2) void gemm8p(const unsigned short* __restrict__ Ahi,
                                                 const unsigned short* __restrict__ Alo,
                                                 const unsigned short* __restrict__ Bhi,
                                                 const unsigned short* __restrict__ Blo,
                                                 const float* __restrict__ bias,
                                                 float* __restrict__ Y,
                                                 float* __restrict__ stab,
                                                 const unsigned short* __restrict__ PShi,
                                                 const unsigned short* __restrict__ PSlo,
                                                 const unsigned short* __restrict__ kvThi,
                                                 const unsigned short* __restrict__ kvTlo,
                                                 const float* __restrict__ ksum,
                                                 unsigned short* __restrict__ AttnHi,
                                                 unsigned short* __restrict__ AttnLo)
{
    extern __shared__ char SMEM8[];
    unsigned short* U = (unsigned short*)SMEM8;
    const int t = threadIdx.x;
    const int w = t >> 6, lane = t & 63;
    const int row0 = blockIdx.x * 256, col0 = blockIdx.y * 128;
    const int wrow = (w >> 1) * 64, wcol = (w & 1) * 64;
    const int g = lane >> 4, rl = lane & 15;
    const int lr8 = lane >> 3, lc8 = lane & 7;

    // staging address precompute (granule = 16B = 8 shorts)
    // pre-swizzled source: LDS(row r, slot s) holds global k-octet s ^ ((r>>1)&3)
    int gi0 = t, gi1 = 512 + t;
    int ar0 = gi0 >> 2, as0 = gi0 & 3;
    int ar1 = gi1 >> 2, as1 = gi1 & 3;
    const long aSrc0 = (long)(row0 + ar0) * E_ + ((as0 ^ ((ar0 >> 1) & 3)) << 3);
    const long aSrc1 = (long)(row0 + ar1) * E_ + ((as1 ^ ((ar1 >> 1) & 3)) << 3);
    const int aDst0 = (w * 64) * 8;
    const int aDst1 = (512 + w * 64) * 8;
    const long bSrc = (long)(col0 + (t >> 2)) * E_ + (((t & 3) ^ ((t >> 3) & 3)) << 3);
    const int bDst = (w * 64) * 8;

    f32x4 acc[4][4];
#pragma unroll
    for (int m = 0; m < 4; ++m)
#pragma unroll
        for (int n = 0; n < 4; ++n) acc[m][n] = (f32x4){0.f, 0.f, 0.f, 0.f};

#define STAGE_FULL(TILE, BUFI) {                                        \
        const int k0_ = (TILE) * 32;                                    \
        unsigned short* bu_ = U + (BUFI) * 24576;                       \
        gl_lds16(Ahi + aSrc0 + k0_, bu_ + aDst0);                       \
        gl_lds16(Ahi + aSrc1 + k0_, bu_ + aDst1);                       \
        gl_lds16(Alo + aSrc0 + k0_, bu_ + 8192 + aDst0);                \
        gl_lds16(Alo + aSrc1 + k0_, bu_ + 8192 + aDst1);                \
        gl_lds16(Bhi + bSrc + k0_, bu_ + 16384 + bDst);                 \
        gl_lds16(Blo + bSrc + k0_, bu_ + 20480 + bDst); }

    // 12 MFMA for one m-band (order per-acc unchanged: ah*bh, ah*bl, al*bh over n)
#define MBAND(MI, AH, AL)                                                                     \
        _Pragma("unroll")                                                                     \
        for (int n = 0; n < 4; ++n)                                                           \
            acc[MI][n] = __builtin_amdgcn_mfma_f32_16x16x32_bf16(AH, bhf[n], acc[MI][n], 0, 0, 0); \
        _Pragma("unroll")                                                                     \
        for (int n = 0; n < 4; ++n)                                                           \
            acc[MI][n] = __builtin_amdgcn_mfma_f32_16x16x32_bf16(AH, blf[n], acc[MI][n], 0, 0, 0); \
        _Pragma("unroll")                                                                     \
        for (int n = 0; n < 4; ++n)                                                           \
            acc[MI][n] = __builtin_amdgcn_mfma_f32_16x16x32_bf16(AL, bhf[n], acc[MI][n], 0, 0, 0);

    STAGE_FULL(0, 0);
    STAGE_FULL(1, 1);
    asm volatile("s_waitcnt vmcnt(6)" ::: "memory");   // tile 0 landed (own; FIFO)
    __builtin_amdgcn_s_barrier();                      // all waves' tile 0 landed
    __builtin_amdgcn_sched_barrier(0);

    for (int tt = 0; tt < 32; ++tt) {
        const unsigned short* sb = U + (tt % 3) * 24576;
        unsigned short* ub = U + ((tt + 2) % 3) * 24576;
        const bool st = (tt + 2 < 32);
        const int k2 = (tt + 2) * 32;
        bf16x8 bhf[4], blf[4];

        // ---- phase A: B frags + A bands m=0,1; stage A(t+2) (4 loads) ----
#pragma unroll
        for (int n = 0; n < 4; ++n) {
            int r = wcol + n * 16 + rl;
            int off = r * 32 + ((g ^ ((r >> 1) & 3)) << 3);
            bhf[n] = *(const bf16x8*)(sb + 16384 + off);
            blf[n] = *(const bf16x8*)(sb + 20480 + off);
        }
        {
            int r0 = wrow + rl;
            int off0 = r0 * 32 + ((g ^ ((r0 >> 1) & 3)) << 3);
            bf16x8 ah0 = *(const bf16x8*)(sb + off0);
            bf16x8 al0 = *(const bf16x8*)(sb + 8192 + off0);
            int r1 = wrow + 16 + rl;
            int off1 = r1 * 32 + ((g ^ ((r1 >> 1) & 3)) << 3);
            bf16x8 ah1 = *(const bf16x8*)(sb + off1);
            bf16x8 al1 = *(const bf16x8*)(sb + 8192 + off1);
            if (st) { gl_lds16(Ahi + aSrc0 + k2, ub + aDst0);
                      gl_lds16(Ahi + aSrc1 + k2, ub + aDst1);
                      gl_lds16(Alo + aSrc0 + k2, ub + 8192 + aDst0);
                      gl_lds16(Alo + aSrc1 + k2, ub + 8192 + aDst1); }
            __builtin_amdgcn_s_setprio(1);
            MBAND(0, ah0, al0)
            MBAND(1, ah1, al1)
            __builtin_amdgcn_s_setprio(0);
        }
        // (mid-tile barrier removed — sb stable all iter; disjoint ub halves)

        // ---- phase B: A bands m=2,3; stage B(t+2) (2 loads); boundary wait ----
        {
            int r2 = wrow + 32 + rl;
            int off2 = r2 * 32 + ((g ^ ((r2 >> 1) & 3)) << 3);
            bf16x8 ah2 = *(const bf16x8*)(sb + off2);
            bf16x8 al2 = *(const bf16x8*)(sb + 8192 + off2);
            int r3 = wrow + 48 + rl;
            int off3 = r3 * 32 + ((g ^ ((r3 >> 1) & 3)) << 3);
            bf16x8 ah3 = *(const bf16x8*)(sb + off3);
            bf16x8 al3 = *(const bf16x8*)(sb + 8192 + off3);
            if (st) { gl_lds16(Bhi + bSrc + k2, ub + 16384 + bDst);
                      gl_lds16(Blo + bSrc + k2, ub + 20480 + bDst); }
            __builtin_amdgcn_s_setprio(1);
            MBAND(2, ah2, al2)
            MBAND(3, ah3, al3)
            __builtin_amdgcn_s_setprio(0);
        }
        if (tt < 31) {
            if (st) asm volatile("s_waitcnt vmcnt(6)" ::: "memory");
            else    asm volatile("s_waitcnt vmcnt(0)" ::: "memory");
            __builtin_amdgcn_s_barrier();
            __builtin_amdgcn_sched_barrier(0);
        }
    }
#undef STAGE_FULL
#undef MBAND

    float bv[4];
#pragma unroll
    for (int n = 0; n < 4; ++n) bv[n] = bias[col0 + wcol + n * 16 + rl];

    if (MODE <= 1) {
        // plain epilogue: direct stores from acc registers
#pragma unroll
        for (int m = 0; m < 4; ++m) {
            int rbase = row0 + wrow + m * 16 + g * 4;
#pragma unroll
            for (int n = 0; n < 4; ++n) {
                int c = col0 + wcol + n * 16 + rl;
#pragma unroll
                for (int q = 0; q < 4; ++q) {
                    int r = rbase + q;
                    float v = acc[m][n][q] + bv[n];
                    long off;
                    if (MODE == 0) off = (long)r * E_ + c;
                    else { int b = r >> 12, nn = r & (N_ - 1); off = (long)(nn * B_ + b) * E_ + c; }
                    Y[off] = v;
                }
            }
        }
        return;
    }

    // ---------------- fused favorp epilogue (MODE 2 / 3) ----------------
    __syncthreads();   // all waves done with staging LDS; overlay accF
    float* accF  = (float*)SMEM8 + w * (64 * 68);              // wave-private [64][68]
    float* diagL = (float*)(SMEM8 + 139264) + w * 64;
    float* rnmL  = (float*)(SMEM8 + 139264 + 2048) + w * 64;
    const int b_idx = row0 >> 12;
    const int hg = (col0 >> 6) + (w & 1);                      // global head 0..15
    const int bh_i = b_idx * H_ + hg;

    // hoisted PS fragment loads — band-invariant
    bf16x8 pbh[8], pbl[8];
#pragma unroll
    for (int n = 0; n < 4; ++n)
#pragma unroll
        for (int kk = 0; kk < 2; ++kk) {
            long po = (long)hg * 4096 + (n*16 + rl) * 64 + kk*32 + g*8;
            pbh[n*2+kk] = *(const bf16x8*)(PShi + po);
            pbl[n*2+kk] = *(const bf16x8*)(PSlo + po);
        }

#pragma unroll
    for (int m = 0; m < 4; ++m)
#pragma unroll
        for (int n = 0; n < 4; ++n)
#pragma unroll
            for (int q = 0; q < 4; ++q)
                accF[(m*16 + g*4 + q) * 68 + n*16 + rl] = acc[m][n][q] + bv[n];
    {
        float s = 0.f;
#pragma unroll 16
        for (int d = 0; d < 64; ++d) { float x = accF[lane * 68 + d]; s = fmaf(x, x, s); }
        diagL[lane] = s * DIAG_C;
    }
    __syncthreads();

    float wavemax = -INFINITY;
#pragma unroll
    for (int mi = 0; mi < 4; ++mi) {
        bf16x8 dah[2], dal[2];
#pragma unroll
        for (int kk = 0; kk < 2; ++kk) {
            const float* src = &accF[(mi*16 + rl) * 68 + kk*32 + g*8];
            float4 f0 = *(const float4*)src, f1 = *(const float4*)(src + 4);
            f32x8_split(f0, f1, dah[kk], dal[kk]);
        }
        f32x4 dacc[4];
#pragma unroll
        for (int n = 0; n < 4; ++n) dacc[n] = (f32x4){0.f,0.f,0.f,0.f};
#pragma unroll
        for (int n = 0; n < 4; ++n)
#pragma unroll
            for (int kk = 0; kk < 2; ++kk) {
                dacc[n] = __builtin_amdgcn_mfma_f32_16x16x32_bf16(dah[kk], pbh[n*2+kk], dacc[n], 0, 0, 0);
                dacc[n] = __builtin_amdgcn_mfma_f32_16x16x32_bf16(dah[kk], pbl[n*2+kk], dacc[n], 0, 0, 0);
                dacc[n] = __builtin_amdgcn_mfma_f32_16x16x32_bf16(dal[kk], pbh[n*2+kk], dacc[n], 0, 0, 0);
            }
        if (MODE == 2) {
#pragma unroll
            for (int n = 0; n < 4; ++n)
#pragma unroll
                for (int q = 0; q < 4; ++q) {
                    float dsh = dacc[n][q] * NRM_C;
                    wavemax = fmaxf(wavemax, dsh);
                    int rloc = mi*16 + g*4 + q;
                    accF[rloc * 68 + n*16 + rl] = dsh - diagL[rloc];
                }
        } else {
            float rm0 = -INFINITY, rm1 = -INFINITY, rm2 = -INFINITY, rm3 = -INFINITY;
#pragma unroll
            for (int n = 0; n < 4; ++n) {
                rm0 = fmaxf(rm0, dacc[n][0]); rm1 = fmaxf(rm1, dacc[n][1]);
                rm2 = fmaxf(rm2, dacc[n][2]); rm3 = fmaxf(rm3, dacc[n][3]);
            }
#pragma unroll
            for (int off = 1; off < 16; off <<= 1) {
                rm0 = fmaxf(rm0, __shfl_xor(rm0, off));
                rm1 = fmaxf(rm1, __shfl_xor(rm1, off));
                rm2 = fmaxf(rm2, __shfl_xor(rm2, off));
                rm3 = fmaxf(rm3, __shfl_xor(rm3, off));
            }
            float rmq[4] = {rm0 * NRM_C, rm1 * NRM_C, rm2 * NRM_C, rm3 * NRM_C};
#pragma unroll
            for (int n = 0; n < 4; ++n)
#pragma unroll
                for (int q = 0; q < 4; ++q) {
                    int rloc = mi*16 + g*4 + q;
                    float qp = RATIO_C * expf(dacc[n][q] * NRM_C - diagL[rloc] - rmq[q]) + EPSF;
                    accF[rloc * 68 + n*16 + rl] = qp;
                }
        }
    }

    if (MODE == 2) {
#pragma unroll
        for (int off = 1; off < 64; off <<= 1) wavemax = fmaxf(wavemax, __shfl_xor(wavemax, off));
        if (lane == 0) atomicMaxF(&stab[bh_i], wavemax);
#pragma unroll
        for (int pass = 0; pass < 8; ++pass) {
            int rloc = pass * 8 + lr8;
            const float* sp = &accF[rloc * 68 + lc8 * 8];
            float4 f0 = *(const float4*)sp;
            float4 f1 = *(const float4*)(sp + 4);
            long off = (long)(row0 + wrow + rloc) * E_ + col0 + wcol + lc8 * 8;
            *(float4*)(Y + off) = f0;
            *(float4*)(Y + off + 4) = f1;
        }
        return;
    }

    // MODE 3: normalizer, then qkv via MFMA against kvT
    {
        float s = 0.f;
        const float* kb = ksum + bh_i * 64;
#pragma unroll 16
        for (int m = 0; m < 64; ++m) s = fmaf(accF[lane * 68 + m], kb[m], s);
        rnmL[lane] = 1.f / fmaxf(s, EPSD);
    }
    bf16x8 kbh[8], kbl[8];
#pragma unroll
    for (int n = 0; n < 4; ++n)
#pragma unroll
        for (int kk = 0; kk < 2; ++kk) {
            long ko = (long)bh_i * 4096 + (n*16 + rl) * 64 + kk*32 + g*8;
            kbh[n*2+kk] = *(const bf16x8*)(kvThi + ko);
            kbl[n*2+kk] = *(const bf16x8*)(kvTlo + ko);
        }
    __syncthreads();
#pragma unroll
    for (int mi = 0; mi < 4; ++mi) {
        bf16x8 qah[2], qal[2];
#pragma unroll
        for (int kk = 0; kk < 2; ++kk) {
            const float* src = &accF[(mi*16 + rl) * 68 + kk*32 + g*8];
            float4 f0 = *(const float4*)src, f1 = *(const float4*)(src + 4);
            f32x8_split(f0, f1, qah[kk], qal[kk]);
        }
        f32x4 oacc[4];
#pragma unroll
        for (int n = 0; n < 4; ++n) oacc[n] = (f32x4){0.f,0.f,0.f,0.f};
#pragma unroll
        for (int n = 0; n < 4; ++n)
#pragma unroll
            for (int kk = 0; kk < 2; ++kk) {
                oacc[n] = __builtin_amdgcn_mfma_f32_16x16x32_bf16(qah[kk], kbh[n*2+kk], oacc[n], 0, 0, 0);
                oacc[n] = __builtin_amdgcn_mfma_f32_16x16x32_bf16(qah[kk], kbl[n*2+kk], oacc[n], 0, 0, 0);
                oacc[n] = __builtin_amdgcn_mfma_f32_16x16x32_bf16(qal[kk], kbh[n*2+kk], oacc[n], 0, 0, 0);
            }
#pragma unroll
        for (int n = 0; n < 4; ++n)
#pragma unroll
            for (int q = 0; q < 4; ++q) {
                int rloc = mi*16 + g*4 + q;
                accF[rloc * 68 + n*16 + rl] = oacc[n][q] * rnmL[rloc];
            }
    }
#pragma unroll
    for (int pass = 0; pass < 8; ++pass) {
        int rloc = pass * 8 + lr8;
        const float* sp = &accF[rloc * 68 + lc8 * 8];
        float4 f0 = *(const float4*)sp;
        float4 f1 = *(const float4*)(sp + 4);
        float v[8] = {f0.x,f0.y,f0.z,f0.w,f1.x,f1.y,f1.z,f1.w};
        unsigned int hu[4], lu[4];
#pragma unroll
        for (int j = 0; j < 4; ++j) {
            hu[j] = pk_bf16(v[2*j], v[2*j+1]);
            float ea = __uint_as_float(hu[j] << 16);
            float eb = __uint_as_float(hu[j] & 0xffff0000u);
            lu[j] = pk_bf16(v[2*j] - ea, v[2*j+1] - eb);
        }
        long off = (long)(row0 + wrow + rloc) * E_ + col0 + wcol + lc8 * 8;
        uint4 hv = {hu[0], hu[1], hu[2], hu[3]};
        uint4 lv = {lu[0], lu[1], lu[2], lu[3]};
        *(uint4*)(AttnHi + off) = hv;
        *(uint4*)(AttnLo + off) = lv;
    }
}

// ---------------- fp32 fallback GEMM (round-2 proven) ----------------
template<int IN_MODE, int OUT_MODE>
__global__ __launch_bounds__(256) void lin_gemm(const float* __restrict__ X,
                                                const float* __restrict__ W,
                                                const float* __restrict__ bias,
                                                float* __restrict__ Y)
{
    __shared__ float As[16][68];
    __shared__ float Ws[16][68];
    const int row0 = blockIdx.x * 64;
    const int col0 = blockIdx.y * 64;
    const int t  = threadIdx.x;
    const int lr = t >> 2;
    const int lk = (t & 3) * 4;
    const int ty = t >> 4, tx = t & 15;

    long arow;
    {
        int r = row0 + lr;
        if (IN_MODE == 0) { int b = r >> 12, n = r & (N_ - 1); arow = (long)(n * B_ + b) * E_; }
        else              { arow = (long)r * E_; }
    }
    const long wrow = (long)(col0 + lr) * E_;

    float acc[4][4] = {};
    for (int e0 = 0; e0 < E_; e0 += 16) {
        float4 av = *(const float4*)(X + arow + e0 + lk);
        float4 wv = *(const float4*)(W + wrow + e0 + lk);
        As[lk+0][lr] = av.x; As[lk+1][lr] = av.y; As[lk+2][lr] = av.z; As[lk+3][lr] = av.w;
        Ws[lk+0][lr] = wv.x; Ws[lk+1][lr] = wv.y; Ws[lk+2][lr] = wv.z; Ws[lk+3][lr] = wv.w;
        __syncthreads();
#pragma unroll
        for (int k = 0; k < 16; ++k) {
            float4 a = *(const float4*)&As[k][ty*4];
            float4 w = *(const float4*)&Ws[k][tx*4];
            float a_[4] = {a.x,a.y,a.z,a.w};
            float w_[4] = {w.x,w.y,w.z,w.w};
#pragma unroll
            for (int i = 0; i < 4; ++i)
#pragma unroll
                for (int j = 0; j < 4; ++j)
                    acc[i][j] = fmaf(a_[i], w_[j], acc[i][j]);
        }
        __syncthreads();
    }
    float4 bvv = *(const float4*)(bias + col0 + tx*4);
    float b_[4] = {bvv.x,bvv.y,bvv.z,bvv.w};
#pragma unroll
    for (int i = 0; i < 4; ++i) {
        int r = row0 + ty*4 + i;
        float4 o;
        o.x = acc[i][0] + b_[0]; o.y = acc[i][1] + b_[1];
        o.z = acc[i][2] + b_[2]; o.w = acc[i][3] + b_[3];
        long off;
        if (OUT_MODE == 0) off = (long)r * E_ + col0 + tx*4;
        else { int b = r >> 12, n = r & (N_ - 1); off = (long)(n * B_ + b) * E_ + col0 + tx*4; }
        *(float4*)(Y + off) = o;
    }
}

// ---------------- favorp dash (fallback, IN-PLACE over [B,N,E]) ----------------
template<int IS_QUERY>
__global__ __launch_bounds__(256) void favorp_dash(float* __restrict__ Xh,
                                                   const float* __restrict__ proj,
                                                   float* __restrict__ stab)
{
    __shared__ float Xs[64][68];
    __shared__ float Ps[64][68];
    __shared__ float diag[64];
    __shared__ float red4[4];
    __shared__ float rowred[64][17];
    const int bh = blockIdx.x, b = bh >> 4, h = bh & 15;
    const int n0 = blockIdx.y * 64;
    const int t = threadIdx.x;
    const int r = t >> 2, c0 = (t & 3) * 16;
    const int ty = t >> 4, tx = t & 15;

    const float* xrow = Xh + (long)(b * N_ + n0 + r) * E_ + h * 64;
    const float* prow = proj + (long)(h * 64 + r) * 64;
#pragma unroll
    for (int c = 0; c < 4; ++c) {
        float4 v = *(const float4*)(xrow + c0 + c*4);
        Xs[c0+c*4+0][r] = v.x; Xs[c0+c*4+1][r] = v.y; Xs[c0+c*4+2][r] = v.z; Xs[c0+c*4+3][r] = v.w;
        float4 p = *(const float4*)(prow + c0 + c*4);
        Ps[c0+c*4+0][r] = p.x; Ps[c0+c*4+1][r] = p.y; Ps[c0+c*4+2][r] = p.z; Ps[c0+c*4+3][r] = p.w;
    }
    __syncthreads();
    if (t < 64) {
        float s = 0.f;
#pragma unroll 16
        for (int d = 0; d < 64; ++d) { float x = Xs[d][t]; s = fmaf(x, x, s); }
        diag[t] = s * DIAG_C;
    }
    __syncthreads();

    float acc[4][4] = {};
#pragma unroll 16
    for (int d = 0; d < 64; ++d) {
        float4 a = *(const float4*)&Xs[d][ty*4];
        float4 p = *(const float4*)&Ps[d][tx*4];
        float a_[4] = {a.x,a.y,a.z,a.w};
        float p_[4] = {p.x,p.y,p.z,p.w};
#pragma unroll
        for (int i = 0; i < 4; ++i)
#pragma unroll
            for (int j = 0; j < 4; ++j)
                acc[i][j] = fmaf(a_[i], p_[j], acc[i][j]);
    }
    float dash[4][4];
#pragma unroll
    for (int i = 0; i < 4; ++i)
#pragma unroll
        for (int j = 0; j < 4; ++j) dash[i][j] = acc[i][j] * NRM_C;

    if (IS_QUERY) {
#pragma unroll
        for (int i = 0; i < 4; ++i) {
            float m = fmaxf(fmaxf(dash[i][0], dash[i][1]), fmaxf(dash[i][2], dash[i][3]));
            rowred[ty*4+i][tx] = m;
        }
        __syncthreads();
#pragma unroll
        for (int i = 0; i < 4; ++i) {
            int row = ty*4 + i;
            float m = rowred[row][0];
#pragma unroll
            for (int jj = 1; jj < 16; ++jj) m = fmaxf(m, rowred[row][jj]);
            float dg = diag[row];
            float4 o;
            o.x = RATIO_C * expf(dash[i][0] - dg - m) + EPSF;
            o.y = RATIO_C * expf(dash[i][1] - dg - m) + EPSF;
            o.z = RATIO_C * expf(dash[i][2] - dg - m) + EPSF;
            o.w = RATIO_C * expf(dash[i][3] - dg - m) + EPSF;
            *(float4*)(Xh + (long)(b * N_ + n0 + row) * E_ + h * 64 + tx*4) = o;
        }
    } else {
        float lmax = dash[0][0];
#pragma unroll
        for (int i = 0; i < 4; ++i)
#pragma unroll
            for (int j = 0; j < 4; ++j) lmax = fmaxf(lmax, dash[i][j]);
#pragma unroll
        for (int i = 0; i < 4; ++i) {
            int row = ty*4 + i;
            float dg = diag[row];
            float4 o = { dash[i][0]-dg, dash[i][1]-dg, dash[i][2]-dg, dash[i][3]-dg };
            *(float4*)(Xh + (long)(b * N_ + n0 + row) * E_ + h * 64 + tx*4) = o;
        }
#pragma unroll
        for (int off = 32; off > 0; off >>= 1) lmax = fmaxf(lmax, __shfl_down(lmax, off));
        if ((t & 63) == 0) red4[t >> 6] = lmax;
        __syncthreads();
        if (t == 0)
            atomicMaxF(&stab[bh], fmaxf(fmaxf(red4[0], red4[1]), fmaxf(red4[2], red4[3])));
    }
}

// ---------------- kv partials ----------------
__global__ __launch_bounds__(256) void kv_partial(const float* __restrict__ T1,
                                                  const float* __restrict__ V,
                                                  const float* __restrict__ stab,
                                                  float* __restrict__ kvp,
                                                  float* __restrict__ ksump)
{
    __shared__ float KPs[16][68];
    __shared__ float Vs[16][68];
    const int bh = blockIdx.x, chunk = blockIdx.y;
    const int b = bh >> 4, h = bh & 15;
    const int t = threadIdx.x;
    const int lr = t >> 4, lm = (t & 15) * 4;
    const int ty = t >> 4, tx = t & 15;
    const float stb = stab[bh];
    float acc[4][4] = {};
    float ks = 0.f;
    const int nbeg = chunk * (N_ / SPLITK), nend = nbeg + (N_ / SPLITK);
    for (int n0 = nbeg; n0 < nend; n0 += 16) {
        long rowoff = (long)(b * N_ + n0 + lr) * E_ + h * 64 + lm;
        float4 tv = *(const float4*)(T1 + rowoff);
        float4 vv = *(const float4*)(V + rowoff);
        KPs[lr][lm+0] = RATIO_C * expf(tv.x - stb) + EPSF;
        KPs[lr][lm+1] = RATIO_C * expf(tv.y - stb) + EPSF;
        KPs[lr][lm+2] = RATIO_C * expf(tv.z - stb) + EPSF;
        KPs[lr][lm+3] = RATIO_C * expf(tv.w - stb) + EPSF;
        *(float4*)&Vs[lr][lm] = vv;
        __syncthreads();
        if (t < 64) {
#pragma unroll
            for (int rr = 0; rr < 16; ++rr) ks += KPs[rr][t];
        }
#pragma unroll
        for (int k = 0; k < 16; ++k) {
            float4 a = *(const float4*)&KPs[k][ty*4];
            float4 v4 = *(const float4*)&Vs[k][tx*4];
            float a_[4] = {a.x,a.y,a.z,a.w};
            float v_[4] = {v4.x,v4.y,v4.z,v4.w};
#pragma unroll
            for (int i = 0; i < 4; ++i)
#pragma unroll
                for (int j = 0; j < 4; ++j)
                    acc[i][j] = fmaf(a_[i], v_[j], acc[i][j]);
        }
        __syncthreads();
    }
    const long kvbase = ((long)chunk * BH_ + bh) * 4096;
#pragma unroll
    for (int i = 0; i < 4; ++i) {
        float4 o = {acc[i][0], acc[i][1], acc[i][2], acc[i][3]};
        *(float4*)(kvp + kvbase + (ty*4+i) * 64 + tx*4) = o;
    }
    if (t < 64) ksump[((long)chunk * BH_ + bh) * 64 + t] = ks;
}

// reduce partials; write kv TRANSPOSED split-bf16 [BH][d][m] + ksum fp32 (+kvM fp32 for fallback)
__global__ __launch_bounds__(256) void kv_reduce(const float* __restrict__ kvp,
                                                 const float* __restrict__ ksump,
                                                 float* __restrict__ kvM,
                                                 float* __restrict__ ksum,
                                                 unsigned short* __restrict__ kvThi,
                                                 unsigned short* __restrict__ kvTlo)
{
    int idx = blockIdx.x * 256 + threadIdx.x;
    if (idx < BH_ * 4096) {
        float s = 0.f;
#pragma unroll
        for (int c = 0; c < SPLITK; ++c) s += kvp[(long)c * BH_ * 4096 + idx];
        kvM[idx] = s;
        int bh = idx >> 12, md = idx & 4095, m = md >> 6, d = md & 63;
        unsigned short h16 = f32_to_bf16(s);
        long toff = (long)bh * 4096 + d * 64 + m;
        kvThi[toff] = h16;
        kvTlo[toff] = f32_to_bf16(s - bf16_to_f32(h16));
    } else {
        int j = idx - BH_ * 4096;
        if (j < BH_ * 64) {
            float s = 0.f;
#pragma unroll
            for (int c = 0; c < SPLITK; ++c) s += ksump[(long)c * BH_ * 64 + j];
            ksum[j] = s;
        }
    }
}

// ---------------- qkv + normalize (fallback only) ----------------
__global__ __launch_bounds__(256) void qkv_attn(const float* __restrict__ Qp,
                                                const float* __restrict__ kvM,
                                                const float* __restrict__ ksum,
                                                float* __restrict__ attn)
{
    __shared__ float QPs[64][68];
    __shared__ float kvs[64][68];
    __shared__ float ksums[64];
    __shared__ float rnorm[64];
    const int bh = blockIdx.x, b = bh >> 4, h = bh & 15;
    const int n0 = blockIdx.y * 64;
    const int t = threadIdx.x;
    const int r = t >> 2, c0 = (t & 3) * 16;
    const int ty = t >> 4, tx = t & 15;

#pragma unroll
    for (int c = 0; c < 4; ++c) {
        int idx = t * 16 + c * 4;
        float4 v = *(const float4*)(kvM + (long)bh * 4096 + idx);
        *(float4*)&kvs[idx >> 6][idx & 63] = v;
    }
    if (t < 64) ksums[t] = ksum[bh * 64 + t];
    const float* qrow = Qp + (long)(b * N_ + n0 + r) * E_ + h * 64;
#pragma unroll
    for (int c = 0; c < 4; ++c) {
        float4 v = *(const float4*)(qrow + c0 + c*4);
        QPs[c0+c*4+0][r] = v.x; QPs[c0+c*4+1][r] = v.y; QPs[c0+c*4+2][r] = v.z; QPs[c0+c*4+3][r] = v.w;
    }
    __syncthreads();
    if (t < 64) {
        float s = 0.f;
#pragma unroll 16
        for (int m = 0; m < 64; ++m) s = fmaf(QPs[m][t], ksums[m], s);
        rnorm[t] = 1.f / fmaxf(s, EPSD);
    }
    __syncthreads();
    float acc[4][4] = {};
#pragma unroll 16
    for (int m = 0; m < 64; ++m) {
        float4 a = *(const float4*)&QPs[m][ty*4];
        float4 v4 = *(const float4*)&kvs[m][tx*4];
        float a_[4] = {a.x,a.y,a.z,a.w};
        float v_[4] = {v4.x,v4.y,v4.z,v4.w};
#pragma unroll
        for (int i = 0; i < 4; ++i)
#pragma unroll
            for (int j = 0; j < 4; ++j)
                acc[i][j] = fmaf(a_[i], v_[j], acc[i][j]);
    }
#pragma unroll
    for (int i = 0; i < 4; ++i) {
        int row = ty*4 + i;
        float rn = rnorm[row];
        float4 o = {acc[i][0]*rn, acc[i][1]*rn, acc[i][2]*rn, acc[i][3]*rn};
        *(float4*)(attn + (long)(b * N_ + n0 + row) * E_ + h * 64 + tx*4) = o;
    }
}

extern "C" void kernel_launch(void* const* d_in, const int* in_sizes, int n_in,
                              void* d_out, int out_size, void* d_ws, size_t ws_size,
                              hipStream_t stream)
{
    const float* query = (const float*)d_in[0];
    const float* key   = (const float*)d_in[1];
    const float* value = (const float*)d_in[2];
    const float* Wq    = (const float*)d_in[3];
    const float* bq    = (const float*)d_in[4];
    const float* Wk    = (const float*)d_in[5];
    const float* bk    = (const float*)d_in[6];
    const float* Wv    = (const float*)d_in[7];
    const float* bv    = (const float*)d_in[8];
    const float* Wo    = (const float*)d_in[9];
    const float* bo    = (const float*)d_in[10];
    const float* proj  = (const float*)d_in[11];
    float* O = (float*)d_out;                 // scratch; fully rewritten by final GEMM

    float* ws = (float*)d_ws;
    const size_t SZ = (size_t)BN_ * E_;       // 16.78M floats
    float* A     = ws;                        // V fp32; later attn (split-bf16 in fast path)
    float* kvp   = ws + SZ;
    float* ksump = kvp + (size_t)SPLITK * BH_ * 4096;
    float* kvM   = ksump + (size_t)SPLITK * BH_ * 64;
    float* ksum  = kvM + (size_t)BH_ * 4096;
    float* stab  = ksum + (size_t)BH_ * 64;
    unsigned short* kvThi = (unsigned short*)(stab + 64);            // BH*4096 ush
    unsigned short* kvTlo = kvThi + (size_t)BH_ * 4096;
    unsigned short* PShi  = kvTlo + (size_t)BH_ * 4096;              // 65536 ush
    unsigned short* PSlo  = PShi + 65536;
    const size_t EXTRA_F = (size_t)BH_ * 4096 /*kvT pair*/ + 65536 /*PS pair*/;
    const size_t COMMON_F = SZ + (size_t)SPLITK * BH_ * 4096 + (size_t)SPLITK * BH_ * 64
                          + (size_t)BH_ * 4096 + (size_t)BH_ * 64 + 64 + EXTRA_F;
    unsigned short* Xhi = (unsigned short*)(ws + COMMON_F);
    unsigned short* Xlo = Xhi + SZ;
    unsigned short* Whi = Xlo + SZ;
    unsigned short* Wlo = Whi + (size_t)E_ * E_;
    const size_t NEED_FAST = (COMMON_F + SZ + (size_t)E_ * E_) * 4;  // bytes

    dim3 gF(BH_, N_ / 64);
    dim3 gKV(BH_, SPLITK);
    const int nRed = (BH_ * 4096 + BH_ * 64) / 256;

    if (ws_size >= NEED_FAST) {
        dim3 gP(BN_ / 256, E_ / 128);    // pipelined GEMM, all modes
        const int X4 = (int)(SZ / 4), W4 = (E_ * E_) / 4;
        unsigned short* AttnHi = (unsigned short*)A;
        unsigned short* AttnLo = AttnHi + SZ;

        (void)hipFuncSetAttribute((const void*)&gemm8p<0>, hipFuncAttributeMaxDynamicSharedMemorySize, SMEM_DYN8);
        (void)hipFuncSetAttribute((const void*)&gemm8p<1>, hipFuncAttributeMaxDynamicSharedMemorySize, SMEM_DYN8);
        (void)hipFuncSetAttribute((const void*)&gemm8p<2>, hipFuncAttributeMaxDynamicSharedMemorySize, SMEM_DYN8);
        (void)hipFuncSetAttribute((const void*)&gemm8p<3>, hipFuncAttributeMaxDynamicSharedMemorySize, SMEM_DYN8);

        convert_split<1><<<64, 256, 0, stream>>>(proj, PShi, PSlo, 16384);
        init_stab<<<1, 64, 0, stream>>>(stab);
        // K chain: pipelined GEMM + fused favorp_k -> T1 (O) + stab
        convert_split<0><<<2048, 256, 0, stream>>>(key, Xhi, Xlo, X4);
        convert_split<1><<<1024, 256, 0, stream>>>(Wk, Whi, Wlo, W4);
        gemm8p<2><<<gP, 512, SMEM_DYN8, stream>>>(Xhi, Xlo, Whi, Wlo, bk, O, stab,
                                                  PShi, PSlo, nullptr, nullptr, nullptr, nullptr, nullptr);
        // V chain
        convert_split<0><<<2048, 256, 0, stream>>>(value, Xhi, Xlo, X4);
        convert_split<1><<<1024, 256, 0, stream>>>(Wv, Whi, Wlo, W4);
        gemm8p<0><<<gP, 512, SMEM_DYN8, stream>>>(Xhi, Xlo, Whi, Wlo, bv, A, nullptr,
                                                  nullptr, nullptr, nullptr, nullptr, nullptr, nullptr, nullptr);
        // kv
        kv_partial<<<gKV, 256, 0, stream>>>(O, A, stab, kvp, ksump);
        kv_reduce<<<nRed, 256, 0, stream>>>(kvp, ksump, kvM, ksum, kvThi, kvTlo);
        // Q chain: pipelined GEMM + fused favorp_q + qkv -> attn split-bf16 (A region)
        convert_split<0><<<2048, 256, 0, stream>>>(query, Xhi, Xlo, X4);
        convert_split<1><<<1024, 256, 0, stream>>>(Wq, Whi, Wlo, W4);
        gemm8p<3><<<gP, 512, SMEM_DYN8, stream>>>(Xhi, Xlo, Whi, Wlo, bq, nullptr, nullptr,
                                                  PShi, PSlo, kvThi, kvTlo, ksum, AttnHi, AttnLo);
        // output GEMM (transposed store)
        convert_split<1><<<1024, 256, 0, stream>>>(Wo, Whi, Wlo, W4);
        gemm8p<1><<<gP, 512, SMEM_DYN8, stream>>>(AttnHi, AttnLo, Whi, Wlo, bo, O, nullptr,
                                                  nullptr, nullptr, nullptr, nullptr, nullptr, nullptr, nullptr);
    } else {
        // fp32 fallback (round-2 proven path)
        dim3 gGemm(BN_ / 64, E_ / 64);
        lin_gemm<0,0><<<gGemm, 256, 0, stream>>>(key, Wk, bk, O);
        init_stab<<<1, 64, 0, stream>>>(stab);
        favorp_dash<0><<<gF, 256, 0, stream>>>(O, proj, stab);
        lin_gemm<0,0><<<gGemm, 256, 0, stream>>>(value, Wv, bv, A);
        kv_partial<<<gKV, 256, 0, stream>>>(O, A, stab, kvp, ksump);
        kv_reduce<<<nRed, 256, 0, stream>>>(kvp, ksump, kvM, ksum, kvThi, kvTlo);
        lin_gemm<0,0><<<gGemm, 256, 0, stream>>>(query, Wq, bq, O);
        favorp_dash<1><<<gF, 256, 0, stream>>>(O, proj, stab);
        qkv_attn<<<gF, 256, 0, stream>>>(O, kvM, ksum, A);
        lin_gemm<1,1><<<gGemm, 256, 0, stream>>>(A, Wo, bo, O);
    }
}